// Round 1
// baseline (534.550 us; speedup 1.0000x reference)
//
#include <hip/hip_runtime.h>
#include <hip/hip_bf16.h>

// Problem constants
#define BB 2
#define SS 2048
#define GG 16
#define HH 8
#define EE 64
#define DD 512
#define NCHUNK 32
#define CLEN 64
#define CS_STRIDE 132  // 64 sk + 64 sv + 1 n + 3 pad

// ---------------- generic tiled f32 GEMM: C[M,N] = A[M,K] @ W[K,N] ----------------
__global__ __launch_bounds__(256) void gemm_f32(const float* __restrict__ A,
                                                const float* __restrict__ Wm,
                                                float* __restrict__ C,
                                                int M, int N, int K) {
  __shared__ float As[16][65];
  __shared__ float Bs[16][65];
  const int tid = threadIdx.x;
  const int tx = tid & 15, ty = tid >> 4;
  const int m0 = blockIdx.y * 64, n0 = blockIdx.x * 64;
  float acc[4][4] = {};
  for (int k0 = 0; k0 < K; k0 += 16) {
#pragma unroll
    for (int it = 0; it < 4; ++it) {
      int idx = tid + it * 256;
      int m = idx >> 4, k = idx & 15;
      float v = 0.f;
      if (m0 + m < M) v = A[(size_t)(m0 + m) * K + k0 + k];
      As[k][m] = v;
    }
#pragma unroll
    for (int it = 0; it < 4; ++it) {
      int idx = tid + it * 256;
      int n = idx & 63, k = idx >> 6;
      Bs[k][n] = Wm[(size_t)(k0 + k) * N + n0 + n];
    }
    __syncthreads();
#pragma unroll
    for (int k = 0; k < 16; ++k) {
      float a[4], b[4];
#pragma unroll
      for (int i = 0; i < 4; ++i) a[i] = As[k][ty * 4 + i];
#pragma unroll
      for (int i = 0; i < 4; ++i) b[i] = Bs[k][tx * 4 + i];
#pragma unroll
      for (int i = 0; i < 4; ++i)
#pragma unroll
        for (int jj = 0; jj < 4; ++jj) acc[i][jj] += a[i] * b[jj];
    }
    __syncthreads();
  }
  for (int i = 0; i < 4; ++i) {
    int m = m0 + ty * 4 + i;
    if (m < M) {
      for (int jj = 0; jj < 4; ++jj)
        C[(size_t)m * N + n0 + tx * 4 + jj] = acc[i][jj];
    }
  }
}

// ---------------- scores: w_raw[b,h,g,s] = cs[b,h,g,:]·kk[b,h,s,:] / 8; f64 sum ----------------
__global__ __launch_bounds__(256) void scores_kernel(const float* __restrict__ kk,
                                                     const float* __restrict__ cs,
                                                     float* __restrict__ wraw,
                                                     double* __restrict__ sumbuf) {
  const int bh = blockIdx.y;
  const int b = bh >> 3, h = bh & 7;
  const int s0 = blockIdx.x * 128;
  const int tid = threadIdx.x;
  __shared__ float csL[16][64];
  __shared__ float kkL[128][65];
#pragma unroll
  for (int it = 0; it < 4; ++it) {
    int idx = tid + it * 256;
    int g = idx >> 6, e = idx & 63;
    csL[g][e] = cs[((size_t)(b * GG + g)) * DD + h * EE + e];
  }
  for (int it = 0; it < 32; ++it) {
    int idx = tid + it * 256;
    int s = idx >> 6, e = idx & 63;
    kkL[s][e] = kk[((size_t)(b * SS + s0 + s)) * DD + h * EE + e];
  }
  __syncthreads();
  double lsum = 0.0;
#pragma unroll
  for (int i = 0; i < 8; ++i) {
    int o = i * 256 + tid;
    int g = o >> 7, s = o & 127;
    float d = 0.f;
#pragma unroll
    for (int e = 0; e < 64; ++e) d += csL[g][e] * kkL[s][e];
    d *= 0.125f;
    wraw[((size_t)(bh * GG + g)) * SS + s0 + s] = d;
    lsum += (double)d;
  }
  for (int off = 32; off > 0; off >>= 1) lsum += __shfl_down(lsum, off);
  __shared__ double dred[4];
  int wave = tid >> 6, lane = tid & 63;
  if (lane == 0) dred[wave] = lsum;
  __syncthreads();
  if (tid == 0) {
    double t = dred[0] + dred[1] + dred[2] + dred[3];
    atomicAdd(sumbuf, t);
  }
}

// ---------------- exp: w = exp(w_raw - mean) ----------------
__global__ __launch_bounds__(256) void exp_kernel(float* __restrict__ w,
                                                  const double* __restrict__ sumbuf) {
  int i = blockIdx.x * 256 + threadIdx.x;
  float mean = (float)(*sumbuf * (1.0 / (double)(BB * HH * GG * SS)));
  w[i] = expf(w[i] - mean);
}

// ---------------- scan phase A: chunk-local sums ----------------
__global__ __launch_bounds__(256) void scanA_kernel(const float* __restrict__ w,
                                                    const float* __restrict__ kk,
                                                    const float* __restrict__ vs,
                                                    float* __restrict__ csums) {
  const int bh = blockIdx.y, c = blockIdx.x;
  const int b = bh >> 3, h = bh & 7;
  const int tid = threadIdx.x;
  const int g = tid >> 4, j = tid & 15;
  __shared__ float wL[16][64];
#pragma unroll
  for (int it = 0; it < 4; ++it) {
    int idx = tid + it * 256;
    int gg = idx >> 6, t = idx & 63;
    wL[gg][t] = w[((size_t)(bh * GG + gg)) * SS + c * CLEN + t];
  }
  __syncthreads();
  float sk0 = 0, sk1 = 0, sk2 = 0, sk3 = 0;
  float sv0 = 0, sv1 = 0, sv2 = 0, sv3 = 0;
  float n = 0;
  for (int t = 0; t < CLEN; ++t) {
    float wg = wL[g][t];
    size_t base = ((size_t)(b * SS + c * CLEN + t)) * DD + h * EE + j * 4;
    float4 k4 = *(const float4*)(kk + base);
    float4 v4 = *(const float4*)(vs + base);
    sk0 += wg * k4.x; sk1 += wg * k4.y; sk2 += wg * k4.z; sk3 += wg * k4.w;
    sv0 += wg * v4.x; sv1 += wg * v4.y; sv2 += wg * v4.z; sv3 += wg * v4.w;
    n += wg;
  }
  size_t ob = ((size_t)((bh * NCHUNK + c) * GG + g)) * CS_STRIDE;
  *(float4*)(csums + ob + j * 4) = make_float4(sk0, sk1, sk2, sk3);
  *(float4*)(csums + ob + 64 + j * 4) = make_float4(sv0, sv1, sv2, sv3);
  if (j == 0) csums[ob + 128] = n;
}

// ---------------- scan phase C: prefix init + sequential walk + outputs ----------------
__global__ __launch_bounds__(256) void scanC_kernel(const float* __restrict__ w,
                                                    const float* __restrict__ kk,
                                                    const float* __restrict__ vs,
                                                    const float* __restrict__ qs,
                                                    const float* __restrict__ csums,
                                                    float* __restrict__ attn) {
  const int bh = blockIdx.y, c = blockIdx.x;
  const int b = bh >> 3, h = bh & 7;
  const int tid = threadIdx.x;
  const int g = tid >> 4, j = tid & 15;
  __shared__ float wL[16][64];
  __shared__ float wts[16];
  __shared__ float red[16][68];
#pragma unroll
  for (int it = 0; it < 4; ++it) {
    int idx = tid + it * 256;
    int gg = idx >> 6, t = idx & 63;
    wL[gg][t] = w[((size_t)(bh * GG + gg)) * SS + c * CLEN + t];
  }
  float sk0 = 0, sk1 = 0, sk2 = 0, sk3 = 0;
  float sv0 = 0, sv1 = 0, sv2 = 0, sv3 = 0;
  float n = 0;
  for (int c2 = 0; c2 < c; ++c2) {
    size_t ob = ((size_t)((bh * NCHUNK + c2) * GG + g)) * CS_STRIDE;
    float4 k4 = *(const float4*)(csums + ob + j * 4);
    float4 v4 = *(const float4*)(csums + ob + 64 + j * 4);
    sk0 += k4.x; sk1 += k4.y; sk2 += k4.z; sk3 += k4.w;
    sv0 += v4.x; sv1 += v4.y; sv2 += v4.z; sv3 += v4.w;
    n += csums[ob + 128];
  }
  __syncthreads();
  for (int t = 0; t < CLEN; ++t) {
    int s = c * CLEN + t;
    float wg = wL[g][t];
    size_t base = ((size_t)(b * SS + s)) * DD + h * EE + j * 4;
    float4 k4 = *(const float4*)(kk + base);
    float4 v4 = *(const float4*)(vs + base);
    sk0 += wg * k4.x; sk1 += wg * k4.y; sk2 += wg * k4.z; sk3 += wg * k4.w;
    sv0 += wg * v4.x; sv1 += wg * v4.y; sv2 += wg * v4.z; sv3 += wg * v4.w;
    n += wg;
    float nc = fmaxf(n, 1e-8f);
    float4 q4 = *(const float4*)(qs + base);
    float p = q4.x * sk0 + q4.y * sk1 + q4.z * sk2 + q4.w * sk3;
    p += __shfl_xor(p, 1);
    p += __shfl_xor(p, 2);
    p += __shfl_xor(p, 4);
    p += __shfl_xor(p, 8);
    float wt = p / nc;
    if (j == 0) wts[g] = wt;
    __syncthreads();
    float m = wts[0];
#pragma unroll
    for (int i = 1; i < 16; ++i) m = fmaxf(m, wts[i]);
    float den = 0.f;
#pragma unroll
    for (int i = 0; i < 16; ++i) den += expf(wts[i] - m);
    float pg = expf(wt - m) / den;
    float cg = pg / nc;
    red[g][j * 4 + 0] = cg * sv0;
    red[g][j * 4 + 1] = cg * sv1;
    red[g][j * 4 + 2] = cg * sv2;
    red[g][j * 4 + 3] = cg * sv3;
    __syncthreads();
    if (tid < 64) {
      float o = 0.f;
#pragma unroll
      for (int gg = 0; gg < 16; ++gg) o += red[gg][tid];
      attn[((size_t)(b * SS + s)) * DD + h * EE + tid] = o;
    }
    __syncthreads();
  }
}

extern "C" void kernel_launch(void* const* d_in, const int* in_sizes, int n_in,
                              void* d_out, int out_size, void* d_ws, size_t ws_size,
                              hipStream_t stream) {
  const float* query = (const float*)d_in[0];
  const float* key   = (const float*)d_in[1];
  const float* value = (const float*)d_in[2];
  const float* context = (const float*)d_in[3];
  const float* query_proj   = (const float*)d_in[4];
  const float* key_proj     = (const float*)d_in[5];
  const float* value_proj   = (const float*)d_in[6];
  const float* output_proj  = (const float*)d_in[7];
  const float* context_proj = (const float*)d_in[8];
  float* out = (float*)d_out;

  char* ws = (char*)d_ws;
  double* sumbuf = (double*)ws;                    // 16 B reserved
  float* fbase = (float*)(ws + 16);
  const size_t MS = (size_t)BB * SS * DD;          // 2M floats
  float* qs_t  = fbase;
  float* kk_t  = qs_t + MS;
  float* vs_t  = kk_t + MS;
  float* cs_t  = vs_t + MS;                        // 32*512
  float* wbuf  = cs_t + (size_t)BB * GG * DD;      // 524288
  float* csums = wbuf + (size_t)BB * HH * GG * SS; // 8192*132
  float* attn  = csums + (size_t)BB * HH * NCHUNK * GG * CS_STRIDE;

  hipMemsetAsync(sumbuf, 0, sizeof(double), stream);

  dim3 blk(256);
  dim3 gproj(DD / 64, (BB * SS) / 64);
  gemm_f32<<<gproj, blk, 0, stream>>>(query, query_proj, qs_t, BB * SS, DD, DD);
  gemm_f32<<<gproj, blk, 0, stream>>>(key,   key_proj,   kk_t, BB * SS, DD, DD);
  gemm_f32<<<gproj, blk, 0, stream>>>(value, value_proj, vs_t, BB * SS, DD, DD);
  dim3 gctx(DD / 64, 1);
  gemm_f32<<<gctx, blk, 0, stream>>>(context, context_proj, cs_t, BB * GG, DD, DD);

  dim3 gsc(SS / 128, BB * HH);
  scores_kernel<<<gsc, blk, 0, stream>>>(kk_t, cs_t, wbuf, sumbuf);

  exp_kernel<<<dim3((BB * HH * GG * SS) / 256), blk, 0, stream>>>(wbuf, sumbuf);

  dim3 gscan(NCHUNK, BB * HH);
  scanA_kernel<<<gscan, blk, 0, stream>>>(wbuf, kk_t, vs_t, csums);
  scanC_kernel<<<gscan, blk, 0, stream>>>(wbuf, kk_t, vs_t, qs_t, csums, attn);

  gemm_f32<<<gproj, blk, 0, stream>>>(attn, output_proj, out, BB * SS, DD, DD);
}

// Round 2
// 342.207 us; speedup vs baseline: 1.5621x; 1.5621x over previous
//
#include <hip/hip_runtime.h>
#include <hip/hip_bf16.h>

// Problem constants
#define BB 2
#define SS 2048
#define GG 16
#define HH 8
#define EE 64
#define DD 512
#define NCHUNK 32
#define CLEN 64
#define CS_STRIDE 132  // 64 sk + 64 sv + 1 n + 3 pad

typedef __attribute__((ext_vector_type(8))) short bf16x8;
typedef __attribute__((ext_vector_type(4))) short short4v;
typedef __attribute__((ext_vector_type(4))) float f32x4;

static __device__ __forceinline__ short f2bf(float x) {
  union { float f; unsigned u; } v; v.f = x;
  unsigned r = v.u + 0x7fffu + ((v.u >> 16) & 1u);  // round-nearest-even
  return (short)(r >> 16);
}

// ---------------- f32 -> bf16 elementwise (4 elems/thread) ----------------
__global__ __launch_bounds__(256) void cvt_bf16(const float* __restrict__ in,
                                                short* __restrict__ out) {
  int i = (blockIdx.x * 256 + threadIdx.x) * 4;
  float4 v = *(const float4*)(in + i);
  short4v o;
  o.x = f2bf(v.x); o.y = f2bf(v.y); o.z = f2bf(v.z); o.w = f2bf(v.w);
  *(short4v*)(out + i) = o;
}

// ---------------- weight f32[K][N] -> bf16 transposed [N][K] (K=N=512) ----------------
__global__ __launch_bounds__(256) void cvtT_bf16(const float* __restrict__ W,
                                                 short* __restrict__ Wt) {
  __shared__ float t[32][33];
  const int tx = threadIdx.x, ty = threadIdx.y;
  const int k0 = blockIdx.x * 32, n0 = blockIdx.y * 32;
#pragma unroll
  for (int i = 0; i < 4; ++i)
    t[ty + i * 8][tx] = W[(size_t)(k0 + ty + i * 8) * DD + n0 + tx];
  __syncthreads();
#pragma unroll
  for (int i = 0; i < 4; ++i)
    Wt[(size_t)(n0 + ty + i * 8) * DD + k0 + tx] = f2bf(t[tx][ty + i * 8]);
}

// ---------------- bf16 MFMA GEMM: C[M,N] = A[M,K] @ Bt[N,K]^T, f32 out ----------------
// 64x64 tile, 256 threads = 4 waves, each wave 32x32 via 2x2 mfma_16x16x32 frags.
__global__ __launch_bounds__(256) void gemm_bf16(const short* __restrict__ A,
                                                 const short* __restrict__ Bt,
                                                 float* __restrict__ C,
                                                 int M, int N, int K) {
  __shared__ short As[64 * 40];  // row stride 40 bf16 -> 2-way bank alias only
  __shared__ short Bs[64 * 40];
  const int tid = threadIdx.x;
  const int m0 = blockIdx.y * 64, n0 = blockIdx.x * 64;
  const int wid = tid >> 6, lane = tid & 63;
  const int wm = (wid >> 1) * 32, wn = (wid & 1) * 32;
  const int r = lane & 15, q = lane >> 4;
  const int srow = tid >> 2, scol = (tid & 3) * 8;
  f32x4 acc[2][2] = {};
  for (int k0 = 0; k0 < K; k0 += 32) {
    bf16x8 av = *(const bf16x8*)(A + (size_t)(m0 + srow) * K + k0 + scol);
    bf16x8 bv = *(const bf16x8*)(Bt + (size_t)(n0 + srow) * K + k0 + scol);
    __syncthreads();
    *(bf16x8*)(&As[srow * 40 + scol]) = av;
    *(bf16x8*)(&Bs[srow * 40 + scol]) = bv;
    __syncthreads();
    bf16x8 a0 = *(const bf16x8*)(&As[(wm + r) * 40 + q * 8]);
    bf16x8 a1 = *(const bf16x8*)(&As[(wm + 16 + r) * 40 + q * 8]);
    bf16x8 b0 = *(const bf16x8*)(&Bs[(wn + r) * 40 + q * 8]);
    bf16x8 b1 = *(const bf16x8*)(&Bs[(wn + 16 + r) * 40 + q * 8]);
    acc[0][0] = __builtin_amdgcn_mfma_f32_16x16x32_bf16(a0, b0, acc[0][0], 0, 0, 0);
    acc[0][1] = __builtin_amdgcn_mfma_f32_16x16x32_bf16(a0, b1, acc[0][1], 0, 0, 0);
    acc[1][0] = __builtin_amdgcn_mfma_f32_16x16x32_bf16(a1, b0, acc[1][0], 0, 0, 0);
    acc[1][1] = __builtin_amdgcn_mfma_f32_16x16x32_bf16(a1, b1, acc[1][1], 0, 0, 0);
  }
#pragma unroll
  for (int i = 0; i < 2; ++i)
#pragma unroll
    for (int j = 0; j < 2; ++j)
#pragma unroll
      for (int reg = 0; reg < 4; ++reg) {
        int m = m0 + wm + i * 16 + q * 4 + reg;
        int n = n0 + wn + j * 16 + r;
        C[(size_t)m * N + n] = acc[i][j][reg];
      }
}

// ---------------- small f32 GEMM for context proj (M=32) ----------------
__global__ __launch_bounds__(256) void gemm_f32(const float* __restrict__ A,
                                                const float* __restrict__ Wm,
                                                float* __restrict__ C,
                                                int M, int N, int K) {
  __shared__ float As[16][65];
  __shared__ float Bs[16][65];
  const int tid = threadIdx.x;
  const int tx = tid & 15, ty = tid >> 4;
  const int m0 = blockIdx.y * 64, n0 = blockIdx.x * 64;
  float acc[4][4] = {};
  for (int k0 = 0; k0 < K; k0 += 16) {
#pragma unroll
    for (int it = 0; it < 4; ++it) {
      int idx = tid + it * 256;
      int m = idx >> 4, k = idx & 15;
      float v = 0.f;
      if (m0 + m < M) v = A[(size_t)(m0 + m) * K + k0 + k];
      As[k][m] = v;
    }
#pragma unroll
    for (int it = 0; it < 4; ++it) {
      int idx = tid + it * 256;
      int n = idx & 63, k = idx >> 6;
      Bs[k][n] = Wm[(size_t)(k0 + k) * N + n0 + n];
    }
    __syncthreads();
#pragma unroll
    for (int k = 0; k < 16; ++k) {
      float a[4], b[4];
#pragma unroll
      for (int i = 0; i < 4; ++i) a[i] = As[k][ty * 4 + i];
#pragma unroll
      for (int i = 0; i < 4; ++i) b[i] = Bs[k][tx * 4 + i];
#pragma unroll
      for (int i = 0; i < 4; ++i)
#pragma unroll
        for (int jj = 0; jj < 4; ++jj) acc[i][jj] += a[i] * b[jj];
    }
    __syncthreads();
  }
  for (int i = 0; i < 4; ++i) {
    int m = m0 + ty * 4 + i;
    if (m < M) {
      for (int jj = 0; jj < 4; ++jj)
        C[(size_t)m * N + n0 + tx * 4 + jj] = acc[i][jj];
    }
  }
}

// ---------------- scores: w_raw[b,h,g,s] = cs·kk / 8; f64 global sum ----------------
__global__ __launch_bounds__(256) void scores_kernel(const float* __restrict__ kk,
                                                     const float* __restrict__ cs,
                                                     float* __restrict__ wraw,
                                                     double* __restrict__ sumbuf) {
  const int bh = blockIdx.y;
  const int b = bh >> 3, h = bh & 7;
  const int s0 = blockIdx.x * 128;
  const int tid = threadIdx.x;
  __shared__ float csL[16][64];
  __shared__ float kkL[128][65];
#pragma unroll
  for (int it = 0; it < 4; ++it) {
    int idx = tid + it * 256;
    int g = idx >> 6, e = idx & 63;
    csL[g][e] = cs[((size_t)(b * GG + g)) * DD + h * EE + e];
  }
  for (int it = 0; it < 32; ++it) {
    int idx = tid + it * 256;
    int s = idx >> 6, e = idx & 63;
    kkL[s][e] = kk[((size_t)(b * SS + s0 + s)) * DD + h * EE + e];
  }
  __syncthreads();
  double lsum = 0.0;
#pragma unroll
  for (int i = 0; i < 8; ++i) {
    int o = i * 256 + tid;
    int g = o >> 7, s = o & 127;
    float d = 0.f;
#pragma unroll
    for (int e = 0; e < 64; ++e) d += csL[g][e] * kkL[s][e];
    d *= 0.125f;
    wraw[((size_t)(bh * GG + g)) * SS + s0 + s] = d;
    lsum += (double)d;
  }
  for (int off = 32; off > 0; off >>= 1) lsum += __shfl_down(lsum, off);
  __shared__ double dred[4];
  int wave = tid >> 6, lane = tid & 63;
  if (lane == 0) dred[wave] = lsum;
  __syncthreads();
  if (tid == 0) {
    double t = dred[0] + dred[1] + dred[2] + dred[3];
    atomicAdd(sumbuf, t);
  }
}

// ---------------- exp: w = exp(w_raw - mean) ----------------
__global__ __launch_bounds__(256) void exp_kernel(float* __restrict__ w,
                                                  const double* __restrict__ sumbuf) {
  int i = blockIdx.x * 256 + threadIdx.x;
  float mean = (float)(*sumbuf * (1.0 / (double)(BB * HH * GG * SS)));
  w[i] = expf(w[i] - mean);
}

// ---------------- scan phase A: chunk-local sums ----------------
__global__ __launch_bounds__(256) void scanA_kernel(const float* __restrict__ w,
                                                    const float* __restrict__ kk,
                                                    const float* __restrict__ vs,
                                                    float* __restrict__ csums) {
  const int bh = blockIdx.y, c = blockIdx.x;
  const int b = bh >> 3, h = bh & 7;
  const int tid = threadIdx.x;
  const int g = tid >> 4, j = tid & 15;
  __shared__ float wL[16][64];
#pragma unroll
  for (int it = 0; it < 4; ++it) {
    int idx = tid + it * 256;
    int gg = idx >> 6, t = idx & 63;
    wL[gg][t] = w[((size_t)(bh * GG + gg)) * SS + c * CLEN + t];
  }
  __syncthreads();
  float sk0 = 0, sk1 = 0, sk2 = 0, sk3 = 0;
  float sv0 = 0, sv1 = 0, sv2 = 0, sv3 = 0;
  float n = 0;
  for (int t = 0; t < CLEN; ++t) {
    float wg = wL[g][t];
    size_t base = ((size_t)(b * SS + c * CLEN + t)) * DD + h * EE + j * 4;
    float4 k4 = *(const float4*)(kk + base);
    float4 v4 = *(const float4*)(vs + base);
    sk0 += wg * k4.x; sk1 += wg * k4.y; sk2 += wg * k4.z; sk3 += wg * k4.w;
    sv0 += wg * v4.x; sv1 += wg * v4.y; sv2 += wg * v4.z; sv3 += wg * v4.w;
    n += wg;
  }
  size_t ob = ((size_t)((bh * NCHUNK + c) * GG + g)) * CS_STRIDE;
  *(float4*)(csums + ob + j * 4) = make_float4(sk0, sk1, sk2, sk3);
  *(float4*)(csums + ob + 64 + j * 4) = make_float4(sv0, sv1, sv2, sv3);
  if (j == 0) csums[ob + 128] = n;
}

// ---------------- scan phase C: prefix init + sequential walk + outputs ----------------
__global__ __launch_bounds__(256) void scanC_kernel(const float* __restrict__ w,
                                                    const float* __restrict__ kk,
                                                    const float* __restrict__ vs,
                                                    const float* __restrict__ qs,
                                                    const float* __restrict__ csums,
                                                    float* __restrict__ attn) {
  const int bh = blockIdx.y, c = blockIdx.x;
  const int b = bh >> 3, h = bh & 7;
  const int tid = threadIdx.x;
  const int g = tid >> 4, j = tid & 15;
  __shared__ float wL[16][64];
  __shared__ float wts[16];
  __shared__ float red[16][68];
#pragma unroll
  for (int it = 0; it < 4; ++it) {
    int idx = tid + it * 256;
    int gg = idx >> 6, t = idx & 63;
    wL[gg][t] = w[((size_t)(bh * GG + gg)) * SS + c * CLEN + t];
  }
  float sk0 = 0, sk1 = 0, sk2 = 0, sk3 = 0;
  float sv0 = 0, sv1 = 0, sv2 = 0, sv3 = 0;
  float n = 0;
  for (int c2 = 0; c2 < c; ++c2) {
    size_t ob = ((size_t)((bh * NCHUNK + c2) * GG + g)) * CS_STRIDE;
    float4 k4 = *(const float4*)(csums + ob + j * 4);
    float4 v4 = *(const float4*)(csums + ob + 64 + j * 4);
    sk0 += k4.x; sk1 += k4.y; sk2 += k4.z; sk3 += k4.w;
    sv0 += v4.x; sv1 += v4.y; sv2 += v4.z; sv3 += v4.w;
    n += csums[ob + 128];
  }
  __syncthreads();
  for (int t = 0; t < CLEN; ++t) {
    int s = c * CLEN + t;
    float wg = wL[g][t];
    size_t base = ((size_t)(b * SS + s)) * DD + h * EE + j * 4;
    float4 k4 = *(const float4*)(kk + base);
    float4 v4 = *(const float4*)(vs + base);
    sk0 += wg * k4.x; sk1 += wg * k4.y; sk2 += wg * k4.z; sk3 += wg * k4.w;
    sv0 += wg * v4.x; sv1 += wg * v4.y; sv2 += wg * v4.z; sv3 += wg * v4.w;
    n += wg;
    float nc = fmaxf(n, 1e-8f);
    float4 q4 = *(const float4*)(qs + base);
    float p = q4.x * sk0 + q4.y * sk1 + q4.z * sk2 + q4.w * sk3;
    p += __shfl_xor(p, 1);
    p += __shfl_xor(p, 2);
    p += __shfl_xor(p, 4);
    p += __shfl_xor(p, 8);
    float wt = p / nc;
    if (j == 0) wts[g] = wt;
    __syncthreads();
    float m = wts[0];
#pragma unroll
    for (int i = 1; i < 16; ++i) m = fmaxf(m, wts[i]);
    float den = 0.f;
#pragma unroll
    for (int i = 0; i < 16; ++i) den += expf(wts[i] - m);
    float pg = expf(wt - m) / den;
    float cg = pg / nc;
    red[g][j * 4 + 0] = cg * sv0;
    red[g][j * 4 + 1] = cg * sv1;
    red[g][j * 4 + 2] = cg * sv2;
    red[g][j * 4 + 3] = cg * sv3;
    __syncthreads();
    if (tid < 64) {
      float o = 0.f;
#pragma unroll
      for (int gg = 0; gg < 16; ++gg) o += red[gg][tid];
      attn[((size_t)(b * SS + s)) * DD + h * EE + tid] = o;
    }
    __syncthreads();
  }
}

extern "C" void kernel_launch(void* const* d_in, const int* in_sizes, int n_in,
                              void* d_out, int out_size, void* d_ws, size_t ws_size,
                              hipStream_t stream) {
  const float* query = (const float*)d_in[0];
  const float* key   = (const float*)d_in[1];
  const float* value = (const float*)d_in[2];
  const float* context = (const float*)d_in[3];
  const float* query_proj   = (const float*)d_in[4];
  const float* key_proj     = (const float*)d_in[5];
  const float* value_proj   = (const float*)d_in[6];
  const float* output_proj  = (const float*)d_in[7];
  const float* context_proj = (const float*)d_in[8];
  float* out = (float*)d_out;

  char* ws = (char*)d_ws;
  double* sumbuf = (double*)ws;                    // 16 B reserved
  float* fbase = (float*)(ws + 16);
  const size_t MS = (size_t)BB * SS * DD;          // 2M floats
  float* qs_t  = fbase;
  float* kk_t  = qs_t + MS;
  float* vs_t  = kk_t + MS;
  float* cs_t  = vs_t + MS;                        // 32*512
  float* wbuf  = cs_t + (size_t)BB * GG * DD;      // 524288
  float* csums = wbuf + (size_t)BB * HH * GG * SS; // 8192*132
  float* attn  = csums + (size_t)BB * HH * NCHUNK * GG * CS_STRIDE;
  short* Abf   = (short*)(attn + MS);              // 2M bf16 (reused 4x)
  short* Wbf   = Abf + MS;                         // 512*512 bf16 (reused 4x)

  hipMemsetAsync(sumbuf, 0, sizeof(double), stream);

  dim3 blk(256);
  dim3 gmm(DD / 64, (BB * SS) / 64);               // (8, 64)
  dim3 tb(32, 8), tg(DD / 32, DD / 32);
  dim3 gcv(MS / 1024);                             // 4 elems/thread

  // q projection
  cvtT_bf16<<<tg, tb, 0, stream>>>(query_proj, Wbf);
  cvt_bf16<<<gcv, blk, 0, stream>>>(query, Abf);
  gemm_bf16<<<gmm, blk, 0, stream>>>(Abf, Wbf, qs_t, BB * SS, DD, DD);
  // k projection
  cvtT_bf16<<<tg, tb, 0, stream>>>(key_proj, Wbf);
  cvt_bf16<<<gcv, blk, 0, stream>>>(key, Abf);
  gemm_bf16<<<gmm, blk, 0, stream>>>(Abf, Wbf, kk_t, BB * SS, DD, DD);
  // v projection
  cvtT_bf16<<<tg, tb, 0, stream>>>(value_proj, Wbf);
  cvt_bf16<<<gcv, blk, 0, stream>>>(value, Abf);
  gemm_bf16<<<gmm, blk, 0, stream>>>(Abf, Wbf, vs_t, BB * SS, DD, DD);
  // context projection (tiny, f32)
  gemm_f32<<<dim3(DD / 64, 1), blk, 0, stream>>>(context, context_proj, cs_t, BB * GG, DD, DD);

  dim3 gsc(SS / 128, BB * HH);
  scores_kernel<<<gsc, blk, 0, stream>>>(kk_t, cs_t, wbuf, sumbuf);
  exp_kernel<<<dim3((BB * HH * GG * SS) / 256), blk, 0, stream>>>(wbuf, sumbuf);

  dim3 gscan(NCHUNK, BB * HH);
  scanA_kernel<<<gscan, blk, 0, stream>>>(wbuf, kk_t, vs_t, csums);
  scanC_kernel<<<gscan, blk, 0, stream>>>(wbuf, kk_t, vs_t, qs_t, csums, attn);

  // output projection
  cvtT_bf16<<<tg, tb, 0, stream>>>(output_proj, Wbf);
  cvt_bf16<<<gcv, blk, 0, stream>>>(attn, Abf);
  gemm_bf16<<<gmm, blk, 0, stream>>>(Abf, Wbf, out, BB * SS, DD, DD);
}

// Round 3
// 256.142 us; speedup vs baseline: 2.0869x; 1.3360x over previous
//
#include <hip/hip_runtime.h>
#include <hip/hip_bf16.h>

// Problem constants
#define BB 2
#define SS 2048
#define GG 16
#define HH 8
#define EE 64
#define DD 512
#define NCHUNK 32
#define CLEN 64
#define CS_STRIDE 132  // 64 sk + 64 sv + 1 n + 3 pad

typedef __attribute__((ext_vector_type(8))) short bf16x8;
typedef __attribute__((ext_vector_type(4))) short short4v;
typedef __attribute__((ext_vector_type(4))) float f32x4;

static __device__ __forceinline__ short f2bf(float x) {
  union { float f; unsigned u; } v; v.f = x;
  unsigned r = v.u + 0x7fffu + ((v.u >> 16) & 1u);  // round-nearest-even
  return (short)(r >> 16);
}
static __device__ __forceinline__ float bf2f(short s) {
  return __uint_as_float(((unsigned)(unsigned short)s) << 16);
}
static __device__ __forceinline__ void bsplit(float x, short& hi, short& lo) {
  hi = f2bf(x);
  lo = f2bf(x - bf2f(hi));
}

// ---------------- f32 -> bf16 elementwise (4 elems/thread) ----------------
__global__ __launch_bounds__(256) void cvt_bf16(const float* __restrict__ in,
                                                short* __restrict__ out) {
  int i = (blockIdx.x * 256 + threadIdx.x) * 4;
  float4 v = *(const float4*)(in + i);
  short4v o;
  o.x = f2bf(v.x); o.y = f2bf(v.y); o.z = f2bf(v.z); o.w = f2bf(v.w);
  *(short4v*)(out + i) = o;
}

// ------- 4 weights f32[K][N] -> bf16 transposed [N][K] in one launch -------
__global__ __launch_bounds__(256) void cvtT4_bf16(const float* __restrict__ w0,
                                                  const float* __restrict__ w1,
                                                  const float* __restrict__ w2,
                                                  const float* __restrict__ w3,
                                                  short* __restrict__ o0,
                                                  short* __restrict__ o1,
                                                  short* __restrict__ o2,
                                                  short* __restrict__ o3) {
  const float* W; short* O;
  if (blockIdx.z == 0)      { W = w0; O = o0; }
  else if (blockIdx.z == 1) { W = w1; O = o1; }
  else if (blockIdx.z == 2) { W = w2; O = o2; }
  else                      { W = w3; O = o3; }
  __shared__ float t[32][33];
  const int tx = threadIdx.x, ty = threadIdx.y;
  const int k0 = blockIdx.x * 32, n0 = blockIdx.y * 32;
#pragma unroll
  for (int i = 0; i < 4; ++i)
    t[ty + i * 8][tx] = W[(size_t)(k0 + ty + i * 8) * DD + n0 + tx];
  __syncthreads();
#pragma unroll
  for (int i = 0; i < 4; ++i)
    O[(size_t)(n0 + ty + i * 8) * DD + k0 + tx] = f2bf(t[tx][ty + i * 8]);
}

// ---------------- bf16 MFMA GEMM: C[M,N] = A[M,K] @ Bt[N,K]^T, f32 out ----------------
__global__ __launch_bounds__(256) void gemm_bf16(const short* __restrict__ A,
                                                 const short* __restrict__ Bt,
                                                 float* __restrict__ C,
                                                 int M, int N, int K) {
  __shared__ short As[64 * 40];
  __shared__ short Bs[64 * 40];
  const int tid = threadIdx.x;
  const int m0 = blockIdx.y * 64, n0 = blockIdx.x * 64;
  const int wid = tid >> 6, lane = tid & 63;
  const int wm = (wid >> 1) * 32, wn = (wid & 1) * 32;
  const int r = lane & 15, q = lane >> 4;
  const int srow = tid >> 2, scol = (tid & 3) * 8;
  f32x4 acc[2][2] = {};
  for (int k0 = 0; k0 < K; k0 += 32) {
    bf16x8 av = *(const bf16x8*)(A + (size_t)(m0 + srow) * K + k0 + scol);
    bf16x8 bv = *(const bf16x8*)(Bt + (size_t)(n0 + srow) * K + k0 + scol);
    __syncthreads();
    *(bf16x8*)(&As[srow * 40 + scol]) = av;
    *(bf16x8*)(&Bs[srow * 40 + scol]) = bv;
    __syncthreads();
    bf16x8 a0 = *(const bf16x8*)(&As[(wm + r) * 40 + q * 8]);
    bf16x8 a1 = *(const bf16x8*)(&As[(wm + 16 + r) * 40 + q * 8]);
    bf16x8 b0 = *(const bf16x8*)(&Bs[(wn + r) * 40 + q * 8]);
    bf16x8 b1 = *(const bf16x8*)(&Bs[(wn + 16 + r) * 40 + q * 8]);
    acc[0][0] = __builtin_amdgcn_mfma_f32_16x16x32_bf16(a0, b0, acc[0][0], 0, 0, 0);
    acc[0][1] = __builtin_amdgcn_mfma_f32_16x16x32_bf16(a0, b1, acc[0][1], 0, 0, 0);
    acc[1][0] = __builtin_amdgcn_mfma_f32_16x16x32_bf16(a1, b0, acc[1][0], 0, 0, 0);
    acc[1][1] = __builtin_amdgcn_mfma_f32_16x16x32_bf16(a1, b1, acc[1][1], 0, 0, 0);
  }
#pragma unroll
  for (int i = 0; i < 2; ++i)
#pragma unroll
    for (int j = 0; j < 2; ++j)
#pragma unroll
      for (int reg = 0; reg < 4; ++reg) {
        int m = m0 + wm + i * 16 + q * 4 + reg;
        int n = n0 + wn + j * 16 + r;
        C[(size_t)m * N + n] = acc[i][j][reg];
      }
}

// ---------------- small f32 GEMM for context proj (M=32) ----------------
__global__ __launch_bounds__(256) void gemm_f32(const float* __restrict__ A,
                                                const float* __restrict__ Wm,
                                                float* __restrict__ C,
                                                int M, int N, int K) {
  __shared__ float As[16][65];
  __shared__ float Bs[16][65];
  const int tid = threadIdx.x;
  const int tx = tid & 15, ty = tid >> 4;
  const int m0 = blockIdx.y * 64, n0 = blockIdx.x * 64;
  float acc[4][4] = {};
  for (int k0 = 0; k0 < K; k0 += 16) {
#pragma unroll
    for (int it = 0; it < 4; ++it) {
      int idx = tid + it * 256;
      int m = idx >> 4, k = idx & 15;
      float v = 0.f;
      if (m0 + m < M) v = A[(size_t)(m0 + m) * K + k0 + k];
      As[k][m] = v;
    }
#pragma unroll
    for (int it = 0; it < 4; ++it) {
      int idx = tid + it * 256;
      int n = idx & 63, k = idx >> 6;
      Bs[k][n] = Wm[(size_t)(k0 + k) * N + n0 + n];
    }
    __syncthreads();
#pragma unroll
    for (int k = 0; k < 16; ++k) {
      float a[4], b[4];
#pragma unroll
      for (int i = 0; i < 4; ++i) a[i] = As[k][ty * 4 + i];
#pragma unroll
      for (int i = 0; i < 4; ++i) b[i] = Bs[k][tx * 4 + i];
#pragma unroll
      for (int i = 0; i < 4; ++i)
#pragma unroll
        for (int jj = 0; jj < 4; ++jj) acc[i][jj] += a[i] * b[jj];
    }
    __syncthreads();
  }
  for (int i = 0; i < 4; ++i) {
    int m = m0 + ty * 4 + i;
    if (m < M) {
      for (int jj = 0; jj < 4; ++jj)
        C[(size_t)m * N + n0 + tx * 4 + jj] = acc[i][jj];
    }
  }
}

// ---------------- scores: w_raw = cs·kk / 8; f64 global sum ----------------
__global__ __launch_bounds__(256) void scores_kernel(const float* __restrict__ kk,
                                                     const float* __restrict__ cs,
                                                     float* __restrict__ wraw,
                                                     double* __restrict__ sumbuf) {
  const int bh = blockIdx.y;
  const int b = bh >> 3, h = bh & 7;
  const int s0 = blockIdx.x * 128;
  const int tid = threadIdx.x;
  __shared__ float csL[16][64];
  __shared__ float kkL[128][65];
#pragma unroll
  for (int it = 0; it < 4; ++it) {
    int idx = tid + it * 256;
    int g = idx >> 6, e = idx & 63;
    csL[g][e] = cs[((size_t)(b * GG + g)) * DD + h * EE + e];
  }
  for (int it = 0; it < 32; ++it) {
    int idx = tid + it * 256;
    int s = idx >> 6, e = idx & 63;
    kkL[s][e] = kk[((size_t)(b * SS + s0 + s)) * DD + h * EE + e];
  }
  __syncthreads();
  double lsum = 0.0;
#pragma unroll
  for (int i = 0; i < 8; ++i) {
    int o = i * 256 + tid;
    int g = o >> 7, s = o & 127;
    float d = 0.f;
#pragma unroll
    for (int e = 0; e < 64; ++e) d += csL[g][e] * kkL[s][e];
    d *= 0.125f;
    wraw[((size_t)(bh * GG + g)) * SS + s0 + s] = d;
    lsum += (double)d;
  }
  for (int off = 32; off > 0; off >>= 1) lsum += __shfl_down(lsum, off);
  __shared__ double dred[4];
  int wave = tid >> 6, lane = tid & 63;
  if (lane == 0) dred[wave] = lsum;
  __syncthreads();
  if (tid == 0) {
    double t = dred[0] + dred[1] + dred[2] + dred[3];
    atomicAdd(sumbuf, t);
  }
}

// ---------------- exp: w = exp(w_raw - mean) ----------------
__global__ __launch_bounds__(256) void exp_kernel(float* __restrict__ w,
                                                  const double* __restrict__ sumbuf) {
  int i = blockIdx.x * 256 + threadIdx.x;
  float mean = (float)(*sumbuf * (1.0 / (double)(BB * HH * GG * SS)));
  w[i] = expf(w[i] - mean);
}

// ---------------- scan phase A: chunk-local sums ----------------
__global__ __launch_bounds__(256) void scanA_kernel(const float* __restrict__ w,
                                                    const float* __restrict__ kk,
                                                    const float* __restrict__ vs,
                                                    float* __restrict__ csums) {
  const int bh = blockIdx.y, c = blockIdx.x;
  const int b = bh >> 3, h = bh & 7;
  const int tid = threadIdx.x;
  const int g = tid >> 4, j = tid & 15;
  __shared__ float wL[16][64];
#pragma unroll
  for (int it = 0; it < 4; ++it) {
    int idx = tid + it * 256;
    int gg = idx >> 6, t = idx & 63;
    wL[gg][t] = w[((size_t)(bh * GG + gg)) * SS + c * CLEN + t];
  }
  __syncthreads();
  float sk0 = 0, sk1 = 0, sk2 = 0, sk3 = 0;
  float sv0 = 0, sv1 = 0, sv2 = 0, sv3 = 0;
  float n = 0;
  for (int t = 0; t < CLEN; ++t) {
    float wg = wL[g][t];
    size_t base = ((size_t)(b * SS + c * CLEN + t)) * DD + h * EE + j * 4;
    float4 k4 = *(const float4*)(kk + base);
    float4 v4 = *(const float4*)(vs + base);
    sk0 += wg * k4.x; sk1 += wg * k4.y; sk2 += wg * k4.z; sk3 += wg * k4.w;
    sv0 += wg * v4.x; sv1 += wg * v4.y; sv2 += wg * v4.z; sv3 += wg * v4.w;
    n += wg;
  }
  size_t ob = ((size_t)((bh * NCHUNK + c) * GG + g)) * CS_STRIDE;
  *(float4*)(csums + ob + j * 4) = make_float4(sk0, sk1, sk2, sk3);
  *(float4*)(csums + ob + 64 + j * 4) = make_float4(sv0, sv1, sv2, sv3);
  if (j == 0) csums[ob + 128] = n;
}

// ---------------- scan phase B: exclusive prefix over chunks ----------------
__global__ __launch_bounds__(256) void scanB_kernel(const float* __restrict__ csums,
                                                    float* __restrict__ pfx) {
  const int bh = blockIdx.x;
  const int g = threadIdx.x >> 4, j = threadIdx.x & 15;
  float4 ak = make_float4(0, 0, 0, 0), av = make_float4(0, 0, 0, 0);
  float an = 0.f;
  for (int c = 0; c < NCHUNK; ++c) {
    size_t ob = ((size_t)((bh * NCHUNK + c) * GG + g)) * CS_STRIDE;
    *(float4*)(pfx + ob + j * 4) = ak;
    *(float4*)(pfx + ob + 64 + j * 4) = av;
    if (j == 0) pfx[ob + 128] = an;
    float4 ck = *(const float4*)(csums + ob + j * 4);
    float4 cv = *(const float4*)(csums + ob + 64 + j * 4);
    float cn = csums[ob + 128];
    ak.x += ck.x; ak.y += ck.y; ak.z += ck.z; ak.w += ck.w;
    av.x += cv.x; av.y += cv.y; av.z += cv.z; av.w += cv.w;
    an += cn;
  }
}

// ---------------- chunk kernel: MFMA-based parallel causal attention ----------------
#define LDW 72
#define LDN 40
__global__ __launch_bounds__(256) void chunk_kernel(const float* __restrict__ w,
                                                    const float* __restrict__ kk,
                                                    const float* __restrict__ vs,
                                                    const float* __restrict__ qs,
                                                    const float* __restrict__ pfx,
                                                    short* __restrict__ attnbf) {
  const int c = blockIdx.x, bh = blockIdx.y;
  const int b = bh >> 3, h = bh & 7;
  const int tid = threadIdx.x;
  const int lane = tid & 63, wv = tid >> 6;
  const int r = lane & 15, q = lane >> 4;
  const int sw = wv * 16;

  __shared__ short qh[64 * LDW], qlo[64 * LDW], khb[64 * LDW], dh[64 * LDW];
  __shared__ short whb[16 * LDW], wlb[16 * LDW], skph[16 * LDW], skpl[16 * LDW];
  __shared__ short svpt[64 * LDN];
  __shared__ float nL[16 * 68];
  __shared__ float npreL[16];
  short* wct = qh;   // reused post-B1: Wc^T [t][g], stride LDN
  short* cmb = qlo;  // reused post-B1: C [s][g], stride LDN
  short* vt = khb;   // reused post-B1: Vc^T [e][t], stride LDW
  short* uh = dh;    // reused post-phase3: masked U [s][t], stride LDW

  // ---- phase 0: global loads ----
  const int row = tid >> 2, c16 = (tid & 3) * 16;
  const size_t gb = ((size_t)(b * SS + c * CLEN + row)) * DD + h * EE + c16;
  float4 qv[4], kv[4], vv[4];
#pragma unroll
  for (int i = 0; i < 4; ++i) {
    qv[i] = *(const float4*)(qs + gb + i * 4);
    kv[i] = *(const float4*)(kk + gb + i * 4);
    vv[i] = *(const float4*)(vs + gb + i * 4);
  }
  const int g0 = tid >> 4, t4 = (tid & 15) * 4;
  float4 wv4 = *(const float4*)(w + ((size_t)(bh * GG + g0)) * SS + c * CLEN + t4);
  const size_t ob = ((size_t)((bh * NCHUNK + c) * GG + g0)) * CS_STRIDE;
  float4 skv = *(const float4*)(pfx + ob + t4);
  float4 svv = *(const float4*)(pfx + ob + 64 + t4);
  float npr = 0.f;
  if (tid < 16)
    npr = pfx[((size_t)((bh * NCHUNK + c) * GG + tid)) * CS_STRIDE + 128];

#pragma unroll
  for (int i = 0; i < 4; ++i) {
    const float* pq = (const float*)&qv[i];
    const float* pk = (const float*)&kv[i];
#pragma unroll
    for (int e = 0; e < 4; ++e) {
      int col = c16 + i * 4 + e;
      short hi, lo;
      bsplit(pq[e], hi, lo);
      qh[row * LDW + col] = hi;
      qlo[row * LDW + col] = lo;
      khb[row * LDW + col] = f2bf(pk[e]);
    }
  }
  {
    const float* pw = (const float*)&wv4;
    const float* ps = (const float*)&skv;
#pragma unroll
    for (int e = 0; e < 4; ++e) {
      short hi, lo;
      bsplit(pw[e], hi, lo);
      whb[g0 * LDW + t4 + e] = hi;
      wlb[g0 * LDW + t4 + e] = lo;
      bsplit(ps[e], hi, lo);
      skph[g0 * LDW + t4 + e] = hi;
      skpl[g0 * LDW + t4 + e] = lo;
    }
  }
  if (tid < 16) npreL[tid] = npr;
  __syncthreads();  // B0

  // ---- nL: n[g][s] = npre + inclusive cumsum of w ----
  {
    int s_ = tid & 63, gq = tid >> 6;
#pragma unroll
    for (int gg = 0; gg < 4; ++gg) {
      int g = gq * 4 + gg;
      float acc = npreL[g];
      for (int t = 0; t <= s_; ++t)
        acc += bf2f(whb[g * LDW + t]) + bf2f(wlb[g * LDW + t]);
      nL[g * 68 + s_] = acc;
    }
  }

  // ---- phase 2: dloc = Qc@Kc^T, accwt = Qc@Skp^T (hi/lo refined) ----
  f32x4 accd[4];
  f32x4 accwt = {0.f, 0.f, 0.f, 0.f};
#pragma unroll
  for (int ct = 0; ct < 4; ++ct) accd[ct] = accwt;
#pragma unroll
  for (int kst = 0; kst < 2; ++kst) {
    bf16x8 aq = *(const bf16x8*)(&qh[(sw + r) * LDW + kst * 32 + q * 8]);
    bf16x8 aql = *(const bf16x8*)(&qlo[(sw + r) * LDW + kst * 32 + q * 8]);
    bf16x8 bsh = *(const bf16x8*)(&skph[r * LDW + kst * 32 + q * 8]);
    bf16x8 bsl = *(const bf16x8*)(&skpl[r * LDW + kst * 32 + q * 8]);
    accwt = __builtin_amdgcn_mfma_f32_16x16x32_bf16(aq, bsh, accwt, 0, 0, 0);
    accwt = __builtin_amdgcn_mfma_f32_16x16x32_bf16(aq, bsl, accwt, 0, 0, 0);
    accwt = __builtin_amdgcn_mfma_f32_16x16x32_bf16(aql, bsh, accwt, 0, 0, 0);
#pragma unroll
    for (int ct = 0; ct < 4; ++ct) {
      bf16x8 bk = *(const bf16x8*)(&khb[(ct * 16 + r) * LDW + kst * 32 + q * 8]);
      accd[ct] = __builtin_amdgcn_mfma_f32_16x16x32_bf16(aq, bk, accd[ct], 0, 0, 0);
    }
  }
#pragma unroll
  for (int ct = 0; ct < 4; ++ct)
#pragma unroll
    for (int reg = 0; reg < 4; ++reg) {
      int sl = sw + q * 4 + reg, tl = ct * 16 + r;
      float v = (tl <= sl) ? accd[ct][reg] : 0.f;
      dh[sl * LDW + tl] = f2bf(v);
    }
  __syncthreads();  // B1 (qh/qlo/khb regions free for reuse)

  // ---- phase 2.5: repack vt, svpt, wct (+zero pads) ----
#pragma unroll
  for (int i = 0; i < 4; ++i) {
    const float* pv = (const float*)&vv[i];
#pragma unroll
    for (int e = 0; e < 4; ++e)
      vt[(c16 + i * 4 + e) * LDW + row] = f2bf(pv[e]);
  }
  {
    const float* pv = (const float*)&svv;
#pragma unroll
    for (int e = 0; e < 4; ++e)
      svpt[(t4 + e) * LDN + g0] = f2bf(pv[e]);
    int ez = tid >> 2, gz = 16 + (tid & 3) * 4;
#pragma unroll
    for (int e = 0; e < 4; ++e) svpt[ez * LDN + gz + e] = 0;
    int tt = tid >> 2, gw = (tid & 3) * 4;
#pragma unroll
    for (int e = 0; e < 4; ++e) {
      wct[tt * LDN + gw + e] = whb[(gw + e) * LDW + tt];
      wct[tt * LDN + 16 + gw + e] = 0;
    }
  }

  // ---- phase 3: accwt += tril(dloc)@Wc^T (w hi/lo), then softmax ----
#pragma unroll
  for (int kst = 0; kst < 2; ++kst) {
    bf16x8 ad = *(const bf16x8*)(&dh[(sw + r) * LDW + kst * 32 + q * 8]);
    bf16x8 bw = *(const bf16x8*)(&whb[r * LDW + kst * 32 + q * 8]);
    bf16x8 bl = *(const bf16x8*)(&wlb[r * LDW + kst * 32 + q * 8]);
    accwt = __builtin_amdgcn_mfma_f32_16x16x32_bf16(ad, bw, accwt, 0, 0, 0);
    accwt = __builtin_amdgcn_mfma_f32_16x16x32_bf16(ad, bl, accwt, 0, 0, 0);
  }
#pragma unroll
  for (int reg = 0; reg < 4; ++reg) {
    int sl = sw + q * 4 + reg;
    float nv = fmaxf(nL[r * 68 + sl], 1e-8f);
    float wt = accwt[reg] / nv;
    float m = wt;
    m = fmaxf(m, __shfl_xor(m, 1));
    m = fmaxf(m, __shfl_xor(m, 2));
    m = fmaxf(m, __shfl_xor(m, 4));
    m = fmaxf(m, __shfl_xor(m, 8));
    float ex = expf(wt - m);
    float den = ex;
    den += __shfl_xor(den, 1);
    den += __shfl_xor(den, 2);
    den += __shfl_xor(den, 4);
    den += __shfl_xor(den, 8);
    float cmv = (ex / den) / nv;
    cmb[sl * LDN + r] = f2bf(cmv);
    cmb[sl * LDN + 16 + r] = 0;
  }
  __syncthreads();  // B2 (vt/svpt/wct visible; cm visible)

  // ---- phase 4: U = C@Wc, masked, to uh ----
  bf16x8 acm = *(const bf16x8*)(&cmb[(sw + r) * LDN + q * 8]);
  f32x4 accu[4];
#pragma unroll
  for (int ct = 0; ct < 4; ++ct) accu[ct] = (f32x4){0.f, 0.f, 0.f, 0.f};
#pragma unroll
  for (int ct = 0; ct < 4; ++ct) {
    bf16x8 bwc = *(const bf16x8*)(&wct[(ct * 16 + r) * LDN + q * 8]);
    accu[ct] = __builtin_amdgcn_mfma_f32_16x16x32_bf16(acm, bwc, accu[ct], 0, 0, 0);
  }
#pragma unroll
  for (int ct = 0; ct < 4; ++ct)
#pragma unroll
    for (int reg = 0; reg < 4; ++reg) {
      int sl = sw + q * 4 + reg, tl = ct * 16 + r;
      float v = (tl <= sl) ? accu[ct][reg] : 0.f;
      uh[sl * LDW + tl] = f2bf(v);
    }

  // ---- phase 5: out = C@Svp^T + tril(U)@Vc, store bf16 ----
  f32x4 acco[4];
#pragma unroll
  for (int et = 0; et < 4; ++et) acco[et] = (f32x4){0.f, 0.f, 0.f, 0.f};
#pragma unroll
  for (int et = 0; et < 4; ++et) {
    bf16x8 bs = *(const bf16x8*)(&svpt[(et * 16 + r) * LDN + q * 8]);
    acco[et] = __builtin_amdgcn_mfma_f32_16x16x32_bf16(acm, bs, acco[et], 0, 0, 0);
  }
#pragma unroll
  for (int kst = 0; kst < 2; ++kst) {
    bf16x8 au = *(const bf16x8*)(&uh[(sw + r) * LDW + kst * 32 + q * 8]);
#pragma unroll
    for (int et = 0; et < 4; ++et) {
      bf16x8 bv = *(const bf16x8*)(&vt[(et * 16 + r) * LDW + kst * 32 + q * 8]);
      acco[et] = __builtin_amdgcn_mfma_f32_16x16x32_bf16(au, bv, acco[et], 0, 0, 0);
    }
  }
#pragma unroll
  for (int et = 0; et < 4; ++et)
#pragma unroll
    for (int reg = 0; reg < 4; ++reg) {
      int sl = sw + q * 4 + reg;
      attnbf[((size_t)(b * SS + c * CLEN + sl)) * DD + h * EE + et * 16 + r] =
          f2bf(acco[et][reg]);
    }
}

extern "C" void kernel_launch(void* const* d_in, const int* in_sizes, int n_in,
                              void* d_out, int out_size, void* d_ws, size_t ws_size,
                              hipStream_t stream) {
  const float* query = (const float*)d_in[0];
  const float* key = (const float*)d_in[1];
  const float* value = (const float*)d_in[2];
  const float* context = (const float*)d_in[3];
  const float* query_proj = (const float*)d_in[4];
  const float* key_proj = (const float*)d_in[5];
  const float* value_proj = (const float*)d_in[6];
  const float* output_proj = (const float*)d_in[7];
  const float* context_proj = (const float*)d_in[8];
  float* out = (float*)d_out;

  char* ws = (char*)d_ws;
  double* sumbuf = (double*)ws;  // 16 B reserved
  float* fbase = (float*)(ws + 16);
  const size_t MS = (size_t)BB * SS * DD;  // 2M
  float* qs_t = fbase;
  float* kk_t = qs_t + MS;
  float* vs_t = kk_t + MS;
  float* cs_t = vs_t + MS;                           // 32*512
  float* wbuf = cs_t + (size_t)BB * GG * DD;         // 524288
  float* csums = wbuf + (size_t)BB * HH * GG * SS;   // 8192*132
  float* pfx = csums + (size_t)BB * HH * NCHUNK * GG * CS_STRIDE;
  short* Ain = (short*)(pfx + (size_t)BB * HH * NCHUNK * GG * CS_STRIDE);
  short* Abf = Ain + MS;  // attn bf16
  short* Wq = Abf + MS;
  short* Wk = Wq + (size_t)DD * DD;
  short* Wv = Wk + (size_t)DD * DD;
  short* Wo = Wv + (size_t)DD * DD;

  hipMemsetAsync(sumbuf, 0, sizeof(double), stream);

  dim3 blk(256);
  dim3 gmm(DD / 64, (BB * SS) / 64);  // (8, 64)
  dim3 tb(32, 8), tg4(DD / 32, DD / 32, 4);
  dim3 gcv(MS / 1024);

  cvtT4_bf16<<<tg4, tb, 0, stream>>>(query_proj, key_proj, value_proj, output_proj,
                                     Wq, Wk, Wv, Wo);
  cvt_bf16<<<gcv, blk, 0, stream>>>(query, Ain);
  gemm_bf16<<<gmm, blk, 0, stream>>>(Ain, Wq, qs_t, BB * SS, DD, DD);
  cvt_bf16<<<gcv, blk, 0, stream>>>(key, Ain);
  gemm_bf16<<<gmm, blk, 0, stream>>>(Ain, Wk, kk_t, BB * SS, DD, DD);
  cvt_bf16<<<gcv, blk, 0, stream>>>(value, Ain);
  gemm_bf16<<<gmm, blk, 0, stream>>>(Ain, Wv, vs_t, BB * SS, DD, DD);
  gemm_f32<<<dim3(DD / 64, 1), blk, 0, stream>>>(context, context_proj, cs_t,
                                                 BB * GG, DD, DD);

  dim3 gsc(SS / 128, BB * HH);
  scores_kernel<<<gsc, blk, 0, stream>>>(kk_t, cs_t, wbuf, sumbuf);
  exp_kernel<<<dim3((BB * HH * GG * SS) / 256), blk, 0, stream>>>(wbuf, sumbuf);

  dim3 gscan(NCHUNK, BB * HH);
  scanA_kernel<<<gscan, blk, 0, stream>>>(wbuf, kk_t, vs_t, csums);
  scanB_kernel<<<dim3(BB * HH), blk, 0, stream>>>(csums, pfx);
  chunk_kernel<<<gscan, blk, 0, stream>>>(wbuf, kk_t, vs_t, qs_t, pfx, Abf);

  gemm_bf16<<<gmm, blk, 0, stream>>>(Abf, Wo, out, BB * SS, DD, DD);
}

// Round 4
// 198.323 us; speedup vs baseline: 2.6954x; 1.2915x over previous
//
#include <hip/hip_runtime.h>
#include <hip/hip_bf16.h>

// Problem constants
#define BB 2
#define SS 2048
#define GG 16
#define HH 8
#define EE 64
#define DD 512
#define NCHUNK 32
#define CLEN 64
#define CS_STRIDE 132  // 64 sk + 64 sv + 1 n + 3 pad

typedef __attribute__((ext_vector_type(8))) short bf16x8;
typedef __attribute__((ext_vector_type(4))) short short4v;
typedef __attribute__((ext_vector_type(4))) float f32x4;

static __device__ __forceinline__ short f2bf(float x) {
  union { float f; unsigned u; } v; v.f = x;
  unsigned r = v.u + 0x7fffu + ((v.u >> 16) & 1u);  // round-nearest-even
  return (short)(r >> 16);
}
static __device__ __forceinline__ float bf2f(short s) {
  return __uint_as_float(((unsigned)(unsigned short)s) << 16);
}
static __device__ __forceinline__ void bsplit(float x, short& hi, short& lo) {
  hi = f2bf(x);
  lo = f2bf(x - bf2f(hi));
}

// ---------------- q,k,v f32 -> bf16 in one launch (4 elems/thread) ----------------
__global__ __launch_bounds__(256) void cvt3_bf16(const float* __restrict__ q,
                                                 const float* __restrict__ k,
                                                 const float* __restrict__ v,
                                                 short* __restrict__ oq,
                                                 short* __restrict__ ok,
                                                 short* __restrict__ ov) {
  const float* in; short* out;
  if (blockIdx.y == 0) { in = q; out = oq; }
  else if (blockIdx.y == 1) { in = k; out = ok; }
  else { in = v; out = ov; }
  int i = (blockIdx.x * 256 + threadIdx.x) * 4;
  float4 val = *(const float4*)(in + i);
  short4v o;
  o.x = f2bf(val.x); o.y = f2bf(val.y); o.z = f2bf(val.z); o.w = f2bf(val.w);
  *(short4v*)(out + i) = o;
}

// ------- 4 weights f32[K][N] -> bf16 transposed [N][K] in one launch -------
__global__ __launch_bounds__(256) void cvtT4_bf16(const float* __restrict__ w0,
                                                  const float* __restrict__ w1,
                                                  const float* __restrict__ w2,
                                                  const float* __restrict__ w3,
                                                  short* __restrict__ o0,
                                                  short* __restrict__ o1,
                                                  short* __restrict__ o2,
                                                  short* __restrict__ o3) {
  const float* W; short* O;
  if (blockIdx.z == 0)      { W = w0; O = o0; }
  else if (blockIdx.z == 1) { W = w1; O = o1; }
  else if (blockIdx.z == 2) { W = w2; O = o2; }
  else                      { W = w3; O = o3; }
  __shared__ float t[32][33];
  const int tx = threadIdx.x, ty = threadIdx.y;
  const int k0 = blockIdx.x * 32, n0 = blockIdx.y * 32;
#pragma unroll
  for (int i = 0; i < 4; ++i)
    t[ty + i * 8][tx] = W[(size_t)(k0 + ty + i * 8) * DD + n0 + tx];
  __syncthreads();
#pragma unroll
  for (int i = 0; i < 4; ++i)
    O[(size_t)(n0 + ty + i * 8) * DD + k0 + tx] = f2bf(t[tx][ty + i * 8]);
}

// ---------------- bf16 MFMA GEMM: C[M,N] = A[M,K] @ Bt[N,K]^T, f32 out ----------------
__global__ __launch_bounds__(256) void gemm_bf16(const short* __restrict__ A,
                                                 const short* __restrict__ Bt,
                                                 float* __restrict__ C,
                                                 int M, int N, int K) {
  __shared__ short As[64 * 40];
  __shared__ short Bs[64 * 40];
  const int tid = threadIdx.x;
  const int m0 = blockIdx.y * 64, n0 = blockIdx.x * 64;
  const int wid = tid >> 6, lane = tid & 63;
  const int wm = (wid >> 1) * 32, wn = (wid & 1) * 32;
  const int r = lane & 15, q = lane >> 4;
  const int srow = tid >> 2, scol = (tid & 3) * 8;
  f32x4 acc[2][2] = {};
  for (int k0 = 0; k0 < K; k0 += 32) {
    bf16x8 av = *(const bf16x8*)(A + (size_t)(m0 + srow) * K + k0 + scol);
    bf16x8 bv = *(const bf16x8*)(Bt + (size_t)(n0 + srow) * K + k0 + scol);
    __syncthreads();
    *(bf16x8*)(&As[srow * 40 + scol]) = av;
    *(bf16x8*)(&Bs[srow * 40 + scol]) = bv;
    __syncthreads();
    bf16x8 a0 = *(const bf16x8*)(&As[(wm + r) * 40 + q * 8]);
    bf16x8 a1 = *(const bf16x8*)(&As[(wm + 16 + r) * 40 + q * 8]);
    bf16x8 b0 = *(const bf16x8*)(&Bs[(wn + r) * 40 + q * 8]);
    bf16x8 b1 = *(const bf16x8*)(&Bs[(wn + 16 + r) * 40 + q * 8]);
    acc[0][0] = __builtin_amdgcn_mfma_f32_16x16x32_bf16(a0, b0, acc[0][0], 0, 0, 0);
    acc[0][1] = __builtin_amdgcn_mfma_f32_16x16x32_bf16(a0, b1, acc[0][1], 0, 0, 0);
    acc[1][0] = __builtin_amdgcn_mfma_f32_16x16x32_bf16(a1, b0, acc[1][0], 0, 0, 0);
    acc[1][1] = __builtin_amdgcn_mfma_f32_16x16x32_bf16(a1, b1, acc[1][1], 0, 0, 0);
  }
#pragma unroll
  for (int i = 0; i < 2; ++i)
#pragma unroll
    for (int j = 0; j < 2; ++j)
#pragma unroll
      for (int reg = 0; reg < 4; ++reg) {
        int m = m0 + wm + i * 16 + q * 4 + reg;
        int n = n0 + wn + j * 16 + r;
        C[(size_t)m * N + n] = acc[i][j][reg];
      }
}

// ------- context proj, split-K f32: part[ky][32][512] = A[32][64ky] @ W[64ky][512] -------
__global__ __launch_bounds__(256) void ctx_gemm(const float* __restrict__ A,
                                                const float* __restrict__ Wm,
                                                float* __restrict__ part) {
  const int nt = blockIdx.x;  // n tile (64 cols)
  const int ky = blockIdx.y;  // k slice (64)
  const int tid = threadIdx.x;
  __shared__ float As[32][68];
  __shared__ float Ws[64][68];
  {
    int m = tid >> 3, kq = (tid & 7) * 8;
    float4 a0 = *(const float4*)(A + (size_t)m * DD + ky * 64 + kq);
    float4 a1 = *(const float4*)(A + (size_t)m * DD + ky * 64 + kq + 4);
    As[m][kq + 0] = a0.x; As[m][kq + 1] = a0.y; As[m][kq + 2] = a0.z; As[m][kq + 3] = a0.w;
    As[m][kq + 4] = a1.x; As[m][kq + 5] = a1.y; As[m][kq + 6] = a1.z; As[m][kq + 7] = a1.w;
  }
  {
    int k = tid >> 2, nq = (tid & 3) * 16;
#pragma unroll
    for (int i = 0; i < 4; ++i) {
      float4 wv = *(const float4*)(Wm + (size_t)(ky * 64 + k) * DD + nt * 64 + nq + i * 4);
      Ws[k][nq + i * 4 + 0] = wv.x; Ws[k][nq + i * 4 + 1] = wv.y;
      Ws[k][nq + i * 4 + 2] = wv.z; Ws[k][nq + i * 4 + 3] = wv.w;
    }
  }
  __syncthreads();
  const int tx = tid & 63, my = tid >> 6;
  float acc[8] = {};
  for (int k = 0; k < 64; ++k) {
    float wv = Ws[k][tx];
#pragma unroll
    for (int m = 0; m < 8; ++m) acc[m] += As[my * 8 + m][k] * wv;
  }
#pragma unroll
  for (int m = 0; m < 8; ++m)
    part[((size_t)ky * 32 + my * 8 + m) * DD + nt * 64 + tx] = acc[m];
}

__global__ __launch_bounds__(256) void ctx_reduce(const float* __restrict__ part,
                                                  float* __restrict__ cs) {
  int i = blockIdx.x * 256 + threadIdx.x;  // 16384 total
  float s = 0.f;
#pragma unroll
  for (int ky = 0; ky < 8; ++ky) s += part[(size_t)ky * 32 * DD + i];
  cs[i] = s;
}

// ---------------- scores: w_raw = cs·kk / 8; f64 global sum ----------------
__global__ __launch_bounds__(256) void scores_kernel(const float* __restrict__ kk,
                                                     const float* __restrict__ cs,
                                                     float* __restrict__ wraw,
                                                     double* __restrict__ sumbuf) {
  const int bh = blockIdx.y;
  const int b = bh >> 3, h = bh & 7;
  const int s0 = blockIdx.x * 128;
  const int tid = threadIdx.x;
  __shared__ float csL[16][64];
  __shared__ float kkL[128][65];
#pragma unroll
  for (int it = 0; it < 4; ++it) {
    int idx = tid + it * 256;
    int g = idx >> 6, e = idx & 63;
    csL[g][e] = cs[((size_t)(b * GG + g)) * DD + h * EE + e];
  }
  for (int it = 0; it < 32; ++it) {
    int idx = tid + it * 256;
    int s = idx >> 6, e = idx & 63;
    kkL[s][e] = kk[((size_t)(b * SS + s0 + s)) * DD + h * EE + e];
  }
  __syncthreads();
  double lsum = 0.0;
#pragma unroll
  for (int i = 0; i < 8; ++i) {
    int o = i * 256 + tid;
    int g = o >> 7, s = o & 127;
    float d = 0.f;
#pragma unroll
    for (int e = 0; e < 64; ++e) d += csL[g][e] * kkL[s][e];
    d *= 0.125f;
    wraw[((size_t)(bh * GG + g)) * SS + s0 + s] = d;
    lsum += (double)d;
  }
  for (int off = 32; off > 0; off >>= 1) lsum += __shfl_down(lsum, off);
  __shared__ double dred[4];
  int wave = tid >> 6, lane = tid & 63;
  if (lane == 0) dred[wave] = lsum;
  __syncthreads();
  if (tid == 0) {
    double t = dred[0] + dred[1] + dred[2] + dred[3];
    atomicAdd(sumbuf, t);
  }
}

// ---------------- exp: w = exp(w_raw - mean) ----------------
__global__ __launch_bounds__(256) void exp_kernel(float* __restrict__ w,
                                                  const double* __restrict__ sumbuf) {
  int i = blockIdx.x * 256 + threadIdx.x;
  float mean = (float)(*sumbuf * (1.0 / (double)(BB * HH * GG * SS)));
  w[i] = expf(w[i] - mean);
}

// ---------------- scan phase A: chunk-local sums ----------------
__global__ __launch_bounds__(256) void scanA_kernel(const float* __restrict__ w,
                                                    const float* __restrict__ kk,
                                                    const float* __restrict__ vs,
                                                    float* __restrict__ csums) {
  const int bh = blockIdx.y, c = blockIdx.x;
  const int b = bh >> 3, h = bh & 7;
  const int tid = threadIdx.x;
  const int g = tid >> 4, j = tid & 15;
  __shared__ float wL[16][64];
#pragma unroll
  for (int it = 0; it < 4; ++it) {
    int idx = tid + it * 256;
    int gg = idx >> 6, t = idx & 63;
    wL[gg][t] = w[((size_t)(bh * GG + gg)) * SS + c * CLEN + t];
  }
  __syncthreads();
  float sk0 = 0, sk1 = 0, sk2 = 0, sk3 = 0;
  float sv0 = 0, sv1 = 0, sv2 = 0, sv3 = 0;
  float n = 0;
  for (int t = 0; t < CLEN; ++t) {
    float wg = wL[g][t];
    size_t base = ((size_t)(b * SS + c * CLEN + t)) * DD + h * EE + j * 4;
    float4 k4 = *(const float4*)(kk + base);
    float4 v4 = *(const float4*)(vs + base);
    sk0 += wg * k4.x; sk1 += wg * k4.y; sk2 += wg * k4.z; sk3 += wg * k4.w;
    sv0 += wg * v4.x; sv1 += wg * v4.y; sv2 += wg * v4.z; sv3 += wg * v4.w;
    n += wg;
  }
  size_t ob = ((size_t)((bh * NCHUNK + c) * GG + g)) * CS_STRIDE;
  *(float4*)(csums + ob + j * 4) = make_float4(sk0, sk1, sk2, sk3);
  *(float4*)(csums + ob + 64 + j * 4) = make_float4(sv0, sv1, sv2, sv3);
  if (j == 0) csums[ob + 128] = n;
}

// ---------------- scan phase B: exclusive prefix over chunks ----------------
__global__ __launch_bounds__(256) void scanB_kernel(const float* __restrict__ csums,
                                                    float* __restrict__ pfx) {
  const int bh = blockIdx.x;
  const int g = threadIdx.x >> 4, j = threadIdx.x & 15;
  float4 ak = make_float4(0, 0, 0, 0), av = make_float4(0, 0, 0, 0);
  float an = 0.f;
  for (int c = 0; c < NCHUNK; ++c) {
    size_t ob = ((size_t)((bh * NCHUNK + c) * GG + g)) * CS_STRIDE;
    *(float4*)(pfx + ob + j * 4) = ak;
    *(float4*)(pfx + ob + 64 + j * 4) = av;
    if (j == 0) pfx[ob + 128] = an;
    float4 ck = *(const float4*)(csums + ob + j * 4);
    float4 cv = *(const float4*)(csums + ob + 64 + j * 4);
    float cn = csums[ob + 128];
    ak.x += ck.x; ak.y += ck.y; ak.z += ck.z; ak.w += ck.w;
    av.x += cv.x; av.y += cv.y; av.z += cv.z; av.w += cv.w;
    an += cn;
  }
}

// ---------------- chunk kernel: MFMA-based parallel causal attention ----------------
#define LDW 72
#define LDN 40
__global__ __launch_bounds__(256) void chunk_kernel(const float* __restrict__ w,
                                                    const float* __restrict__ kk,
                                                    const float* __restrict__ vs,
                                                    const float* __restrict__ qs,
                                                    const float* __restrict__ pfx,
                                                    short* __restrict__ attnbf) {
  const int c = blockIdx.x, bh = blockIdx.y;
  const int b = bh >> 3, h = bh & 7;
  const int tid = threadIdx.x;
  const int lane = tid & 63, wv = tid >> 6;
  const int r = lane & 15, q = lane >> 4;
  const int sw = wv * 16;

  __shared__ short qh[64 * LDW], qlo[64 * LDW], khb[64 * LDW], dh[64 * LDW];
  __shared__ short whb[16 * LDW], wlb[16 * LDW], skph[16 * LDW], skpl[16 * LDW];
  __shared__ short svpt[64 * LDN];
  __shared__ float nL[16 * 68];
  __shared__ float npreL[16];
  short* wct = qh;   // reused post-B1
  short* cmb = qlo;  // reused post-B1
  short* vt = khb;   // reused post-B1
  short* uh = dh;    // reused post-phase3

  const int row = tid >> 2, c16 = (tid & 3) * 16;
  const size_t gb = ((size_t)(b * SS + c * CLEN + row)) * DD + h * EE + c16;
  float4 qv[4], kv[4], vv[4];
#pragma unroll
  for (int i = 0; i < 4; ++i) {
    qv[i] = *(const float4*)(qs + gb + i * 4);
    kv[i] = *(const float4*)(kk + gb + i * 4);
    vv[i] = *(const float4*)(vs + gb + i * 4);
  }
  const int g0 = tid >> 4, t4 = (tid & 15) * 4;
  float4 wv4 = *(const float4*)(w + ((size_t)(bh * GG + g0)) * SS + c * CLEN + t4);
  const size_t ob = ((size_t)((bh * NCHUNK + c) * GG + g0)) * CS_STRIDE;
  float4 skv = *(const float4*)(pfx + ob + t4);
  float4 svv = *(const float4*)(pfx + ob + 64 + t4);
  float npr = 0.f;
  if (tid < 16)
    npr = pfx[((size_t)((bh * NCHUNK + c) * GG + tid)) * CS_STRIDE + 128];

#pragma unroll
  for (int i = 0; i < 4; ++i) {
    const float* pq = (const float*)&qv[i];
    const float* pk = (const float*)&kv[i];
#pragma unroll
    for (int e = 0; e < 4; ++e) {
      int col = c16 + i * 4 + e;
      short hi, lo;
      bsplit(pq[e], hi, lo);
      qh[row * LDW + col] = hi;
      qlo[row * LDW + col] = lo;
      khb[row * LDW + col] = f2bf(pk[e]);
    }
  }
  {
    const float* pw = (const float*)&wv4;
    const float* ps = (const float*)&skv;
#pragma unroll
    for (int e = 0; e < 4; ++e) {
      short hi, lo;
      bsplit(pw[e], hi, lo);
      whb[g0 * LDW + t4 + e] = hi;
      wlb[g0 * LDW + t4 + e] = lo;
      bsplit(ps[e], hi, lo);
      skph[g0 * LDW + t4 + e] = hi;
      skpl[g0 * LDW + t4 + e] = lo;
    }
  }
  if (tid < 16) npreL[tid] = npr;
  __syncthreads();  // B0

  {
    int s_ = tid & 63, gq = tid >> 6;
#pragma unroll
    for (int gg = 0; gg < 4; ++gg) {
      int g = gq * 4 + gg;
      float acc = npreL[g];
      for (int t = 0; t <= s_; ++t)
        acc += bf2f(whb[g * LDW + t]) + bf2f(wlb[g * LDW + t]);
      nL[g * 68 + s_] = acc;
    }
  }

  f32x4 accd[4];
  f32x4 accwt = {0.f, 0.f, 0.f, 0.f};
#pragma unroll
  for (int ct = 0; ct < 4; ++ct) accd[ct] = accwt;
#pragma unroll
  for (int kst = 0; kst < 2; ++kst) {
    bf16x8 aq = *(const bf16x8*)(&qh[(sw + r) * LDW + kst * 32 + q * 8]);
    bf16x8 aql = *(const bf16x8*)(&qlo[(sw + r) * LDW + kst * 32 + q * 8]);
    bf16x8 bsh = *(const bf16x8*)(&skph[r * LDW + kst * 32 + q * 8]);
    bf16x8 bsl = *(const bf16x8*)(&skpl[r * LDW + kst * 32 + q * 8]);
    accwt = __builtin_amdgcn_mfma_f32_16x16x32_bf16(aq, bsh, accwt, 0, 0, 0);
    accwt = __builtin_amdgcn_mfma_f32_16x16x32_bf16(aq, bsl, accwt, 0, 0, 0);
    accwt = __builtin_amdgcn_mfma_f32_16x16x32_bf16(aql, bsh, accwt, 0, 0, 0);
#pragma unroll
    for (int ct = 0; ct < 4; ++ct) {
      bf16x8 bk = *(const bf16x8*)(&khb[(ct * 16 + r) * LDW + kst * 32 + q * 8]);
      accd[ct] = __builtin_amdgcn_mfma_f32_16x16x32_bf16(aq, bk, accd[ct], 0, 0, 0);
    }
  }
#pragma unroll
  for (int ct = 0; ct < 4; ++ct)
#pragma unroll
    for (int reg = 0; reg < 4; ++reg) {
      int sl = sw + q * 4 + reg, tl = ct * 16 + r;
      float v = (tl <= sl) ? accd[ct][reg] : 0.f;
      dh[sl * LDW + tl] = f2bf(v);
    }
  __syncthreads();  // B1

#pragma unroll
  for (int i = 0; i < 4; ++i) {
    const float* pv = (const float*)&vv[i];
#pragma unroll
    for (int e = 0; e < 4; ++e)
      vt[(c16 + i * 4 + e) * LDW + row] = f2bf(pv[e]);
  }
  {
    const float* pv = (const float*)&svv;
#pragma unroll
    for (int e = 0; e < 4; ++e)
      svpt[(t4 + e) * LDN + g0] = f2bf(pv[e]);
    int ez = tid >> 2, gz = 16 + (tid & 3) * 4;
#pragma unroll
    for (int e = 0; e < 4; ++e) svpt[ez * LDN + gz + e] = 0;
    int tt = tid >> 2, gw = (tid & 3) * 4;
#pragma unroll
    for (int e = 0; e < 4; ++e) {
      wct[tt * LDN + gw + e] = whb[(gw + e) * LDW + tt];
      wct[tt * LDN + 16 + gw + e] = 0;
    }
  }

#pragma unroll
  for (int kst = 0; kst < 2; ++kst) {
    bf16x8 ad = *(const bf16x8*)(&dh[(sw + r) * LDW + kst * 32 + q * 8]);
    bf16x8 bw = *(const bf16x8*)(&whb[r * LDW + kst * 32 + q * 8]);
    bf16x8 bl = *(const bf16x8*)(&wlb[r * LDW + kst * 32 + q * 8]);
    accwt = __builtin_amdgcn_mfma_f32_16x16x32_bf16(ad, bw, accwt, 0, 0, 0);
    accwt = __builtin_amdgcn_mfma_f32_16x16x32_bf16(ad, bl, accwt, 0, 0, 0);
  }
#pragma unroll
  for (int reg = 0; reg < 4; ++reg) {
    int sl = sw + q * 4 + reg;
    float nv = fmaxf(nL[r * 68 + sl], 1e-8f);
    float wt = accwt[reg] / nv;
    float m = wt;
    m = fmaxf(m, __shfl_xor(m, 1));
    m = fmaxf(m, __shfl_xor(m, 2));
    m = fmaxf(m, __shfl_xor(m, 4));
    m = fmaxf(m, __shfl_xor(m, 8));
    float ex = expf(wt - m);
    float den = ex;
    den += __shfl_xor(den, 1);
    den += __shfl_xor(den, 2);
    den += __shfl_xor(den, 4);
    den += __shfl_xor(den, 8);
    float cmv = (ex / den) / nv;
    cmb[sl * LDN + r] = f2bf(cmv);
    cmb[sl * LDN + 16 + r] = 0;
  }
  __syncthreads();  // B2

  bf16x8 acm = *(const bf16x8*)(&cmb[(sw + r) * LDN + q * 8]);
  f32x4 accu[4];
#pragma unroll
  for (int ct = 0; ct < 4; ++ct) accu[ct] = (f32x4){0.f, 0.f, 0.f, 0.f};
#pragma unroll
  for (int ct = 0; ct < 4; ++ct) {
    bf16x8 bwc = *(const bf16x8*)(&wct[(ct * 16 + r) * LDN + q * 8]);
    accu[ct] = __builtin_amdgcn_mfma_f32_16x16x32_bf16(acm, bwc, accu[ct], 0, 0, 0);
  }
#pragma unroll
  for (int ct = 0; ct < 4; ++ct)
#pragma unroll
    for (int reg = 0; reg < 4; ++reg) {
      int sl = sw + q * 4 + reg, tl = ct * 16 + r;
      float v = (tl <= sl) ? accu[ct][reg] : 0.f;
      uh[sl * LDW + tl] = f2bf(v);
    }

  f32x4 acco[4];
#pragma unroll
  for (int et = 0; et < 4; ++et) acco[et] = (f32x4){0.f, 0.f, 0.f, 0.f};
#pragma unroll
  for (int et = 0; et < 4; ++et) {
    bf16x8 bs = *(const bf16x8*)(&svpt[(et * 16 + r) * LDN + q * 8]);
    acco[et] = __builtin_amdgcn_mfma_f32_16x16x32_bf16(acm, bs, acco[et], 0, 0, 0);
  }
#pragma unroll
  for (int kst = 0; kst < 2; ++kst) {
    bf16x8 au = *(const bf16x8*)(&uh[(sw + r) * LDW + kst * 32 + q * 8]);
#pragma unroll
    for (int et = 0; et < 4; ++et) {
      bf16x8 bv = *(const bf16x8*)(&vt[(et * 16 + r) * LDW + kst * 32 + q * 8]);
      acco[et] = __builtin_amdgcn_mfma_f32_16x16x32_bf16(au, bv, acco[et], 0, 0, 0);
    }
  }
#pragma unroll
  for (int et = 0; et < 4; ++et)
#pragma unroll
    for (int reg = 0; reg < 4; ++reg) {
      int sl = sw + q * 4 + reg;
      attnbf[((size_t)(b * SS + c * CLEN + sl)) * DD + h * EE + et * 16 + r] =
          f2bf(acco[et][reg]);
    }
}

extern "C" void kernel_launch(void* const* d_in, const int* in_sizes, int n_in,
                              void* d_out, int out_size, void* d_ws, size_t ws_size,
                              hipStream_t stream) {
  const float* query = (const float*)d_in[0];
  const float* key = (const float*)d_in[1];
  const float* value = (const float*)d_in[2];
  const float* context = (const float*)d_in[3];
  const float* query_proj = (const float*)d_in[4];
  const float* key_proj = (const float*)d_in[5];
  const float* value_proj = (const float*)d_in[6];
  const float* output_proj = (const float*)d_in[7];
  const float* context_proj = (const float*)d_in[8];
  float* out = (float*)d_out;

  char* ws = (char*)d_ws;
  double* sumbuf = (double*)ws;  // 16 B reserved
  float* fbase = (float*)(ws + 16);
  const size_t MS = (size_t)BB * SS * DD;  // 2M
  float* qs_t = fbase;
  float* kk_t = qs_t + MS;
  float* vs_t = kk_t + MS;
  float* cs_t = vs_t + MS;                          // 32*512
  float* wbuf = cs_t + (size_t)BB * GG * DD;        // 524288
  float* csums = wbuf + (size_t)BB * HH * GG * SS;  // 8192*132
  float* pfx = csums + (size_t)BB * HH * NCHUNK * GG * CS_STRIDE;
  float* part = pfx + (size_t)BB * HH * NCHUNK * GG * CS_STRIDE;  // 8*32*512
  short* Qbf = (short*)(part + (size_t)8 * 32 * DD);
  short* Kbf = Qbf + MS;
  short* Vbf = Kbf + MS;
  short* Abf = Vbf + MS;  // attn bf16 (written directly by chunk_kernel)
  short* Wq = Abf + MS;
  short* Wk = Wq + (size_t)DD * DD;
  short* Wv = Wk + (size_t)DD * DD;
  short* Wo = Wv + (size_t)DD * DD;

  hipMemsetAsync(sumbuf, 0, sizeof(double), stream);

  dim3 blk(256);
  dim3 gmm(DD / 64, (BB * SS) / 64);  // (8, 64)
  dim3 tb(32, 8), tg4(DD / 32, DD / 32, 4);

  cvtT4_bf16<<<tg4, tb, 0, stream>>>(query_proj, key_proj, value_proj, output_proj,
                                     Wq, Wk, Wv, Wo);
  cvt3_bf16<<<dim3(MS / 1024, 3), blk, 0, stream>>>(query, key, value, Qbf, Kbf, Vbf);
  gemm_bf16<<<gmm, blk, 0, stream>>>(Qbf, Wq, qs_t, BB * SS, DD, DD);
  gemm_bf16<<<gmm, blk, 0, stream>>>(Kbf, Wk, kk_t, BB * SS, DD, DD);
  gemm_bf16<<<gmm, blk, 0, stream>>>(Vbf, Wv, vs_t, BB * SS, DD, DD);

  ctx_gemm<<<dim3(8, 8), blk, 0, stream>>>(context, context_proj, part);
  ctx_reduce<<<dim3(BB * GG * DD / 256), blk, 0, stream>>>(part, cs_t);

  dim3 gsc(SS / 128, BB * HH);
  scores_kernel<<<gsc, blk, 0, stream>>>(kk_t, cs_t, wbuf, sumbuf);
  exp_kernel<<<dim3((BB * HH * GG * SS) / 256), blk, 0, stream>>>(wbuf, sumbuf);

  dim3 gscan(NCHUNK, BB * HH);
  scanA_kernel<<<gscan, blk, 0, stream>>>(wbuf, kk_t, vs_t, csums);
  scanB_kernel<<<dim3(BB * HH), blk, 0, stream>>>(csums, pfx);
  chunk_kernel<<<gscan, blk, 0, stream>>>(wbuf, kk_t, vs_t, qs_t, pfx, Abf);

  gemm_bf16<<<gmm, blk, 0, stream>>>(Abf, Wo, out, BB * SS, DD, DD);
}

// Round 5
// 181.703 us; speedup vs baseline: 2.9419x; 1.0915x over previous
//
#include <hip/hip_runtime.h>
#include <hip/hip_bf16.h>

// Problem constants
#define BB 2
#define SS 2048
#define GG 16
#define HH 8
#define EE 64
#define DD 512
#define NCHUNK 32
#define CLEN 64
#define CS_STRIDE 132  // 64 sk + 64 sv + 1 n + 3 pad

typedef __attribute__((ext_vector_type(8))) short bf16x8;
typedef __attribute__((ext_vector_type(4))) short short4v;
typedef __attribute__((ext_vector_type(4))) float f32x4;

static __device__ __forceinline__ short f2bf(float x) {
  union { float f; unsigned u; } v; v.f = x;
  unsigned r = v.u + 0x7fffu + ((v.u >> 16) & 1u);  // round-nearest-even
  return (short)(r >> 16);
}
static __device__ __forceinline__ float bf2f(short s) {
  return __uint_as_float(((unsigned)(unsigned short)s) << 16);
}
static __device__ __forceinline__ void bsplit(float x, short& hi, short& lo) {
  hi = f2bf(x);
  lo = f2bf(x - bf2f(hi));
}

// ------- 4 weights f32[K][N] -> bf16 transposed [N][K] in one launch -------
__global__ __launch_bounds__(256) void cvtT4_bf16(const float* __restrict__ w0,
                                                  const float* __restrict__ w1,
                                                  const float* __restrict__ w2,
                                                  const float* __restrict__ w3,
                                                  short* __restrict__ o0,
                                                  short* __restrict__ o1,
                                                  short* __restrict__ o2,
                                                  short* __restrict__ o3) {
  const float* W; short* O;
  if (blockIdx.z == 0)      { W = w0; O = o0; }
  else if (blockIdx.z == 1) { W = w1; O = o1; }
  else if (blockIdx.z == 2) { W = w2; O = o2; }
  else                      { W = w3; O = o3; }
  __shared__ float t[32][33];
  const int tx = threadIdx.x, ty = threadIdx.y;
  const int k0 = blockIdx.x * 32, n0 = blockIdx.y * 32;
#pragma unroll
  for (int i = 0; i < 4; ++i)
    t[ty + i * 8][tx] = W[(size_t)(k0 + ty + i * 8) * DD + n0 + tx];
  __syncthreads();
#pragma unroll
  for (int i = 0; i < 4; ++i)
    O[(size_t)(n0 + ty + i * 8) * DD + k0 + tx] = f2bf(t[tx][ty + i * 8]);
}

// ---- batched projection GEMM: C[M,N] = cvt_bf16(A_f32[M,K]) @ Bt[N,K]^T ----
// 64x64 tile, BK=64; blockIdx.z selects (A,Bt,C) triple.
#define LDA 72
__global__ __launch_bounds__(256) void proj_gemm(const float* __restrict__ a0,
                                                 const float* __restrict__ a1,
                                                 const float* __restrict__ a2,
                                                 const short* __restrict__ b0,
                                                 const short* __restrict__ b1,
                                                 const short* __restrict__ b2,
                                                 float* __restrict__ c0,
                                                 float* __restrict__ c1,
                                                 float* __restrict__ c2) {
  const float* A; const short* Bt; float* C;
  if (blockIdx.z == 0)      { A = a0; Bt = b0; C = c0; }
  else if (blockIdx.z == 1) { A = a1; Bt = b1; C = c1; }
  else                      { A = a2; Bt = b2; C = c2; }
  const int M = BB * SS, N = DD, K = DD;
  __shared__ short As[64 * LDA];
  __shared__ short Bs[64 * LDA];
  const int tid = threadIdx.x;
  const int m0 = blockIdx.y * 64, n0 = blockIdx.x * 64;
  const int wid = tid >> 6, lane = tid & 63;
  const int wm = (wid >> 1) * 32, wn = (wid & 1) * 32;
  const int r = lane & 15, q = lane >> 4;
  f32x4 acc[2][2] = {};
  for (int k0 = 0; k0 < K; k0 += 64) {
    float4 af[2][2];
    bf16x8 bv[2];
#pragma unroll
    for (int it = 0; it < 2; ++it) {
      int idx = tid + it * 256;
      int row = idx >> 3, colq = (idx & 7) * 8;
      af[it][0] = *(const float4*)(A + (size_t)(m0 + row) * K + k0 + colq);
      af[it][1] = *(const float4*)(A + (size_t)(m0 + row) * K + k0 + colq + 4);
      bv[it] = *(const bf16x8*)(Bt + (size_t)(n0 + row) * K + k0 + colq);
    }
    __syncthreads();
#pragma unroll
    for (int it = 0; it < 2; ++it) {
      int idx = tid + it * 256;
      int row = idx >> 3, colq = (idx & 7) * 8;
      bf16x8 av;
      const float* p0 = (const float*)&af[it][0];
      const float* p1 = (const float*)&af[it][1];
      av[0] = f2bf(p0[0]); av[1] = f2bf(p0[1]); av[2] = f2bf(p0[2]); av[3] = f2bf(p0[3]);
      av[4] = f2bf(p1[0]); av[5] = f2bf(p1[1]); av[6] = f2bf(p1[2]); av[7] = f2bf(p1[3]);
      *(bf16x8*)(&As[row * LDA + colq]) = av;
      *(bf16x8*)(&Bs[row * LDA + colq]) = bv[it];
    }
    __syncthreads();
#pragma unroll
    for (int ks = 0; ks < 2; ++ks) {
      bf16x8 a0r = *(const bf16x8*)(&As[(wm + r) * LDA + ks * 32 + q * 8]);
      bf16x8 a1r = *(const bf16x8*)(&As[(wm + 16 + r) * LDA + ks * 32 + q * 8]);
      bf16x8 b0r = *(const bf16x8*)(&Bs[(wn + r) * LDA + ks * 32 + q * 8]);
      bf16x8 b1r = *(const bf16x8*)(&Bs[(wn + 16 + r) * LDA + ks * 32 + q * 8]);
      acc[0][0] = __builtin_amdgcn_mfma_f32_16x16x32_bf16(a0r, b0r, acc[0][0], 0, 0, 0);
      acc[0][1] = __builtin_amdgcn_mfma_f32_16x16x32_bf16(a0r, b1r, acc[0][1], 0, 0, 0);
      acc[1][0] = __builtin_amdgcn_mfma_f32_16x16x32_bf16(a1r, b0r, acc[1][0], 0, 0, 0);
      acc[1][1] = __builtin_amdgcn_mfma_f32_16x16x32_bf16(a1r, b1r, acc[1][1], 0, 0, 0);
    }
  }
#pragma unroll
  for (int i = 0; i < 2; ++i)
#pragma unroll
    for (int j = 0; j < 2; ++j)
#pragma unroll
      for (int reg = 0; reg < 4; ++reg) {
        int m = m0 + wm + i * 16 + q * 4 + reg;
        int n = n0 + wn + j * 16 + r;
        C[(size_t)m * N + n] = acc[i][j][reg];
      }
}

// ---------------- bf16 MFMA GEMM (bf16 A), BK=64: output projection ----------------
__global__ __launch_bounds__(256) void gemm_bf16(const short* __restrict__ A,
                                                 const short* __restrict__ Bt,
                                                 float* __restrict__ C,
                                                 int M, int N, int K) {
  __shared__ short As[64 * LDA];
  __shared__ short Bs[64 * LDA];
  const int tid = threadIdx.x;
  const int m0 = blockIdx.y * 64, n0 = blockIdx.x * 64;
  const int wid = tid >> 6, lane = tid & 63;
  const int wm = (wid >> 1) * 32, wn = (wid & 1) * 32;
  const int r = lane & 15, q = lane >> 4;
  f32x4 acc[2][2] = {};
  for (int k0 = 0; k0 < K; k0 += 64) {
    bf16x8 av[2], bv[2];
#pragma unroll
    for (int it = 0; it < 2; ++it) {
      int idx = tid + it * 256;
      int row = idx >> 3, colq = (idx & 7) * 8;
      av[it] = *(const bf16x8*)(A + (size_t)(m0 + row) * K + k0 + colq);
      bv[it] = *(const bf16x8*)(Bt + (size_t)(n0 + row) * K + k0 + colq);
    }
    __syncthreads();
#pragma unroll
    for (int it = 0; it < 2; ++it) {
      int idx = tid + it * 256;
      int row = idx >> 3, colq = (idx & 7) * 8;
      *(bf16x8*)(&As[row * LDA + colq]) = av[it];
      *(bf16x8*)(&Bs[row * LDA + colq]) = bv[it];
    }
    __syncthreads();
#pragma unroll
    for (int ks = 0; ks < 2; ++ks) {
      bf16x8 a0r = *(const bf16x8*)(&As[(wm + r) * LDA + ks * 32 + q * 8]);
      bf16x8 a1r = *(const bf16x8*)(&As[(wm + 16 + r) * LDA + ks * 32 + q * 8]);
      bf16x8 b0r = *(const bf16x8*)(&Bs[(wn + r) * LDA + ks * 32 + q * 8]);
      bf16x8 b1r = *(const bf16x8*)(&Bs[(wn + 16 + r) * LDA + ks * 32 + q * 8]);
      acc[0][0] = __builtin_amdgcn_mfma_f32_16x16x32_bf16(a0r, b0r, acc[0][0], 0, 0, 0);
      acc[0][1] = __builtin_amdgcn_mfma_f32_16x16x32_bf16(a0r, b1r, acc[0][1], 0, 0, 0);
      acc[1][0] = __builtin_amdgcn_mfma_f32_16x16x32_bf16(a1r, b0r, acc[1][0], 0, 0, 0);
      acc[1][1] = __builtin_amdgcn_mfma_f32_16x16x32_bf16(a1r, b1r, acc[1][1], 0, 0, 0);
    }
  }
#pragma unroll
  for (int i = 0; i < 2; ++i)
#pragma unroll
    for (int j = 0; j < 2; ++j)
#pragma unroll
      for (int reg = 0; reg < 4; ++reg) {
        int m = m0 + wm + i * 16 + q * 4 + reg;
        int n = n0 + wn + j * 16 + r;
        C[(size_t)m * N + n] = acc[i][j][reg];
      }
}

// ------- context proj, split-K f32 -------
__global__ __launch_bounds__(256) void ctx_gemm(const float* __restrict__ A,
                                                const float* __restrict__ Wm,
                                                float* __restrict__ part) {
  const int nt = blockIdx.x;
  const int ky = blockIdx.y;
  const int tid = threadIdx.x;
  __shared__ float As[32][68];
  __shared__ float Ws[64][68];
  {
    int m = tid >> 3, kq = (tid & 7) * 8;
    float4 a0 = *(const float4*)(A + (size_t)m * DD + ky * 64 + kq);
    float4 a1 = *(const float4*)(A + (size_t)m * DD + ky * 64 + kq + 4);
    As[m][kq + 0] = a0.x; As[m][kq + 1] = a0.y; As[m][kq + 2] = a0.z; As[m][kq + 3] = a0.w;
    As[m][kq + 4] = a1.x; As[m][kq + 5] = a1.y; As[m][kq + 6] = a1.z; As[m][kq + 7] = a1.w;
  }
  {
    int k = tid >> 2, nq = (tid & 3) * 16;
#pragma unroll
    for (int i = 0; i < 4; ++i) {
      float4 wv = *(const float4*)(Wm + (size_t)(ky * 64 + k) * DD + nt * 64 + nq + i * 4);
      Ws[k][nq + i * 4 + 0] = wv.x; Ws[k][nq + i * 4 + 1] = wv.y;
      Ws[k][nq + i * 4 + 2] = wv.z; Ws[k][nq + i * 4 + 3] = wv.w;
    }
  }
  __syncthreads();
  const int tx = tid & 63, my = tid >> 6;
  float acc[8] = {};
  for (int k = 0; k < 64; ++k) {
    float wv = Ws[k][tx];
#pragma unroll
    for (int m = 0; m < 8; ++m) acc[m] += As[my * 8 + m][k] * wv;
  }
#pragma unroll
  for (int m = 0; m < 8; ++m)
    part[((size_t)ky * 32 + my * 8 + m) * DD + nt * 64 + tx] = acc[m];
}

__global__ __launch_bounds__(256) void ctx_reduce(const float* __restrict__ part,
                                                  float* __restrict__ cs) {
  int i = blockIdx.x * 256 + threadIdx.x;
  float s = 0.f;
#pragma unroll
  for (int ky = 0; ky < 8; ++ky) s += part[(size_t)ky * 32 * DD + i];
  cs[i] = s;
}

// ---------------- scores: w_raw = cs·kk / 8; f64 global sum ----------------
__global__ __launch_bounds__(256) void scores_kernel(const float* __restrict__ kk,
                                                     const float* __restrict__ cs,
                                                     float* __restrict__ wraw,
                                                     double* __restrict__ sumbuf) {
  const int bh = blockIdx.y;
  const int b = bh >> 3, h = bh & 7;
  const int s0 = blockIdx.x * 128;
  const int tid = threadIdx.x;
  __shared__ float csL[16][64];
  __shared__ float kkL[128][65];
#pragma unroll
  for (int it = 0; it < 4; ++it) {
    int idx = tid + it * 256;
    int g = idx >> 6, e = idx & 63;
    csL[g][e] = cs[((size_t)(b * GG + g)) * DD + h * EE + e];
  }
  for (int it = 0; it < 32; ++it) {
    int idx = tid + it * 256;
    int s = idx >> 6, e = idx & 63;
    kkL[s][e] = kk[((size_t)(b * SS + s0 + s)) * DD + h * EE + e];
  }
  __syncthreads();
  double lsum = 0.0;
#pragma unroll
  for (int i = 0; i < 8; ++i) {
    int o = i * 256 + tid;
    int g = o >> 7, s = o & 127;
    float d = 0.f;
#pragma unroll
    for (int e = 0; e < 64; ++e) d += csL[g][e] * kkL[s][e];
    d *= 0.125f;
    wraw[((size_t)(bh * GG + g)) * SS + s0 + s] = d;
    lsum += (double)d;
  }
  for (int off = 32; off > 0; off >>= 1) lsum += __shfl_down(lsum, off);
  __shared__ double dred[4];
  int wave = tid >> 6, lane = tid & 63;
  if (lane == 0) dred[wave] = lsum;
  __syncthreads();
  if (tid == 0) {
    double t = dred[0] + dred[1] + dred[2] + dred[3];
    atomicAdd(sumbuf, t);
  }
}

// ---------------- scan phase A: chunk-local sums (exp fused) ----------------
__global__ __launch_bounds__(256) void scanA_kernel(const float* __restrict__ wraw,
                                                    const float* __restrict__ kk,
                                                    const float* __restrict__ vs,
                                                    const double* __restrict__ sumbuf,
                                                    float* __restrict__ csums) {
  const int bh = blockIdx.y, c = blockIdx.x;
  const int b = bh >> 3, h = bh & 7;
  const int tid = threadIdx.x;
  const int g = tid >> 4, j = tid & 15;
  const float mean = (float)(*sumbuf * (1.0 / (double)(BB * HH * GG * SS)));
  __shared__ float wL[16][64];
#pragma unroll
  for (int it = 0; it < 4; ++it) {
    int idx = tid + it * 256;
    int gg = idx >> 6, t = idx & 63;
    wL[gg][t] = expf(wraw[((size_t)(bh * GG + gg)) * SS + c * CLEN + t] - mean);
  }
  __syncthreads();
  float sk0 = 0, sk1 = 0, sk2 = 0, sk3 = 0;
  float sv0 = 0, sv1 = 0, sv2 = 0, sv3 = 0;
  float n = 0;
  for (int t = 0; t < CLEN; ++t) {
    float wg = wL[g][t];
    size_t base = ((size_t)(b * SS + c * CLEN + t)) * DD + h * EE + j * 4;
    float4 k4 = *(const float4*)(kk + base);
    float4 v4 = *(const float4*)(vs + base);
    sk0 += wg * k4.x; sk1 += wg * k4.y; sk2 += wg * k4.z; sk3 += wg * k4.w;
    sv0 += wg * v4.x; sv1 += wg * v4.y; sv2 += wg * v4.z; sv3 += wg * v4.w;
    n += wg;
  }
  size_t ob = ((size_t)((bh * NCHUNK + c) * GG + g)) * CS_STRIDE;
  *(float4*)(csums + ob + j * 4) = make_float4(sk0, sk1, sk2, sk3);
  *(float4*)(csums + ob + 64 + j * 4) = make_float4(sv0, sv1, sv2, sv3);
  if (j == 0) csums[ob + 128] = n;
}

// ---------------- scan phase B: exclusive prefix over chunks ----------------
__global__ __launch_bounds__(256) void scanB_kernel(const float* __restrict__ csums,
                                                    float* __restrict__ pfx) {
  const int bh = blockIdx.x;
  const int g = threadIdx.x >> 4, j = threadIdx.x & 15;
  float4 ak = make_float4(0, 0, 0, 0), av = make_float4(0, 0, 0, 0);
  float an = 0.f;
  for (int c = 0; c < NCHUNK; ++c) {
    size_t ob = ((size_t)((bh * NCHUNK + c) * GG + g)) * CS_STRIDE;
    *(float4*)(pfx + ob + j * 4) = ak;
    *(float4*)(pfx + ob + 64 + j * 4) = av;
    if (j == 0) pfx[ob + 128] = an;
    float4 ck = *(const float4*)(csums + ob + j * 4);
    float4 cv = *(const float4*)(csums + ob + 64 + j * 4);
    float cn = csums[ob + 128];
    ak.x += ck.x; ak.y += ck.y; ak.z += ck.z; ak.w += ck.w;
    av.x += cv.x; av.y += cv.y; av.z += cv.z; av.w += cv.w;
    an += cn;
  }
}

// ---------------- chunk kernel: MFMA-based parallel causal attention (exp fused) ----------------
#define LDW 72
#define LDN 40
__global__ __launch_bounds__(256) void chunk_kernel(const float* __restrict__ wraw,
                                                    const float* __restrict__ kk,
                                                    const float* __restrict__ vs,
                                                    const float* __restrict__ qs,
                                                    const float* __restrict__ pfx,
                                                    const double* __restrict__ sumbuf,
                                                    short* __restrict__ attnbf) {
  const int c = blockIdx.x, bh = blockIdx.y;
  const int b = bh >> 3, h = bh & 7;
  const int tid = threadIdx.x;
  const int lane = tid & 63, wv = tid >> 6;
  const int r = lane & 15, q = lane >> 4;
  const int sw = wv * 16;
  const float mean = (float)(*sumbuf * (1.0 / (double)(BB * HH * GG * SS)));

  __shared__ short qh[64 * LDW], qlo[64 * LDW], khb[64 * LDW], dh[64 * LDW];
  __shared__ short whb[16 * LDW], wlb[16 * LDW], skph[16 * LDW], skpl[16 * LDW];
  __shared__ short svpt[64 * LDN];
  __shared__ float nL[16 * 68];
  __shared__ float npreL[16];
  short* wct = qh;   // reused post-B1
  short* cmb = qlo;  // reused post-B1
  short* vt = khb;   // reused post-B1
  short* uh = dh;    // reused post-phase3

  const int row = tid >> 2, c16 = (tid & 3) * 16;
  const size_t gb = ((size_t)(b * SS + c * CLEN + row)) * DD + h * EE + c16;
  float4 qv[4], kv[4], vv[4];
#pragma unroll
  for (int i = 0; i < 4; ++i) {
    qv[i] = *(const float4*)(qs + gb + i * 4);
    kv[i] = *(const float4*)(kk + gb + i * 4);
    vv[i] = *(const float4*)(vs + gb + i * 4);
  }
  const int g0 = tid >> 4, t4 = (tid & 15) * 4;
  float4 wv4 = *(const float4*)(wraw + ((size_t)(bh * GG + g0)) * SS + c * CLEN + t4);
  const size_t ob = ((size_t)((bh * NCHUNK + c) * GG + g0)) * CS_STRIDE;
  float4 skv = *(const float4*)(pfx + ob + t4);
  float4 svv = *(const float4*)(pfx + ob + 64 + t4);
  float npr = 0.f;
  if (tid < 16)
    npr = pfx[((size_t)((bh * NCHUNK + c) * GG + tid)) * CS_STRIDE + 128];

#pragma unroll
  for (int i = 0; i < 4; ++i) {
    const float* pq = (const float*)&qv[i];
    const float* pk = (const float*)&kv[i];
#pragma unroll
    for (int e = 0; e < 4; ++e) {
      int col = c16 + i * 4 + e;
      short hi, lo;
      bsplit(pq[e], hi, lo);
      qh[row * LDW + col] = hi;
      qlo[row * LDW + col] = lo;
      khb[row * LDW + col] = f2bf(pk[e]);
    }
  }
  {
    const float* pw = (const float*)&wv4;
    const float* ps = (const float*)&skv;
#pragma unroll
    for (int e = 0; e < 4; ++e) {
      short hi, lo;
      bsplit(expf(pw[e] - mean), hi, lo);
      whb[g0 * LDW + t4 + e] = hi;
      wlb[g0 * LDW + t4 + e] = lo;
      bsplit(ps[e], hi, lo);
      skph[g0 * LDW + t4 + e] = hi;
      skpl[g0 * LDW + t4 + e] = lo;
    }
  }
  if (tid < 16) npreL[tid] = npr;
  __syncthreads();  // B0

  {
    int s_ = tid & 63, gq = tid >> 6;
#pragma unroll
    for (int gg = 0; gg < 4; ++gg) {
      int g = gq * 4 + gg;
      float acc = npreL[g];
      for (int t = 0; t <= s_; ++t)
        acc += bf2f(whb[g * LDW + t]) + bf2f(wlb[g * LDW + t]);
      nL[g * 68 + s_] = acc;
    }
  }

  f32x4 accd[4];
  f32x4 accwt = {0.f, 0.f, 0.f, 0.f};
#pragma unroll
  for (int ct = 0; ct < 4; ++ct) accd[ct] = accwt;
#pragma unroll
  for (int kst = 0; kst < 2; ++kst) {
    bf16x8 aq = *(const bf16x8*)(&qh[(sw + r) * LDW + kst * 32 + q * 8]);
    bf16x8 aql = *(const bf16x8*)(&qlo[(sw + r) * LDW + kst * 32 + q * 8]);
    bf16x8 bsh = *(const bf16x8*)(&skph[r * LDW + kst * 32 + q * 8]);
    bf16x8 bsl = *(const bf16x8*)(&skpl[r * LDW + kst * 32 + q * 8]);
    accwt = __builtin_amdgcn_mfma_f32_16x16x32_bf16(aq, bsh, accwt, 0, 0, 0);
    accwt = __builtin_amdgcn_mfma_f32_16x16x32_bf16(aq, bsl, accwt, 0, 0, 0);
    accwt = __builtin_amdgcn_mfma_f32_16x16x32_bf16(aql, bsh, accwt, 0, 0, 0);
#pragma unroll
    for (int ct = 0; ct < 4; ++ct) {
      bf16x8 bk = *(const bf16x8*)(&khb[(ct * 16 + r) * LDW + kst * 32 + q * 8]);
      accd[ct] = __builtin_amdgcn_mfma_f32_16x16x32_bf16(aq, bk, accd[ct], 0, 0, 0);
    }
  }
#pragma unroll
  for (int ct = 0; ct < 4; ++ct)
#pragma unroll
    for (int reg = 0; reg < 4; ++reg) {
      int sl = sw + q * 4 + reg, tl = ct * 16 + r;
      float v = (tl <= sl) ? accd[ct][reg] : 0.f;
      dh[sl * LDW + tl] = f2bf(v);
    }
  __syncthreads();  // B1

#pragma unroll
  for (int i = 0; i < 4; ++i) {
    const float* pv = (const float*)&vv[i];
#pragma unroll
    for (int e = 0; e < 4; ++e)
      vt[(c16 + i * 4 + e) * LDW + row] = f2bf(pv[e]);
  }
  {
    const float* pv = (const float*)&svv;
#pragma unroll
    for (int e = 0; e < 4; ++e)
      svpt[(t4 + e) * LDN + g0] = f2bf(pv[e]);
    int ez = tid >> 2, gz = 16 + (tid & 3) * 4;
#pragma unroll
    for (int e = 0; e < 4; ++e) svpt[ez * LDN + gz + e] = 0;
    int tt = tid >> 2, gw = (tid & 3) * 4;
#pragma unroll
    for (int e = 0; e < 4; ++e) {
      wct[tt * LDN + gw + e] = whb[(gw + e) * LDW + tt];
      wct[tt * LDN + 16 + gw + e] = 0;
    }
  }

#pragma unroll
  for (int kst = 0; kst < 2; ++kst) {
    bf16x8 ad = *(const bf16x8*)(&dh[(sw + r) * LDW + kst * 32 + q * 8]);
    bf16x8 bw = *(const bf16x8*)(&whb[r * LDW + kst * 32 + q * 8]);
    bf16x8 bl = *(const bf16x8*)(&wlb[r * LDW + kst * 32 + q * 8]);
    accwt = __builtin_amdgcn_mfma_f32_16x16x32_bf16(ad, bw, accwt, 0, 0, 0);
    accwt = __builtin_amdgcn_mfma_f32_16x16x32_bf16(ad, bl, accwt, 0, 0, 0);
  }
#pragma unroll
  for (int reg = 0; reg < 4; ++reg) {
    int sl = sw + q * 4 + reg;
    float nv = fmaxf(nL[r * 68 + sl], 1e-8f);
    float wt = accwt[reg] / nv;
    float m = wt;
    m = fmaxf(m, __shfl_xor(m, 1));
    m = fmaxf(m, __shfl_xor(m, 2));
    m = fmaxf(m, __shfl_xor(m, 4));
    m = fmaxf(m, __shfl_xor(m, 8));
    float ex = expf(wt - m);
    float den = ex;
    den += __shfl_xor(den, 1);
    den += __shfl_xor(den, 2);
    den += __shfl_xor(den, 4);
    den += __shfl_xor(den, 8);
    float cmv = (ex / den) / nv;
    cmb[sl * LDN + r] = f2bf(cmv);
    cmb[sl * LDN + 16 + r] = 0;
  }
  __syncthreads();  // B2

  bf16x8 acm = *(const bf16x8*)(&cmb[(sw + r) * LDN + q * 8]);
  f32x4 accu[4];
#pragma unroll
  for (int ct = 0; ct < 4; ++ct) accu[ct] = (f32x4){0.f, 0.f, 0.f, 0.f};
#pragma unroll
  for (int ct = 0; ct < 4; ++ct) {
    bf16x8 bwc = *(const bf16x8*)(&wct[(ct * 16 + r) * LDN + q * 8]);
    accu[ct] = __builtin_amdgcn_mfma_f32_16x16x32_bf16(acm, bwc, accu[ct], 0, 0, 0);
  }
#pragma unroll
  for (int ct = 0; ct < 4; ++ct)
#pragma unroll
    for (int reg = 0; reg < 4; ++reg) {
      int sl = sw + q * 4 + reg, tl = ct * 16 + r;
      float v = (tl <= sl) ? accu[ct][reg] : 0.f;
      uh[sl * LDW + tl] = f2bf(v);
    }

  f32x4 acco[4];
#pragma unroll
  for (int et = 0; et < 4; ++et) acco[et] = (f32x4){0.f, 0.f, 0.f, 0.f};
#pragma unroll
  for (int et = 0; et < 4; ++et) {
    bf16x8 bs = *(const bf16x8*)(&svpt[(et * 16 + r) * LDN + q * 8]);
    acco[et] = __builtin_amdgcn_mfma_f32_16x16x32_bf16(acm, bs, acco[et], 0, 0, 0);
  }
#pragma unroll
  for (int kst = 0; kst < 2; ++kst) {
    bf16x8 au = *(const bf16x8*)(&uh[(sw + r) * LDW + kst * 32 + q * 8]);
#pragma unroll
    for (int et = 0; et < 4; ++et) {
      bf16x8 bv = *(const bf16x8*)(&vt[(et * 16 + r) * LDW + kst * 32 + q * 8]);
      acco[et] = __builtin_amdgcn_mfma_f32_16x16x32_bf16(au, bv, acco[et], 0, 0, 0);
    }
  }
#pragma unroll
  for (int et = 0; et < 4; ++et)
#pragma unroll
    for (int reg = 0; reg < 4; ++reg) {
      int sl = sw + q * 4 + reg;
      attnbf[((size_t)(b * SS + c * CLEN + sl)) * DD + h * EE + et * 16 + r] =
          f2bf(acco[et][reg]);
    }
}

extern "C" void kernel_launch(void* const* d_in, const int* in_sizes, int n_in,
                              void* d_out, int out_size, void* d_ws, size_t ws_size,
                              hipStream_t stream) {
  const float* query = (const float*)d_in[0];
  const float* key = (const float*)d_in[1];
  const float* value = (const float*)d_in[2];
  const float* context = (const float*)d_in[3];
  const float* query_proj = (const float*)d_in[4];
  const float* key_proj = (const float*)d_in[5];
  const float* value_proj = (const float*)d_in[6];
  const float* output_proj = (const float*)d_in[7];
  const float* context_proj = (const float*)d_in[8];
  float* out = (float*)d_out;

  char* ws = (char*)d_ws;
  double* sumbuf = (double*)ws;  // 16 B reserved
  float* fbase = (float*)(ws + 16);
  const size_t MS = (size_t)BB * SS * DD;  // 2M
  float* qs_t = fbase;
  float* kk_t = qs_t + MS;
  float* vs_t = kk_t + MS;
  float* cs_t = vs_t + MS;                          // 32*512
  float* wbuf = cs_t + (size_t)BB * GG * DD;        // 524288 (raw scores)
  float* csums = wbuf + (size_t)BB * HH * GG * SS;  // 8192*132
  float* pfx = csums + (size_t)BB * HH * NCHUNK * GG * CS_STRIDE;
  float* part = pfx + (size_t)BB * HH * NCHUNK * GG * CS_STRIDE;  // 8*32*512
  short* Abf = (short*)(part + (size_t)8 * 32 * DD);  // attn bf16
  short* Wq = Abf + MS;
  short* Wk = Wq + (size_t)DD * DD;
  short* Wv = Wk + (size_t)DD * DD;
  short* Wo = Wv + (size_t)DD * DD;

  hipMemsetAsync(sumbuf, 0, sizeof(double), stream);

  dim3 blk(256);
  dim3 tb(32, 8), tg4(DD / 32, DD / 32, 4);

  cvtT4_bf16<<<tg4, tb, 0, stream>>>(query_proj, key_proj, value_proj, output_proj,
                                     Wq, Wk, Wv, Wo);
  ctx_gemm<<<dim3(8, 8), blk, 0, stream>>>(context, context_proj, part);
  ctx_reduce<<<dim3(BB * GG * DD / 256), blk, 0, stream>>>(part, cs_t);

  proj_gemm<<<dim3(DD / 64, (BB * SS) / 64, 3), blk, 0, stream>>>(
      query, key, value, Wq, Wk, Wv, qs_t, kk_t, vs_t);

  dim3 gsc(SS / 128, BB * HH);
  scores_kernel<<<gsc, blk, 0, stream>>>(kk_t, cs_t, wbuf, sumbuf);

  dim3 gscan(NCHUNK, BB * HH);
  scanA_kernel<<<gscan, blk, 0, stream>>>(wbuf, kk_t, vs_t, sumbuf, csums);
  scanB_kernel<<<dim3(BB * HH), blk, 0, stream>>>(csums, pfx);
  chunk_kernel<<<gscan, blk, 0, stream>>>(wbuf, kk_t, vs_t, qs_t, pfx, sumbuf, Abf);

  gemm_bf16<<<dim3(DD / 64, (BB * SS) / 64), blk, 0, stream>>>(Abf, Wo, out, BB * SS, DD, DD);
}

// Round 6
// 165.915 us; speedup vs baseline: 3.2218x; 1.0952x over previous
//
#include <hip/hip_runtime.h>
#include <hip/hip_bf16.h>

// Problem constants
#define BB 2
#define SS 2048
#define GG 16
#define HH 8
#define EE 64
#define DD 512
#define NCHUNK 32
#define CLEN 64
#define CS_STRIDE 132  // 64 sk + 64 sv + 1 n + 3 pad

typedef __attribute__((ext_vector_type(8))) short bf16x8;
typedef __attribute__((ext_vector_type(4))) float f32x4;

static __device__ __forceinline__ short f2bf(float x) {
  union { float f; unsigned u; } v; v.f = x;
  unsigned r = v.u + 0x7fffu + ((v.u >> 16) & 1u);  // round-nearest-even
  return (short)(r >> 16);
}
static __device__ __forceinline__ float bf2f(short s) {
  return __uint_as_float(((unsigned)(unsigned short)s) << 16);
}
static __device__ __forceinline__ void bsplit(float x, short& hi, short& lo) {
  hi = f2bf(x);
  lo = f2bf(x - bf2f(hi));
}

// ------- 4 weights f32[K][N] -> bf16 transposed [N][K] in one launch -------
__global__ __launch_bounds__(256) void cvtT4_bf16(const float* __restrict__ w0,
                                                  const float* __restrict__ w1,
                                                  const float* __restrict__ w2,
                                                  const float* __restrict__ w3,
                                                  short* __restrict__ o0,
                                                  short* __restrict__ o1,
                                                  short* __restrict__ o2,
                                                  short* __restrict__ o3) {
  const float* W; short* O;
  if (blockIdx.z == 0)      { W = w0; O = o0; }
  else if (blockIdx.z == 1) { W = w1; O = o1; }
  else if (blockIdx.z == 2) { W = w2; O = o2; }
  else                      { W = w3; O = o3; }
  __shared__ float t[32][33];
  const int tx = threadIdx.x, ty = threadIdx.y;
  const int k0 = blockIdx.x * 32, n0 = blockIdx.y * 32;
#pragma unroll
  for (int i = 0; i < 4; ++i)
    t[ty + i * 8][tx] = W[(size_t)(k0 + ty + i * 8) * DD + n0 + tx];
  __syncthreads();
#pragma unroll
  for (int i = 0; i < 4; ++i)
    O[(size_t)(n0 + ty + i * 8) * DD + k0 + tx] = f2bf(t[tx][ty + i * 8]);
}

// ---- batched projection GEMM: C[M,N] = cvt_bf16(A_f32[M,K]) @ Bt[N,K]^T ----
// 128x64 tile, BK=64; blockIdx.z selects (A,Bt,C) triple.
#define LDA 72
__global__ __launch_bounds__(256) void proj_gemm(const float* __restrict__ a0,
                                                 const float* __restrict__ a1,
                                                 const float* __restrict__ a2,
                                                 const short* __restrict__ b0,
                                                 const short* __restrict__ b1,
                                                 const short* __restrict__ b2,
                                                 float* __restrict__ c0,
                                                 float* __restrict__ c1,
                                                 float* __restrict__ c2) {
  const float* A; const short* Bt; float* C;
  if (blockIdx.z == 0)      { A = a0; Bt = b0; C = c0; }
  else if (blockIdx.z == 1) { A = a1; Bt = b1; C = c1; }
  else                      { A = a2; Bt = b2; C = c2; }
  const int N = DD, K = DD;
  __shared__ short As[128 * LDA];
  __shared__ short Bs[64 * LDA];
  const int tid = threadIdx.x;
  const int m0 = blockIdx.y * 128, n0 = blockIdx.x * 64;
  const int wv = tid >> 6, lane = tid & 63;
  const int wm = wv * 32;
  const int r = lane & 15, q = lane >> 4;
  f32x4 acc[2][4] = {};
  for (int k0 = 0; k0 < K; k0 += 64) {
    float4 af[4][2];
    bf16x8 bvv[2];
#pragma unroll
    for (int it = 0; it < 4; ++it) {
      int idx = tid + it * 256;
      int row = idx >> 3, colq = (idx & 7) * 8;
      af[it][0] = *(const float4*)(A + (size_t)(m0 + row) * K + k0 + colq);
      af[it][1] = *(const float4*)(A + (size_t)(m0 + row) * K + k0 + colq + 4);
    }
#pragma unroll
    for (int it = 0; it < 2; ++it) {
      int idx = tid + it * 256;
      int row = idx >> 3, colq = (idx & 7) * 8;
      bvv[it] = *(const bf16x8*)(Bt + (size_t)(n0 + row) * K + k0 + colq);
    }
    __syncthreads();
#pragma unroll
    for (int it = 0; it < 4; ++it) {
      int idx = tid + it * 256;
      int row = idx >> 3, colq = (idx & 7) * 8;
      bf16x8 av;
      const float* p0 = (const float*)&af[it][0];
      const float* p1 = (const float*)&af[it][1];
      av[0] = f2bf(p0[0]); av[1] = f2bf(p0[1]); av[2] = f2bf(p0[2]); av[3] = f2bf(p0[3]);
      av[4] = f2bf(p1[0]); av[5] = f2bf(p1[1]); av[6] = f2bf(p1[2]); av[7] = f2bf(p1[3]);
      *(bf16x8*)(&As[row * LDA + colq]) = av;
    }
#pragma unroll
    for (int it = 0; it < 2; ++it) {
      int idx = tid + it * 256;
      int row = idx >> 3, colq = (idx & 7) * 8;
      *(bf16x8*)(&Bs[row * LDA + colq]) = bvv[it];
    }
    __syncthreads();
#pragma unroll
    for (int ks = 0; ks < 2; ++ks) {
      bf16x8 a0r = *(const bf16x8*)(&As[(wm + r) * LDA + ks * 32 + q * 8]);
      bf16x8 a1r = *(const bf16x8*)(&As[(wm + 16 + r) * LDA + ks * 32 + q * 8]);
#pragma unroll
      for (int j = 0; j < 4; ++j) {
        bf16x8 br = *(const bf16x8*)(&Bs[(j * 16 + r) * LDA + ks * 32 + q * 8]);
        acc[0][j] = __builtin_amdgcn_mfma_f32_16x16x32_bf16(a0r, br, acc[0][j], 0, 0, 0);
        acc[1][j] = __builtin_amdgcn_mfma_f32_16x16x32_bf16(a1r, br, acc[1][j], 0, 0, 0);
      }
    }
  }
#pragma unroll
  for (int i = 0; i < 2; ++i)
#pragma unroll
    for (int j = 0; j < 4; ++j)
#pragma unroll
      for (int reg = 0; reg < 4; ++reg) {
        int m = m0 + wm + i * 16 + q * 4 + reg;
        int n = n0 + j * 16 + r;
        C[(size_t)m * N + n] = acc[i][j][reg];
      }
}

// ---------------- bf16 MFMA GEMM (bf16 A), 128x64 tile, BK=64 ----------------
__global__ __launch_bounds__(256) void gemm_bf16(const short* __restrict__ A,
                                                 const short* __restrict__ Bt,
                                                 float* __restrict__ C,
                                                 int M, int N, int K) {
  __shared__ short As[128 * LDA];
  __shared__ short Bs[64 * LDA];
  const int tid = threadIdx.x;
  const int m0 = blockIdx.y * 128, n0 = blockIdx.x * 64;
  const int wv = tid >> 6, lane = tid & 63;
  const int wm = wv * 32;
  const int r = lane & 15, q = lane >> 4;
  f32x4 acc[2][4] = {};
  for (int k0 = 0; k0 < K; k0 += 64) {
    bf16x8 av[4], bvv[2];
#pragma unroll
    for (int it = 0; it < 4; ++it) {
      int idx = tid + it * 256;
      int row = idx >> 3, colq = (idx & 7) * 8;
      av[it] = *(const bf16x8*)(A + (size_t)(m0 + row) * K + k0 + colq);
    }
#pragma unroll
    for (int it = 0; it < 2; ++it) {
      int idx = tid + it * 256;
      int row = idx >> 3, colq = (idx & 7) * 8;
      bvv[it] = *(const bf16x8*)(Bt + (size_t)(n0 + row) * K + k0 + colq);
    }
    __syncthreads();
#pragma unroll
    for (int it = 0; it < 4; ++it) {
      int idx = tid + it * 256;
      int row = idx >> 3, colq = (idx & 7) * 8;
      *(bf16x8*)(&As[row * LDA + colq]) = av[it];
    }
#pragma unroll
    for (int it = 0; it < 2; ++it) {
      int idx = tid + it * 256;
      int row = idx >> 3, colq = (idx & 7) * 8;
      *(bf16x8*)(&Bs[row * LDA + colq]) = bvv[it];
    }
    __syncthreads();
#pragma unroll
    for (int ks = 0; ks < 2; ++ks) {
      bf16x8 a0r = *(const bf16x8*)(&As[(wm + r) * LDA + ks * 32 + q * 8]);
      bf16x8 a1r = *(const bf16x8*)(&As[(wm + 16 + r) * LDA + ks * 32 + q * 8]);
#pragma unroll
      for (int j = 0; j < 4; ++j) {
        bf16x8 br = *(const bf16x8*)(&Bs[(j * 16 + r) * LDA + ks * 32 + q * 8]);
        acc[0][j] = __builtin_amdgcn_mfma_f32_16x16x32_bf16(a0r, br, acc[0][j], 0, 0, 0);
        acc[1][j] = __builtin_amdgcn_mfma_f32_16x16x32_bf16(a1r, br, acc[1][j], 0, 0, 0);
      }
    }
  }
#pragma unroll
  for (int i = 0; i < 2; ++i)
#pragma unroll
    for (int j = 0; j < 4; ++j)
#pragma unroll
      for (int reg = 0; reg < 4; ++reg) {
        int m = m0 + wm + i * 16 + q * 4 + reg;
        int n = n0 + j * 16 + r;
        C[(size_t)m * N + n] = acc[i][j][reg];
      }
}

// ------- context proj, split-K f32 -------
__global__ __launch_bounds__(256) void ctx_gemm(const float* __restrict__ A,
                                                const float* __restrict__ Wm,
                                                float* __restrict__ part) {
  const int nt = blockIdx.x;
  const int ky = blockIdx.y;
  const int tid = threadIdx.x;
  __shared__ float As[32][68];
  __shared__ float Ws[64][68];
  {
    int m = tid >> 3, kq = (tid & 7) * 8;
    float4 a0 = *(const float4*)(A + (size_t)m * DD + ky * 64 + kq);
    float4 a1 = *(const float4*)(A + (size_t)m * DD + ky * 64 + kq + 4);
    As[m][kq + 0] = a0.x; As[m][kq + 1] = a0.y; As[m][kq + 2] = a0.z; As[m][kq + 3] = a0.w;
    As[m][kq + 4] = a1.x; As[m][kq + 5] = a1.y; As[m][kq + 6] = a1.z; As[m][kq + 7] = a1.w;
  }
  {
    int k = tid >> 2, nq = (tid & 3) * 16;
#pragma unroll
    for (int i = 0; i < 4; ++i) {
      float4 wv = *(const float4*)(Wm + (size_t)(ky * 64 + k) * DD + nt * 64 + nq + i * 4);
      Ws[k][nq + i * 4 + 0] = wv.x; Ws[k][nq + i * 4 + 1] = wv.y;
      Ws[k][nq + i * 4 + 2] = wv.z; Ws[k][nq + i * 4 + 3] = wv.w;
    }
  }
  __syncthreads();
  const int tx = tid & 63, my = tid >> 6;
  float acc[8] = {};
  for (int k = 0; k < 64; ++k) {
    float wv = Ws[k][tx];
#pragma unroll
    for (int m = 0; m < 8; ++m) acc[m] += As[my * 8 + m][k] * wv;
  }
#pragma unroll
  for (int m = 0; m < 8; ++m)
    part[((size_t)ky * 32 + my * 8 + m) * DD + nt * 64 + tx] = acc[m];
}

__global__ __launch_bounds__(256) void ctx_reduce(const float* __restrict__ part,
                                                  float* __restrict__ cs) {
  int i = blockIdx.x * 256 + threadIdx.x;
  float s = 0.f;
#pragma unroll
  for (int ky = 0; ky < 8; ++ky) s += part[(size_t)ky * 32 * DD + i];
  cs[i] = s;
}

// ---------------- scores: w = exp(cs·kk / 8)  (mean algebraically cancels) ----------------
__global__ __launch_bounds__(256) void scores_kernel(const float* __restrict__ kk,
                                                     const float* __restrict__ cs,
                                                     float* __restrict__ wout) {
  const int bh = blockIdx.y;
  const int b = bh >> 3, h = bh & 7;
  const int s0 = blockIdx.x * 128;
  const int tid = threadIdx.x;
  __shared__ float csL[16][64];
  __shared__ float kkL[128][65];
#pragma unroll
  for (int it = 0; it < 4; ++it) {
    int idx = tid + it * 256;
    int g = idx >> 6, e = idx & 63;
    csL[g][e] = cs[((size_t)(b * GG + g)) * DD + h * EE + e];
  }
  for (int it = 0; it < 32; ++it) {
    int idx = tid + it * 256;
    int s = idx >> 6, e = idx & 63;
    kkL[s][e] = kk[((size_t)(b * SS + s0 + s)) * DD + h * EE + e];
  }
  __syncthreads();
#pragma unroll
  for (int i = 0; i < 8; ++i) {
    int o = i * 256 + tid;
    int g = o >> 7, s = o & 127;
    float d = 0.f;
#pragma unroll
    for (int e = 0; e < 64; ++e) d += csL[g][e] * kkL[s][e];
    wout[((size_t)(bh * GG + g)) * SS + s0 + s] = expf(d * 0.125f);
  }
}

// ---------------- scan phase A: chunk-local sums ----------------
__global__ __launch_bounds__(256) void scanA_kernel(const float* __restrict__ w,
                                                    const float* __restrict__ kk,
                                                    const float* __restrict__ vs,
                                                    float* __restrict__ csums) {
  const int bh = blockIdx.y, c = blockIdx.x;
  const int b = bh >> 3, h = bh & 7;
  const int tid = threadIdx.x;
  const int g = tid >> 4, j = tid & 15;
  __shared__ float wL[16][64];
#pragma unroll
  for (int it = 0; it < 4; ++it) {
    int idx = tid + it * 256;
    int gg = idx >> 6, t = idx & 63;
    wL[gg][t] = w[((size_t)(bh * GG + gg)) * SS + c * CLEN + t];
  }
  __syncthreads();
  float sk0 = 0, sk1 = 0, sk2 = 0, sk3 = 0;
  float sv0 = 0, sv1 = 0, sv2 = 0, sv3 = 0;
  float n = 0;
  for (int t = 0; t < CLEN; ++t) {
    float wg = wL[g][t];
    size_t base = ((size_t)(b * SS + c * CLEN + t)) * DD + h * EE + j * 4;
    float4 k4 = *(const float4*)(kk + base);
    float4 v4 = *(const float4*)(vs + base);
    sk0 += wg * k4.x; sk1 += wg * k4.y; sk2 += wg * k4.z; sk3 += wg * k4.w;
    sv0 += wg * v4.x; sv1 += wg * v4.y; sv2 += wg * v4.z; sv3 += wg * v4.w;
    n += wg;
  }
  size_t ob = ((size_t)((bh * NCHUNK + c) * GG + g)) * CS_STRIDE;
  *(float4*)(csums + ob + j * 4) = make_float4(sk0, sk1, sk2, sk3);
  *(float4*)(csums + ob + 64 + j * 4) = make_float4(sv0, sv1, sv2, sv3);
  if (j == 0) csums[ob + 128] = n;
}

// ---------------- chunk kernel: MFMA-based parallel causal attention ----------------
// Self-computes exclusive chunk prefix from csums (scanB folded in).
#define LDW 72
#define LDN 40
__global__ __launch_bounds__(256) void chunk_kernel(const float* __restrict__ w,
                                                    const float* __restrict__ kk,
                                                    const float* __restrict__ vs,
                                                    const float* __restrict__ qs,
                                                    const float* __restrict__ csums,
                                                    short* __restrict__ attnbf) {
  const int c = blockIdx.x, bh = blockIdx.y;
  const int b = bh >> 3, h = bh & 7;
  const int tid = threadIdx.x;
  const int lane = tid & 63, wvid = tid >> 6;
  const int r = lane & 15, q = lane >> 4;
  const int sw = wvid * 16;

  __shared__ short qh[64 * LDW], qlo[64 * LDW], khb[64 * LDW], dh[64 * LDW];
  __shared__ short whb[16 * LDW], wlb[16 * LDW], skph[16 * LDW], skpl[16 * LDW];
  __shared__ short svpt[64 * LDN];
  __shared__ float nL[16 * 68];
  __shared__ float npreL[16];
  short* wct = qh;   // reused post-B1
  short* cmb = qlo;  // reused post-B1
  short* vt = khb;   // reused post-B1
  short* uh = dh;    // reused post-phase3

  // ---- phase 0: global loads + exclusive chunk prefix ----
  const int row = tid >> 2, c16 = (tid & 3) * 16;
  const size_t gb = ((size_t)(b * SS + c * CLEN + row)) * DD + h * EE + c16;
  float4 qv[4], kv[4], vv[4];
#pragma unroll
  for (int i = 0; i < 4; ++i) {
    qv[i] = *(const float4*)(qs + gb + i * 4);
    kv[i] = *(const float4*)(kk + gb + i * 4);
    vv[i] = *(const float4*)(vs + gb + i * 4);
  }
  const int g0 = tid >> 4, t4 = (tid & 15) * 4;
  float4 wv4 = *(const float4*)(w + ((size_t)(bh * GG + g0)) * SS + c * CLEN + t4);

  float4 skv = make_float4(0, 0, 0, 0), svv = make_float4(0, 0, 0, 0);
  {
    int c2 = 0;
    for (; c2 + 4 <= c; c2 += 4) {
#pragma unroll
      for (int u = 0; u < 4; ++u) {
        size_t ob2 = ((size_t)((bh * NCHUNK + c2 + u) * GG + g0)) * CS_STRIDE;
        float4 a = *(const float4*)(csums + ob2 + t4);
        float4 bsum = *(const float4*)(csums + ob2 + 64 + t4);
        skv.x += a.x; skv.y += a.y; skv.z += a.z; skv.w += a.w;
        svv.x += bsum.x; svv.y += bsum.y; svv.z += bsum.z; svv.w += bsum.w;
      }
    }
    for (; c2 < c; ++c2) {
      size_t ob2 = ((size_t)((bh * NCHUNK + c2) * GG + g0)) * CS_STRIDE;
      float4 a = *(const float4*)(csums + ob2 + t4);
      float4 bsum = *(const float4*)(csums + ob2 + 64 + t4);
      skv.x += a.x; skv.y += a.y; skv.z += a.z; skv.w += a.w;
      svv.x += bsum.x; svv.y += bsum.y; svv.z += bsum.z; svv.w += bsum.w;
    }
  }
  if (tid < 16) {
    float npr = 0.f;
    for (int c2 = 0; c2 < c; ++c2)
      npr += csums[((size_t)((bh * NCHUNK + c2) * GG + tid)) * CS_STRIDE + 128];
    npreL[tid] = npr;
  }

#pragma unroll
  for (int i = 0; i < 4; ++i) {
    const float* pq = (const float*)&qv[i];
    const float* pk = (const float*)&kv[i];
#pragma unroll
    for (int e = 0; e < 4; ++e) {
      int col = c16 + i * 4 + e;
      short hi, lo;
      bsplit(pq[e], hi, lo);
      qh[row * LDW + col] = hi;
      qlo[row * LDW + col] = lo;
      khb[row * LDW + col] = f2bf(pk[e]);
    }
  }
  {
    const float* pw = (const float*)&wv4;
    const float* ps = (const float*)&skv;
#pragma unroll
    for (int e = 0; e < 4; ++e) {
      short hi, lo;
      bsplit(pw[e], hi, lo);
      whb[g0 * LDW + t4 + e] = hi;
      wlb[g0 * LDW + t4 + e] = lo;
      bsplit(ps[e], hi, lo);
      skph[g0 * LDW + t4 + e] = hi;
      skpl[g0 * LDW + t4 + e] = lo;
    }
  }
  __syncthreads();  // B0

  // ---- nL: n[g][s] = npre + inclusive cumsum of w, via wave shuffle scan ----
#pragma unroll
  for (int gg = 0; gg < 4; ++gg) {
    int g = wvid * 4 + gg;
    float val = bf2f(whb[g * LDW + lane]) + bf2f(wlb[g * LDW + lane]);
#pragma unroll
    for (int d = 1; d < 64; d <<= 1) {
      float tup = __shfl_up(val, d);
      if (lane >= d) val += tup;
    }
    nL[g * 68 + lane] = npreL[g] + val;
  }

  // ---- phase 2: dloc = Qc@Kc^T, accwt = Qc@Skp^T (hi/lo refined) ----
  f32x4 accd[4];
  f32x4 accwt = {0.f, 0.f, 0.f, 0.f};
#pragma unroll
  for (int ct = 0; ct < 4; ++ct) accd[ct] = accwt;
#pragma unroll
  for (int kst = 0; kst < 2; ++kst) {
    bf16x8 aq = *(const bf16x8*)(&qh[(sw + r) * LDW + kst * 32 + q * 8]);
    bf16x8 aql = *(const bf16x8*)(&qlo[(sw + r) * LDW + kst * 32 + q * 8]);
    bf16x8 bsh = *(const bf16x8*)(&skph[r * LDW + kst * 32 + q * 8]);
    bf16x8 bsl = *(const bf16x8*)(&skpl[r * LDW + kst * 32 + q * 8]);
    accwt = __builtin_amdgcn_mfma_f32_16x16x32_bf16(aq, bsh, accwt, 0, 0, 0);
    accwt = __builtin_amdgcn_mfma_f32_16x16x32_bf16(aq, bsl, accwt, 0, 0, 0);
    accwt = __builtin_amdgcn_mfma_f32_16x16x32_bf16(aql, bsh, accwt, 0, 0, 0);
#pragma unroll
    for (int ct = 0; ct < 4; ++ct) {
      bf16x8 bk = *(const bf16x8*)(&khb[(ct * 16 + r) * LDW + kst * 32 + q * 8]);
      accd[ct] = __builtin_amdgcn_mfma_f32_16x16x32_bf16(aq, bk, accd[ct], 0, 0, 0);
    }
  }
#pragma unroll
  for (int ct = 0; ct < 4; ++ct)
#pragma unroll
    for (int reg = 0; reg < 4; ++reg) {
      int sl = sw + q * 4 + reg, tl = ct * 16 + r;
      float v = (tl <= sl) ? accd[ct][reg] : 0.f;
      dh[sl * LDW + tl] = f2bf(v);
    }
  __syncthreads();  // B1

  // ---- phase 2.5: repack vt, svpt, wct (+zero pads) ----
#pragma unroll
  for (int i = 0; i < 4; ++i) {
    const float* pv = (const float*)&vv[i];
#pragma unroll
    for (int e = 0; e < 4; ++e)
      vt[(c16 + i * 4 + e) * LDW + row] = f2bf(pv[e]);
  }
  {
    const float* pv = (const float*)&svv;
#pragma unroll
    for (int e = 0; e < 4; ++e)
      svpt[(t4 + e) * LDN + g0] = f2bf(pv[e]);
    int ez = tid >> 2, gz = 16 + (tid & 3) * 4;
#pragma unroll
    for (int e = 0; e < 4; ++e) svpt[ez * LDN + gz + e] = 0;
    int tt = tid >> 2, gw = (tid & 3) * 4;
#pragma unroll
    for (int e = 0; e < 4; ++e) {
      wct[tt * LDN + gw + e] = whb[(gw + e) * LDW + tt];
      wct[tt * LDN + 16 + gw + e] = 0;
    }
  }

  // ---- phase 3: accwt += tril(dloc)@Wc^T (w hi/lo), then softmax ----
#pragma unroll
  for (int kst = 0; kst < 2; ++kst) {
    bf16x8 ad = *(const bf16x8*)(&dh[(sw + r) * LDW + kst * 32 + q * 8]);
    bf16x8 bw = *(const bf16x8*)(&whb[r * LDW + kst * 32 + q * 8]);
    bf16x8 bl = *(const bf16x8*)(&wlb[r * LDW + kst * 32 + q * 8]);
    accwt = __builtin_amdgcn_mfma_f32_16x16x32_bf16(ad, bw, accwt, 0, 0, 0);
    accwt = __builtin_amdgcn_mfma_f32_16x16x32_bf16(ad, bl, accwt, 0, 0, 0);
  }
#pragma unroll
  for (int reg = 0; reg < 4; ++reg) {
    int sl = sw + q * 4 + reg;
    float nv = fmaxf(nL[r * 68 + sl], 1e-8f);
    float wt = accwt[reg] / nv;
    float m = wt;
    m = fmaxf(m, __shfl_xor(m, 1));
    m = fmaxf(m, __shfl_xor(m, 2));
    m = fmaxf(m, __shfl_xor(m, 4));
    m = fmaxf(m, __shfl_xor(m, 8));
    float ex = expf(wt - m);
    float den = ex;
    den += __shfl_xor(den, 1);
    den += __shfl_xor(den, 2);
    den += __shfl_xor(den, 4);
    den += __shfl_xor(den, 8);
    float cmv = (ex / den) / nv;
    cmb[sl * LDN + r] = f2bf(cmv);
    cmb[sl * LDN + 16 + r] = 0;
  }
  __syncthreads();  // B2

  // ---- phase 4: U = C@Wc, masked ----
  bf16x8 acm = *(const bf16x8*)(&cmb[(sw + r) * LDN + q * 8]);
  f32x4 accu[4];
#pragma unroll
  for (int ct = 0; ct < 4; ++ct) accu[ct] = (f32x4){0.f, 0.f, 0.f, 0.f};
#pragma unroll
  for (int ct = 0; ct < 4; ++ct) {
    bf16x8 bwc = *(const bf16x8*)(&wct[(ct * 16 + r) * LDN + q * 8]);
    accu[ct] = __builtin_amdgcn_mfma_f32_16x16x32_bf16(acm, bwc, accu[ct], 0, 0, 0);
  }
#pragma unroll
  for (int ct = 0; ct < 4; ++ct)
#pragma unroll
    for (int reg = 0; reg < 4; ++reg) {
      int sl = sw + q * 4 + reg, tl = ct * 16 + r;
      float v = (tl <= sl) ? accu[ct][reg] : 0.f;
      uh[sl * LDW + tl] = f2bf(v);
    }

  // ---- phase 5: out = C@Svp^T + tril(U)@Vc, store bf16 ----
  f32x4 acco[4];
#pragma unroll
  for (int et = 0; et < 4; ++et) acco[et] = (f32x4){0.f, 0.f, 0.f, 0.f};
#pragma unroll
  for (int et = 0; et < 4; ++et) {
    bf16x8 bs = *(const bf16x8*)(&svpt[(et * 16 + r) * LDN + q * 8]);
    acco[et] = __builtin_amdgcn_mfma_f32_16x16x32_bf16(acm, bs, acco[et], 0, 0, 0);
  }
#pragma unroll
  for (int kst = 0; kst < 2; ++kst) {
    bf16x8 au = *(const bf16x8*)(&uh[(sw + r) * LDW + kst * 32 + q * 8]);
#pragma unroll
    for (int et = 0; et < 4; ++et) {
      bf16x8 bv = *(const bf16x8*)(&vt[(et * 16 + r) * LDW + kst * 32 + q * 8]);
      acco[et] = __builtin_amdgcn_mfma_f32_16x16x32_bf16(au, bv, acco[et], 0, 0, 0);
    }
  }
#pragma unroll
  for (int et = 0; et < 4; ++et)
#pragma unroll
    for (int reg = 0; reg < 4; ++reg) {
      int sl = sw + q * 4 + reg;
      attnbf[((size_t)(b * SS + c * CLEN + sl)) * DD + h * EE + et * 16 + r] =
          f2bf(acco[et][reg]);
    }
}

extern "C" void kernel_launch(void* const* d_in, const int* in_sizes, int n_in,
                              void* d_out, int out_size, void* d_ws, size_t ws_size,
                              hipStream_t stream) {
  const float* query = (const float*)d_in[0];
  const float* key = (const float*)d_in[1];
  const float* value = (const float*)d_in[2];
  const float* context = (const float*)d_in[3];
  const float* query_proj = (const float*)d_in[4];
  const float* key_proj = (const float*)d_in[5];
  const float* value_proj = (const float*)d_in[6];
  const float* output_proj = (const float*)d_in[7];
  const float* context_proj = (const float*)d_in[8];
  float* out = (float*)d_out;

  float* fbase = (float*)d_ws;
  const size_t MS = (size_t)BB * SS * DD;  // 2M
  float* qs_t = fbase;
  float* kk_t = qs_t + MS;
  float* vs_t = kk_t + MS;
  float* cs_t = vs_t + MS;                          // 32*512
  float* wbuf = cs_t + (size_t)BB * GG * DD;        // 524288 (w = exp(scores))
  float* csums = wbuf + (size_t)BB * HH * GG * SS;  // 8192*132
  float* part = csums + (size_t)BB * HH * NCHUNK * GG * CS_STRIDE;  // 8*32*512
  short* Abf = (short*)(part + (size_t)8 * 32 * DD);  // attn bf16
  short* Wq = Abf + MS;
  short* Wk = Wq + (size_t)DD * DD;
  short* Wv = Wk + (size_t)DD * DD;
  short* Wo = Wv + (size_t)DD * DD;

  dim3 blk(256);
  dim3 tb(32, 8), tg4(DD / 32, DD / 32, 4);

  cvtT4_bf16<<<tg4, tb, 0, stream>>>(query_proj, key_proj, value_proj, output_proj,
                                     Wq, Wk, Wv, Wo);
  ctx_gemm<<<dim3(8, 8), blk, 0, stream>>>(context, context_proj, part);
  ctx_reduce<<<dim3(BB * GG * DD / 256), blk, 0, stream>>>(part, cs_t);

  proj_gemm<<<dim3(DD / 64, (BB * SS) / 128, 3), blk, 0, stream>>>(
      query, key, value, Wq, Wk, Wv, qs_t, kk_t, vs_t);

  dim3 gsc(SS / 128, BB * HH);
  scores_kernel<<<gsc, blk, 0, stream>>>(kk_t, cs_t, wbuf);

  dim3 gscan(NCHUNK, BB * HH);
  scanA_kernel<<<gscan, blk, 0, stream>>>(wbuf, kk_t, vs_t, csums);
  chunk_kernel<<<gscan, blk, 0, stream>>>(wbuf, kk_t, vs_t, qs_t, csums, Abf);

  gemm_bf16<<<dim3(DD / 64, (BB * SS) / 128), blk, 0, stream>>>(Abf, Wo, out, BB * SS, DD, DD);
}

// Round 7
// 157.372 us; speedup vs baseline: 3.3967x; 1.0543x over previous
//
#include <hip/hip_runtime.h>
#include <hip/hip_bf16.h>

// Problem constants
#define BB 2
#define SS 2048
#define GG 16
#define HH 8
#define EE 64
#define DD 512
#define NCHUNK 32
#define CLEN 64
#define CS_STRIDE 132  // 64 sk + 64 sv + 1 n + 3 pad

typedef __attribute__((ext_vector_type(8))) short bf16x8;
typedef __attribute__((ext_vector_type(4))) float f32x4;

static __device__ __forceinline__ short f2bf(float x) {
  union { float f; unsigned u; } v; v.f = x;
  unsigned r = v.u + 0x7fffu + ((v.u >> 16) & 1u);  // round-nearest-even
  return (short)(r >> 16);
}
static __device__ __forceinline__ float bf2f(short s) {
  return __uint_as_float(((unsigned)(unsigned short)s) << 16);
}
static __device__ __forceinline__ void bsplit(float x, short& hi, short& lo) {
  hi = f2bf(x);
  lo = f2bf(x - bf2f(hi));
}

// ------- 4 weights f32[K][N] -> bf16 transposed [N][K] in one launch -------
__global__ __launch_bounds__(256) void cvtT4_bf16(const float* __restrict__ w0,
                                                  const float* __restrict__ w1,
                                                  const float* __restrict__ w2,
                                                  const float* __restrict__ w3,
                                                  short* __restrict__ o0,
                                                  short* __restrict__ o1,
                                                  short* __restrict__ o2,
                                                  short* __restrict__ o3) {
  const float* W; short* O;
  if (blockIdx.z == 0)      { W = w0; O = o0; }
  else if (blockIdx.z == 1) { W = w1; O = o1; }
  else if (blockIdx.z == 2) { W = w2; O = o2; }
  else                      { W = w3; O = o3; }
  __shared__ float t[32][33];
  const int tx = threadIdx.x, ty = threadIdx.y;
  const int k0 = blockIdx.x * 32, n0 = blockIdx.y * 32;
#pragma unroll
  for (int i = 0; i < 4; ++i)
    t[ty + i * 8][tx] = W[(size_t)(k0 + ty + i * 8) * DD + n0 + tx];
  __syncthreads();
#pragma unroll
  for (int i = 0; i < 4; ++i)
    O[(size_t)(n0 + ty + i * 8) * DD + k0 + tx] = f2bf(t[tx][ty + i * 8]);
}

// ---- batched projection GEMM: C[M,N] = cvt_bf16(A_f32[M,K]) @ Bt[N,K]^T ----
#define LDA 72
__global__ __launch_bounds__(256) void proj_gemm(const float* __restrict__ a0,
                                                 const float* __restrict__ a1,
                                                 const float* __restrict__ a2,
                                                 const short* __restrict__ b0,
                                                 const short* __restrict__ b1,
                                                 const short* __restrict__ b2,
                                                 float* __restrict__ c0,
                                                 float* __restrict__ c1,
                                                 float* __restrict__ c2) {
  const float* A; const short* Bt; float* C;
  if (blockIdx.z == 0)      { A = a0; Bt = b0; C = c0; }
  else if (blockIdx.z == 1) { A = a1; Bt = b1; C = c1; }
  else                      { A = a2; Bt = b2; C = c2; }
  const int N = DD, K = DD;
  __shared__ short As[128 * LDA];
  __shared__ short Bs[64 * LDA];
  const int tid = threadIdx.x;
  const int m0 = blockIdx.y * 128, n0 = blockIdx.x * 64;
  const int wv = tid >> 6, lane = tid & 63;
  const int wm = wv * 32;
  const int r = lane & 15, q = lane >> 4;
  f32x4 acc[2][4] = {};
  for (int k0 = 0; k0 < K; k0 += 64) {
    float4 af[4][2];
    bf16x8 bvv[2];
#pragma unroll
    for (int it = 0; it < 4; ++it) {
      int idx = tid + it * 256;
      int row = idx >> 3, colq = (idx & 7) * 8;
      af[it][0] = *(const float4*)(A + (size_t)(m0 + row) * K + k0 + colq);
      af[it][1] = *(const float4*)(A + (size_t)(m0 + row) * K + k0 + colq + 4);
    }
#pragma unroll
    for (int it = 0; it < 2; ++it) {
      int idx = tid + it * 256;
      int row = idx >> 3, colq = (idx & 7) * 8;
      bvv[it] = *(const bf16x8*)(Bt + (size_t)(n0 + row) * K + k0 + colq);
    }
    __syncthreads();
#pragma unroll
    for (int it = 0; it < 4; ++it) {
      int idx = tid + it * 256;
      int row = idx >> 3, colq = (idx & 7) * 8;
      bf16x8 av;
      const float* p0 = (const float*)&af[it][0];
      const float* p1 = (const float*)&af[it][1];
      av[0] = f2bf(p0[0]); av[1] = f2bf(p0[1]); av[2] = f2bf(p0[2]); av[3] = f2bf(p0[3]);
      av[4] = f2bf(p1[0]); av[5] = f2bf(p1[1]); av[6] = f2bf(p1[2]); av[7] = f2bf(p1[3]);
      *(bf16x8*)(&As[row * LDA + colq]) = av;
    }
#pragma unroll
    for (int it = 0; it < 2; ++it) {
      int idx = tid + it * 256;
      int row = idx >> 3, colq = (idx & 7) * 8;
      *(bf16x8*)(&Bs[row * LDA + colq]) = bvv[it];
    }
    __syncthreads();
#pragma unroll
    for (int ks = 0; ks < 2; ++ks) {
      bf16x8 a0r = *(const bf16x8*)(&As[(wm + r) * LDA + ks * 32 + q * 8]);
      bf16x8 a1r = *(const bf16x8*)(&As[(wm + 16 + r) * LDA + ks * 32 + q * 8]);
#pragma unroll
      for (int j = 0; j < 4; ++j) {
        bf16x8 br = *(const bf16x8*)(&Bs[(j * 16 + r) * LDA + ks * 32 + q * 8]);
        acc[0][j] = __builtin_amdgcn_mfma_f32_16x16x32_bf16(a0r, br, acc[0][j], 0, 0, 0);
        acc[1][j] = __builtin_amdgcn_mfma_f32_16x16x32_bf16(a1r, br, acc[1][j], 0, 0, 0);
      }
    }
  }
#pragma unroll
  for (int i = 0; i < 2; ++i)
#pragma unroll
    for (int j = 0; j < 4; ++j)
#pragma unroll
      for (int reg = 0; reg < 4; ++reg) {
        int m = m0 + wm + i * 16 + q * 4 + reg;
        int n = n0 + j * 16 + r;
        C[(size_t)m * N + n] = acc[i][j][reg];
      }
}

// ---------------- bf16 MFMA GEMM (bf16 A), 128x64 tile, BK=64 ----------------
__global__ __launch_bounds__(256) void gemm_bf16(const short* __restrict__ A,
                                                 const short* __restrict__ Bt,
                                                 float* __restrict__ C,
                                                 int M, int N, int K) {
  __shared__ short As[128 * LDA];
  __shared__ short Bs[64 * LDA];
  const int tid = threadIdx.x;
  const int m0 = blockIdx.y * 128, n0 = blockIdx.x * 64;
  const int wv = tid >> 6, lane = tid & 63;
  const int wm = wv * 32;
  const int r = lane & 15, q = lane >> 4;
  f32x4 acc[2][4] = {};
  for (int k0 = 0; k0 < K; k0 += 64) {
    bf16x8 av[4], bvv[2];
#pragma unroll
    for (int it = 0; it < 4; ++it) {
      int idx = tid + it * 256;
      int row = idx >> 3, colq = (idx & 7) * 8;
      av[it] = *(const bf16x8*)(A + (size_t)(m0 + row) * K + k0 + colq);
    }
#pragma unroll
    for (int it = 0; it < 2; ++it) {
      int idx = tid + it * 256;
      int row = idx >> 3, colq = (idx & 7) * 8;
      bvv[it] = *(const bf16x8*)(Bt + (size_t)(n0 + row) * K + k0 + colq);
    }
    __syncthreads();
#pragma unroll
    for (int it = 0; it < 4; ++it) {
      int idx = tid + it * 256;
      int row = idx >> 3, colq = (idx & 7) * 8;
      *(bf16x8*)(&As[row * LDA + colq]) = av[it];
    }
#pragma unroll
    for (int it = 0; it < 2; ++it) {
      int idx = tid + it * 256;
      int row = idx >> 3, colq = (idx & 7) * 8;
      *(bf16x8*)(&Bs[row * LDA + colq]) = bvv[it];
    }
    __syncthreads();
#pragma unroll
    for (int ks = 0; ks < 2; ++ks) {
      bf16x8 a0r = *(const bf16x8*)(&As[(wm + r) * LDA + ks * 32 + q * 8]);
      bf16x8 a1r = *(const bf16x8*)(&As[(wm + 16 + r) * LDA + ks * 32 + q * 8]);
#pragma unroll
      for (int j = 0; j < 4; ++j) {
        bf16x8 br = *(const bf16x8*)(&Bs[(j * 16 + r) * LDA + ks * 32 + q * 8]);
        acc[0][j] = __builtin_amdgcn_mfma_f32_16x16x32_bf16(a0r, br, acc[0][j], 0, 0, 0);
        acc[1][j] = __builtin_amdgcn_mfma_f32_16x16x32_bf16(a1r, br, acc[1][j], 0, 0, 0);
      }
    }
  }
#pragma unroll
  for (int i = 0; i < 2; ++i)
#pragma unroll
    for (int j = 0; j < 4; ++j)
#pragma unroll
      for (int reg = 0; reg < 4; ++reg) {
        int m = m0 + wm + i * 16 + q * 4 + reg;
        int n = n0 + j * 16 + r;
        C[(size_t)m * N + n] = acc[i][j][reg];
      }
}

// ------- context proj, split-K f32 -------
__global__ __launch_bounds__(256) void ctx_gemm(const float* __restrict__ A,
                                                const float* __restrict__ Wm,
                                                float* __restrict__ part) {
  const int nt = blockIdx.x;
  const int ky = blockIdx.y;
  const int tid = threadIdx.x;
  __shared__ float As[32][68];
  __shared__ float Ws[64][68];
  {
    int m = tid >> 3, kq = (tid & 7) * 8;
    float4 a0 = *(const float4*)(A + (size_t)m * DD + ky * 64 + kq);
    float4 a1 = *(const float4*)(A + (size_t)m * DD + ky * 64 + kq + 4);
    As[m][kq + 0] = a0.x; As[m][kq + 1] = a0.y; As[m][kq + 2] = a0.z; As[m][kq + 3] = a0.w;
    As[m][kq + 4] = a1.x; As[m][kq + 5] = a1.y; As[m][kq + 6] = a1.z; As[m][kq + 7] = a1.w;
  }
  {
    int k = tid >> 2, nq = (tid & 3) * 16;
#pragma unroll
    for (int i = 0; i < 4; ++i) {
      float4 wv = *(const float4*)(Wm + (size_t)(ky * 64 + k) * DD + nt * 64 + nq + i * 4);
      Ws[k][nq + i * 4 + 0] = wv.x; Ws[k][nq + i * 4 + 1] = wv.y;
      Ws[k][nq + i * 4 + 2] = wv.z; Ws[k][nq + i * 4 + 3] = wv.w;
    }
  }
  __syncthreads();
  const int tx = tid & 63, my = tid >> 6;
  float acc[8] = {};
  for (int k = 0; k < 64; ++k) {
    float wv = Ws[k][tx];
#pragma unroll
    for (int m = 0; m < 8; ++m) acc[m] += As[my * 8 + m][k] * wv;
  }
#pragma unroll
  for (int m = 0; m < 8; ++m)
    part[((size_t)ky * 32 + my * 8 + m) * DD + nt * 64 + tx] = acc[m];
}

__global__ __launch_bounds__(256) void ctx_reduce(const float* __restrict__ part,
                                                  float* __restrict__ cs) {
  int i = blockIdx.x * 256 + threadIdx.x;
  float s = 0.f;
#pragma unroll
  for (int ky = 0; ky < 8; ++ky) s += part[(size_t)ky * 32 * DD + i];
  cs[i] = s;
}

#define LDW 72
#define LDN 40

// ---------------- scan phase A: chunk-local sums via MFMA, w computed inline ----------------
// w[g][t] = exp((Cs@Kc^T)/8); Sk = W@Kc (hi/lo 3-combo); Sv = W@Vc; n = rowsum(w).
__global__ __launch_bounds__(256) void scanA_kernel(const float* __restrict__ kk,
                                                    const float* __restrict__ vs,
                                                    const float* __restrict__ cs,
                                                    float* __restrict__ csums) {
  const int bh = blockIdx.y, c = blockIdx.x;
  const int b = bh >> 3, h = bh & 7;
  const int tid = threadIdx.x;
  const int lane = tid & 63, wvid = tid >> 6;
  const int r = lane & 15, q = lane >> 4;

  __shared__ short csh[16 * LDW], csl[16 * LDW];
  __shared__ short kh[64 * LDW], kl[64 * LDW];
  __shared__ short kTh[64 * LDW], kTl[64 * LDW];
  __shared__ short vT[64 * LDW];
  __shared__ short wh[16 * LDW], wl[16 * LDW];
  __shared__ float nPart[4][16];

  // ---- stage k (row hi/lo + transposed hi/lo), v (transposed), cs (hi/lo) ----
  const int row = tid >> 2, c16 = (tid & 3) * 16;
  const size_t gb = ((size_t)(b * SS + c * CLEN + row)) * DD + h * EE + c16;
  float4 kv[4], vv[4];
#pragma unroll
  for (int i = 0; i < 4; ++i) {
    kv[i] = *(const float4*)(kk + gb + i * 4);
    vv[i] = *(const float4*)(vs + gb + i * 4);
  }
  short hiA[16], loA[16];
#pragma unroll
  for (int i = 0; i < 4; ++i) {
    const float* pk = (const float*)&kv[i];
#pragma unroll
    for (int e = 0; e < 4; ++e) bsplit(pk[e], hiA[i * 4 + e], loA[i * 4 + e]);
  }
  {
    bf16x8 p0, p1, p2, p3;
#pragma unroll
    for (int e = 0; e < 8; ++e) { p0[e] = hiA[e]; p1[e] = hiA[8 + e]; p2[e] = loA[e]; p3[e] = loA[8 + e]; }
    *(bf16x8*)(&kh[row * LDW + c16]) = p0;
    *(bf16x8*)(&kh[row * LDW + c16 + 8]) = p1;
    *(bf16x8*)(&kl[row * LDW + c16]) = p2;
    *(bf16x8*)(&kl[row * LDW + c16 + 8]) = p3;
  }
#pragma unroll
  for (int t = 0; t < 16; ++t) {
    kTh[(c16 + t) * LDW + row] = hiA[t];
    kTl[(c16 + t) * LDW + row] = loA[t];
  }
#pragma unroll
  for (int i = 0; i < 4; ++i) {
    const float* pv = (const float*)&vv[i];
#pragma unroll
    for (int e = 0; e < 4; ++e) vT[(c16 + i * 4 + e) * LDW + row] = f2bf(pv[e]);
  }
  {
    const int g0 = tid >> 4, t4 = (tid & 15) * 4;
    float4 csv = *(const float4*)(cs + ((size_t)(b * GG + g0)) * DD + h * EE + t4);
    const float* pc = (const float*)&csv;
#pragma unroll
    for (int e = 0; e < 4; ++e) {
      short hi, lo;
      bsplit(pc[e], hi, lo);
      csh[g0 * LDW + t4 + e] = hi;
      csl[g0 * LDW + t4 + e] = lo;
    }
  }
  __syncthreads();  // S0

  // ---- w-MFMA: wave wvid owns t-tile [wvid*16, +16) ----
  f32x4 accw = {0.f, 0.f, 0.f, 0.f};
#pragma unroll
  for (int ks = 0; ks < 2; ++ks) {
    bf16x8 ah = *(const bf16x8*)(&csh[r * LDW + ks * 32 + q * 8]);
    bf16x8 al = *(const bf16x8*)(&csl[r * LDW + ks * 32 + q * 8]);
    bf16x8 bh = *(const bf16x8*)(&kh[(wvid * 16 + r) * LDW + ks * 32 + q * 8]);
    bf16x8 bl = *(const bf16x8*)(&kl[(wvid * 16 + r) * LDW + ks * 32 + q * 8]);
    accw = __builtin_amdgcn_mfma_f32_16x16x32_bf16(ah, bh, accw, 0, 0, 0);
    accw = __builtin_amdgcn_mfma_f32_16x16x32_bf16(ah, bl, accw, 0, 0, 0);
    accw = __builtin_amdgcn_mfma_f32_16x16x32_bf16(al, bh, accw, 0, 0, 0);
  }
  float wf[4];
#pragma unroll
  for (int reg = 0; reg < 4; ++reg) {
    wf[reg] = expf(accw[reg] * 0.125f);
    short hi, lo;
    bsplit(wf[reg], hi, lo);
    int g = q * 4 + reg, t = wvid * 16 + r;
    wh[g * LDW + t] = hi;
    wl[g * LDW + t] = lo;
  }
  // n partial: reduce over r (t within tile) per g
#pragma unroll
  for (int reg = 0; reg < 4; ++reg) {
    float np = wf[reg];
    np += __shfl_xor(np, 1);
    np += __shfl_xor(np, 2);
    np += __shfl_xor(np, 4);
    np += __shfl_xor(np, 8);
    if (r == 0) nPart[wvid][q * 4 + reg] = np;
  }
  __syncthreads();  // S1

  // ---- Sk/Sv MFMA: wave wvid owns e-tile [wvid*16, +16) ----
  f32x4 ask = {0.f, 0.f, 0.f, 0.f}, asv = ask;
#pragma unroll
  for (int ks = 0; ks < 2; ++ks) {
    bf16x8 awh = *(const bf16x8*)(&wh[r * LDW + ks * 32 + q * 8]);
    bf16x8 awl = *(const bf16x8*)(&wl[r * LDW + ks * 32 + q * 8]);
    bf16x8 bkh = *(const bf16x8*)(&kTh[(wvid * 16 + r) * LDW + ks * 32 + q * 8]);
    bf16x8 bkl = *(const bf16x8*)(&kTl[(wvid * 16 + r) * LDW + ks * 32 + q * 8]);
    bf16x8 bv = *(const bf16x8*)(&vT[(wvid * 16 + r) * LDW + ks * 32 + q * 8]);
    ask = __builtin_amdgcn_mfma_f32_16x16x32_bf16(awh, bkh, ask, 0, 0, 0);
    ask = __builtin_amdgcn_mfma_f32_16x16x32_bf16(awh, bkl, ask, 0, 0, 0);
    ask = __builtin_amdgcn_mfma_f32_16x16x32_bf16(awl, bkh, ask, 0, 0, 0);
    asv = __builtin_amdgcn_mfma_f32_16x16x32_bf16(awh, bv, asv, 0, 0, 0);
    asv = __builtin_amdgcn_mfma_f32_16x16x32_bf16(awl, bv, asv, 0, 0, 0);
  }
#pragma unroll
  for (int reg = 0; reg < 4; ++reg) {
    int g = q * 4 + reg, e = wvid * 16 + r;
    size_t ob = ((size_t)((bh * NCHUNK + c) * GG + g)) * CS_STRIDE;
    csums[ob + e] = ask[reg];
    csums[ob + 64 + e] = asv[reg];
  }
  if (tid < 16) {
    size_t ob = ((size_t)((bh * NCHUNK + c) * GG + tid)) * CS_STRIDE;
    csums[ob + 128] = nPart[0][tid] + nPart[1][tid] + nPart[2][tid] + nPart[3][tid];
  }
}

// ---------------- chunk kernel: MFMA-based parallel causal attention ----------------
// Computes w inline (same MFMA sequence as scanA); self-computes exclusive chunk prefix.
__global__ __launch_bounds__(256) void chunk_kernel(const float* __restrict__ kk,
                                                    const float* __restrict__ vs,
                                                    const float* __restrict__ qs,
                                                    const float* __restrict__ cs,
                                                    const float* __restrict__ csums,
                                                    short* __restrict__ attnbf) {
  const int c = blockIdx.x, bh = blockIdx.y;
  const int b = bh >> 3, h = bh & 7;
  const int tid = threadIdx.x;
  const int lane = tid & 63, wvid = tid >> 6;
  const int r = lane & 15, q = lane >> 4;
  const int sw = wvid * 16;

  __shared__ short qh[64 * LDW], qlo[64 * LDW], khb[64 * LDW], klo[64 * LDW], dh[64 * LDW];
  __shared__ short whb[16 * LDW], wlb[16 * LDW], skph[16 * LDW], skpl[16 * LDW];
  __shared__ short cshb[16 * LDW], cslb[16 * LDW];
  __shared__ short svpt[64 * LDN];
  __shared__ float nL[16 * 68];
  __shared__ float npreL[16];
  short* wct = qh;   // reused post-B1
  short* cmb = qlo;  // reused post-B1
  short* vt = khb;   // reused post-B1
  short* uh = dh;    // reused post-phase3

  // ---- phase 0: global loads + exclusive chunk prefix ----
  const int row = tid >> 2, c16 = (tid & 3) * 16;
  const size_t gb = ((size_t)(b * SS + c * CLEN + row)) * DD + h * EE + c16;
  float4 qv[4], kv[4], vv[4];
#pragma unroll
  for (int i = 0; i < 4; ++i) {
    qv[i] = *(const float4*)(qs + gb + i * 4);
    kv[i] = *(const float4*)(kk + gb + i * 4);
    vv[i] = *(const float4*)(vs + gb + i * 4);
  }
  const int g0 = tid >> 4, t4 = (tid & 15) * 4;
  float4 csv = *(const float4*)(cs + ((size_t)(b * GG + g0)) * DD + h * EE + t4);

  float4 skv = make_float4(0, 0, 0, 0), svv = make_float4(0, 0, 0, 0);
  {
    int c2 = 0;
    for (; c2 + 4 <= c; c2 += 4) {
#pragma unroll
      for (int u = 0; u < 4; ++u) {
        size_t ob2 = ((size_t)((bh * NCHUNK + c2 + u) * GG + g0)) * CS_STRIDE;
        float4 a = *(const float4*)(csums + ob2 + t4);
        float4 bsum = *(const float4*)(csums + ob2 + 64 + t4);
        skv.x += a.x; skv.y += a.y; skv.z += a.z; skv.w += a.w;
        svv.x += bsum.x; svv.y += bsum.y; svv.z += bsum.z; svv.w += bsum.w;
      }
    }
    for (; c2 < c; ++c2) {
      size_t ob2 = ((size_t)((bh * NCHUNK + c2) * GG + g0)) * CS_STRIDE;
      float4 a = *(const float4*)(csums + ob2 + t4);
      float4 bsum = *(const float4*)(csums + ob2 + 64 + t4);
      skv.x += a.x; skv.y += a.y; skv.z += a.z; skv.w += a.w;
      svv.x += bsum.x; svv.y += bsum.y; svv.z += bsum.z; svv.w += bsum.w;
    }
  }
  if (tid < 16) {
    float npr = 0.f;
    for (int c2 = 0; c2 < c; ++c2)
      npr += csums[((size_t)((bh * NCHUNK + c2) * GG + tid)) * CS_STRIDE + 128];
    npreL[tid] = npr;
  }

#pragma unroll
  for (int i = 0; i < 4; ++i) {
    const float* pq = (const float*)&qv[i];
    const float* pk = (const float*)&kv[i];
#pragma unroll
    for (int e = 0; e < 4; ++e) {
      int col = c16 + i * 4 + e;
      short hi, lo;
      bsplit(pq[e], hi, lo);
      qh[row * LDW + col] = hi;
      qlo[row * LDW + col] = lo;
      bsplit(pk[e], hi, lo);
      khb[row * LDW + col] = hi;
      klo[row * LDW + col] = lo;
    }
  }
  {
    const float* pc = (const float*)&csv;
    const float* ps = (const float*)&skv;
#pragma unroll
    for (int e = 0; e < 4; ++e) {
      short hi, lo;
      bsplit(pc[e], hi, lo);
      cshb[g0 * LDW + t4 + e] = hi;
      cslb[g0 * LDW + t4 + e] = lo;
      bsplit(ps[e], hi, lo);
      skph[g0 * LDW + t4 + e] = hi;
      skpl[g0 * LDW + t4 + e] = lo;
    }
  }
  __syncthreads();  // S0

  // ---- w-MFMA (same sequence as scanA) ----
  {
    f32x4 accw = {0.f, 0.f, 0.f, 0.f};
#pragma unroll
    for (int ks = 0; ks < 2; ++ks) {
      bf16x8 ah = *(const bf16x8*)(&cshb[r * LDW + ks * 32 + q * 8]);
      bf16x8 al = *(const bf16x8*)(&cslb[r * LDW + ks * 32 + q * 8]);
      bf16x8 bh = *(const bf16x8*)(&khb[(sw + r) * LDW + ks * 32 + q * 8]);
      bf16x8 bl = *(const bf16x8*)(&klo[(sw + r) * LDW + ks * 32 + q * 8]);
      accw = __builtin_amdgcn_mfma_f32_16x16x32_bf16(ah, bh, accw, 0, 0, 0);
      accw = __builtin_amdgcn_mfma_f32_16x16x32_bf16(ah, bl, accw, 0, 0, 0);
      accw = __builtin_amdgcn_mfma_f32_16x16x32_bf16(al, bh, accw, 0, 0, 0);
    }
#pragma unroll
    for (int reg = 0; reg < 4; ++reg) {
      float wv = expf(accw[reg] * 0.125f);
      short hi, lo;
      bsplit(wv, hi, lo);
      int g = q * 4 + reg, t = sw + r;
      whb[g * LDW + t] = hi;
      wlb[g * LDW + t] = lo;
    }
  }
  __syncthreads();  // S0b

  // ---- nL: n[g][s] = npre + inclusive cumsum of w, via wave shuffle scan ----
#pragma unroll
  for (int gg = 0; gg < 4; ++gg) {
    int g = wvid * 4 + gg;
    float val = bf2f(whb[g * LDW + lane]) + bf2f(wlb[g * LDW + lane]);
#pragma unroll
    for (int d = 1; d < 64; d <<= 1) {
      float tup = __shfl_up(val, d);
      if (lane >= d) val += tup;
    }
    nL[g * 68 + lane] = npreL[g] + val;
  }

  // ---- phase 2: dloc = Qc@Kc^T, accwt = Qc@Skp^T (hi/lo refined) ----
  f32x4 accd[4];
  f32x4 accwt = {0.f, 0.f, 0.f, 0.f};
#pragma unroll
  for (int ct = 0; ct < 4; ++ct) accd[ct] = accwt;
#pragma unroll
  for (int kst = 0; kst < 2; ++kst) {
    bf16x8 aq = *(const bf16x8*)(&qh[(sw + r) * LDW + kst * 32 + q * 8]);
    bf16x8 aql = *(const bf16x8*)(&qlo[(sw + r) * LDW + kst * 32 + q * 8]);
    bf16x8 bsh = *(const bf16x8*)(&skph[r * LDW + kst * 32 + q * 8]);
    bf16x8 bsl = *(const bf16x8*)(&skpl[r * LDW + kst * 32 + q * 8]);
    accwt = __builtin_amdgcn_mfma_f32_16x16x32_bf16(aq, bsh, accwt, 0, 0, 0);
    accwt = __builtin_amdgcn_mfma_f32_16x16x32_bf16(aq, bsl, accwt, 0, 0, 0);
    accwt = __builtin_amdgcn_mfma_f32_16x16x32_bf16(aql, bsh, accwt, 0, 0, 0);
#pragma unroll
    for (int ct = 0; ct < 4; ++ct) {
      bf16x8 bk = *(const bf16x8*)(&khb[(ct * 16 + r) * LDW + kst * 32 + q * 8]);
      accd[ct] = __builtin_amdgcn_mfma_f32_16x16x32_bf16(aq, bk, accd[ct], 0, 0, 0);
    }
  }
#pragma unroll
  for (int ct = 0; ct < 4; ++ct)
#pragma unroll
    for (int reg = 0; reg < 4; ++reg) {
      int sl = sw + q * 4 + reg, tl = ct * 16 + r;
      float v = (tl <= sl) ? accd[ct][reg] : 0.f;
      dh[sl * LDW + tl] = f2bf(v);
    }
  __syncthreads();  // B1

  // ---- phase 2.5: repack vt, svpt, wct (+zero pads) ----
#pragma unroll
  for (int i = 0; i < 4; ++i) {
    const float* pv = (const float*)&vv[i];
#pragma unroll
    for (int e = 0; e < 4; ++e)
      vt[(c16 + i * 4 + e) * LDW + row] = f2bf(pv[e]);
  }
  {
    const float* pv = (const float*)&svv;
#pragma unroll
    for (int e = 0; e < 4; ++e)
      svpt[(t4 + e) * LDN + g0] = f2bf(pv[e]);
    int ez = tid >> 2, gz = 16 + (tid & 3) * 4;
#pragma unroll
    for (int e = 0; e < 4; ++e) svpt[ez * LDN + gz + e] = 0;
    int tt = tid >> 2, gw = (tid & 3) * 4;
#pragma unroll
    for (int e = 0; e < 4; ++e) {
      wct[tt * LDN + gw + e] = whb[(gw + e) * LDW + tt];
      wct[tt * LDN + 16 + gw + e] = 0;
    }
  }

  // ---- phase 3: accwt += tril(dloc)@Wc^T (w hi/lo), then softmax ----
#pragma unroll
  for (int kst = 0; kst < 2; ++kst) {
    bf16x8 ad = *(const bf16x8*)(&dh[(sw + r) * LDW + kst * 32 + q * 8]);
    bf16x8 bw = *(const bf16x8*)(&whb[r * LDW + kst * 32 + q * 8]);
    bf16x8 bl = *(const bf16x8*)(&wlb[r * LDW + kst * 32 + q * 8]);
    accwt = __builtin_amdgcn_mfma_f32_16x16x32_bf16(ad, bw, accwt, 0, 0, 0);
    accwt = __builtin_amdgcn_mfma_f32_16x16x32_bf16(ad, bl, accwt, 0, 0, 0);
  }
#pragma unroll
  for (int reg = 0; reg < 4; ++reg) {
    int sl = sw + q * 4 + reg;
    float nv = fmaxf(nL[r * 68 + sl], 1e-8f);
    float wt = accwt[reg] / nv;
    float m = wt;
    m = fmaxf(m, __shfl_xor(m, 1));
    m = fmaxf(m, __shfl_xor(m, 2));
    m = fmaxf(m, __shfl_xor(m, 4));
    m = fmaxf(m, __shfl_xor(m, 8));
    float ex = expf(wt - m);
    float den = ex;
    den += __shfl_xor(den, 1);
    den += __shfl_xor(den, 2);
    den += __shfl_xor(den, 4);
    den += __shfl_xor(den, 8);
    float cmv = (ex / den) / nv;
    cmb[sl * LDN + r] = f2bf(cmv);
    cmb[sl * LDN + 16 + r] = 0;
  }
  __syncthreads();  // B2

  // ---- phase 4: U = C@Wc, masked ----
  bf16x8 acm = *(const bf16x8*)(&cmb[(sw + r) * LDN + q * 8]);
  f32x4 accu[4];
#pragma unroll
  for (int ct = 0; ct < 4; ++ct) accu[ct] = (f32x4){0.f, 0.f, 0.f, 0.f};
#pragma unroll
  for (int ct = 0; ct < 4; ++ct) {
    bf16x8 bwc = *(const bf16x8*)(&wct[(ct * 16 + r) * LDN + q * 8]);
    accu[ct] = __builtin_amdgcn_mfma_f32_16x16x32_bf16(acm, bwc, accu[ct], 0, 0, 0);
  }
#pragma unroll
  for (int ct = 0; ct < 4; ++ct)
#pragma unroll
    for (int reg = 0; reg < 4; ++reg) {
      int sl = sw + q * 4 + reg, tl = ct * 16 + r;
      float v = (tl <= sl) ? accu[ct][reg] : 0.f;
      uh[sl * LDW + tl] = f2bf(v);
    }

  // ---- phase 5: out = C@Svp^T + tril(U)@Vc, store bf16 ----
  f32x4 acco[4];
#pragma unroll
  for (int et = 0; et < 4; ++et) acco[et] = (f32x4){0.f, 0.f, 0.f, 0.f};
#pragma unroll
  for (int et = 0; et < 4; ++et) {
    bf16x8 bs = *(const bf16x8*)(&svpt[(et * 16 + r) * LDN + q * 8]);
    acco[et] = __builtin_amdgcn_mfma_f32_16x16x32_bf16(acm, bs, acco[et], 0, 0, 0);
  }
#pragma unroll
  for (int kst = 0; kst < 2; ++kst) {
    bf16x8 au = *(const bf16x8*)(&uh[(sw + r) * LDW + kst * 32 + q * 8]);
#pragma unroll
    for (int et = 0; et < 4; ++et) {
      bf16x8 bv = *(const bf16x8*)(&vt[(et * 16 + r) * LDW + kst * 32 + q * 8]);
      acco[et] = __builtin_amdgcn_mfma_f32_16x16x32_bf16(au, bv, acco[et], 0, 0, 0);
    }
  }
#pragma unroll
  for (int et = 0; et < 4; ++et)
#pragma unroll
    for (int reg = 0; reg < 4; ++reg) {
      int sl = sw + q * 4 + reg;
      attnbf[((size_t)(b * SS + c * CLEN + sl)) * DD + h * EE + et * 16 + r] =
          f2bf(acco[et][reg]);
    }
}

extern "C" void kernel_launch(void* const* d_in, const int* in_sizes, int n_in,
                              void* d_out, int out_size, void* d_ws, size_t ws_size,
                              hipStream_t stream) {
  const float* query = (const float*)d_in[0];
  const float* key = (const float*)d_in[1];
  const float* value = (const float*)d_in[2];
  const float* context = (const float*)d_in[3];
  const float* query_proj = (const float*)d_in[4];
  const float* key_proj = (const float*)d_in[5];
  const float* value_proj = (const float*)d_in[6];
  const float* output_proj = (const float*)d_in[7];
  const float* context_proj = (const float*)d_in[8];
  float* out = (float*)d_out;

  float* fbase = (float*)d_ws;
  const size_t MS = (size_t)BB * SS * DD;  // 2M
  float* qs_t = fbase;
  float* kk_t = qs_t + MS;
  float* vs_t = kk_t + MS;
  float* cs_t = vs_t + MS;                          // 32*512
  float* csums = cs_t + (size_t)BB * GG * DD;       // 8192*132
  float* part = csums + (size_t)BB * HH * NCHUNK * GG * CS_STRIDE;  // 8*32*512
  short* Abf = (short*)(part + (size_t)8 * 32 * DD);  // attn bf16
  short* Wq = Abf + MS;
  short* Wk = Wq + (size_t)DD * DD;
  short* Wv = Wk + (size_t)DD * DD;
  short* Wo = Wv + (size_t)DD * DD;

  dim3 blk(256);
  dim3 tb(32, 8), tg4(DD / 32, DD / 32, 4);

  cvtT4_bf16<<<tg4, tb, 0, stream>>>(query_proj, key_proj, value_proj, output_proj,
                                     Wq, Wk, Wv, Wo);
  ctx_gemm<<<dim3(8, 8), blk, 0, stream>>>(context, context_proj, part);
  ctx_reduce<<<dim3(BB * GG * DD / 256), blk, 0, stream>>>(part, cs_t);

  proj_gemm<<<dim3(DD / 64, (BB * SS) / 128, 3), blk, 0, stream>>>(
      query, key, value, Wq, Wk, Wv, qs_t, kk_t, vs_t);

  dim3 gscan(NCHUNK, BB * HH);
  scanA_kernel<<<gscan, blk, 0, stream>>>(kk_t, vs_t, cs_t, csums);
  chunk_kernel<<<gscan, blk, 0, stream>>>(kk_t, vs_t, qs_t, cs_t, csums, Abf);

  gemm_bf16<<<dim3(DD / 64, (BB * SS) / 128), blk, 0, stream>>>(Abf, Wo, out, BB * SS, DD, DD);
}

// Round 8
// 147.369 us; speedup vs baseline: 3.6273x; 1.0679x over previous
//
#include <hip/hip_runtime.h>
#include <hip/hip_bf16.h>

// Problem constants
#define BB 2
#define SS 2048
#define GG 16
#define HH 8
#define EE 64
#define DD 512
#define NCHUNK 32
#define CLEN 64
#define CS_STRIDE 132  // 64 sk + 64 sv + 1 n + 3 pad

typedef __attribute__((ext_vector_type(8))) short bf16x8;
typedef __attribute__((ext_vector_type(4))) float f32x4;

static __device__ __forceinline__ short f2bf(float x) {
  union { float f; unsigned u; } v; v.f = x;
  unsigned r = v.u + 0x7fffu + ((v.u >> 16) & 1u);  // round-nearest-even
  return (short)(r >> 16);
}
static __device__ __forceinline__ float bf2f(short s) {
  return __uint_as_float(((unsigned)(unsigned short)s) << 16);
}
static __device__ __forceinline__ void bsplit(float x, short& hi, short& lo) {
  hi = f2bf(x);
  lo = f2bf(x - bf2f(hi));
}

// ------- 4 weights f32[K][N] -> bf16 transposed [N][K] in one launch -------
__global__ __launch_bounds__(256) void cvtT4_bf16(const float* __restrict__ w0,
                                                  const float* __restrict__ w1,
                                                  const float* __restrict__ w2,
                                                  const float* __restrict__ w3,
                                                  short* __restrict__ o0,
                                                  short* __restrict__ o1,
                                                  short* __restrict__ o2,
                                                  short* __restrict__ o3) {
  const float* W; short* O;
  if (blockIdx.z == 0)      { W = w0; O = o0; }
  else if (blockIdx.z == 1) { W = w1; O = o1; }
  else if (blockIdx.z == 2) { W = w2; O = o2; }
  else                      { W = w3; O = o3; }
  __shared__ float t[32][33];
  const int tx = threadIdx.x, ty = threadIdx.y;
  const int k0 = blockIdx.x * 32, n0 = blockIdx.y * 32;
#pragma unroll
  for (int i = 0; i < 4; ++i)
    t[ty + i * 8][tx] = W[(size_t)(k0 + ty + i * 8) * DD + n0 + tx];
  __syncthreads();
#pragma unroll
  for (int i = 0; i < 4; ++i)
    O[(size_t)(n0 + ty + i * 8) * DD + k0 + tx] = f2bf(t[tx][ty + i * 8]);
}

// ---- batched projection GEMM: C[M,N] = cvt_bf16(A_f32[M,K]) @ Bt[N,K]^T ----
// 128x128 tile, BK=64; blockIdx.z selects (A,Bt,C) triple.
#define LDA 72
__global__ __launch_bounds__(256) void proj_gemm(const float* __restrict__ a0,
                                                 const float* __restrict__ a1,
                                                 const float* __restrict__ a2,
                                                 const short* __restrict__ b0,
                                                 const short* __restrict__ b1,
                                                 const short* __restrict__ b2,
                                                 float* __restrict__ c0,
                                                 float* __restrict__ c1,
                                                 float* __restrict__ c2) {
  const float* A; const short* Bt; float* C;
  if (blockIdx.z == 0)      { A = a0; Bt = b0; C = c0; }
  else if (blockIdx.z == 1) { A = a1; Bt = b1; C = c1; }
  else                      { A = a2; Bt = b2; C = c2; }
  const int N = DD, K = DD;
  __shared__ short As[128 * LDA];
  __shared__ short Bs[128 * LDA];
  const int tid = threadIdx.x;
  const int m0 = blockIdx.y * 128, n0 = blockIdx.x * 128;
  const int wv = tid >> 6, lane = tid & 63;
  const int wm = wv * 32;
  const int r = lane & 15, q = lane >> 4;
  f32x4 acc[2][8] = {};
  for (int k0 = 0; k0 < K; k0 += 64) {
    float4 af[4][2];
    bf16x8 bvv[4];
#pragma unroll
    for (int it = 0; it < 4; ++it) {
      int idx = tid + it * 256;
      int row = idx >> 3, colq = (idx & 7) * 8;
      af[it][0] = *(const float4*)(A + (size_t)(m0 + row) * K + k0 + colq);
      af[it][1] = *(const float4*)(A + (size_t)(m0 + row) * K + k0 + colq + 4);
      bvv[it] = *(const bf16x8*)(Bt + (size_t)(n0 + row) * K + k0 + colq);
    }
    __syncthreads();
#pragma unroll
    for (int it = 0; it < 4; ++it) {
      int idx = tid + it * 256;
      int row = idx >> 3, colq = (idx & 7) * 8;
      bf16x8 av;
      const float* p0 = (const float*)&af[it][0];
      const float* p1 = (const float*)&af[it][1];
      av[0] = f2bf(p0[0]); av[1] = f2bf(p0[1]); av[2] = f2bf(p0[2]); av[3] = f2bf(p0[3]);
      av[4] = f2bf(p1[0]); av[5] = f2bf(p1[1]); av[6] = f2bf(p1[2]); av[7] = f2bf(p1[3]);
      *(bf16x8*)(&As[row * LDA + colq]) = av;
      *(bf16x8*)(&Bs[row * LDA + colq]) = bvv[it];
    }
    __syncthreads();
#pragma unroll
    for (int ks = 0; ks < 2; ++ks) {
      bf16x8 a0r = *(const bf16x8*)(&As[(wm + r) * LDA + ks * 32 + q * 8]);
      bf16x8 a1r = *(const bf16x8*)(&As[(wm + 16 + r) * LDA + ks * 32 + q * 8]);
#pragma unroll
      for (int j = 0; j < 8; ++j) {
        bf16x8 br = *(const bf16x8*)(&Bs[(j * 16 + r) * LDA + ks * 32 + q * 8]);
        acc[0][j] = __builtin_amdgcn_mfma_f32_16x16x32_bf16(a0r, br, acc[0][j], 0, 0, 0);
        acc[1][j] = __builtin_amdgcn_mfma_f32_16x16x32_bf16(a1r, br, acc[1][j], 0, 0, 0);
      }
    }
  }
#pragma unroll
  for (int i = 0; i < 2; ++i)
#pragma unroll
    for (int j = 0; j < 8; ++j)
#pragma unroll
      for (int reg = 0; reg < 4; ++reg) {
        int m = m0 + wm + i * 16 + q * 4 + reg;
        int n = n0 + j * 16 + r;
        C[(size_t)m * N + n] = acc[i][j][reg];
      }
}

// ---------------- bf16 MFMA GEMM (bf16 A), 128x128 tile, BK=64 ----------------
__global__ __launch_bounds__(256) void gemm_bf16(const short* __restrict__ A,
                                                 const short* __restrict__ Bt,
                                                 float* __restrict__ C,
                                                 int M, int N, int K) {
  __shared__ short As[128 * LDA];
  __shared__ short Bs[128 * LDA];
  const int tid = threadIdx.x;
  const int m0 = blockIdx.y * 128, n0 = blockIdx.x * 128;
  const int wv = tid >> 6, lane = tid & 63;
  const int wm = wv * 32;
  const int r = lane & 15, q = lane >> 4;
  f32x4 acc[2][8] = {};
  for (int k0 = 0; k0 < K; k0 += 64) {
    bf16x8 av[4], bvv[4];
#pragma unroll
    for (int it = 0; it < 4; ++it) {
      int idx = tid + it * 256;
      int row = idx >> 3, colq = (idx & 7) * 8;
      av[it] = *(const bf16x8*)(A + (size_t)(m0 + row) * K + k0 + colq);
      bvv[it] = *(const bf16x8*)(Bt + (size_t)(n0 + row) * K + k0 + colq);
    }
    __syncthreads();
#pragma unroll
    for (int it = 0; it < 4; ++it) {
      int idx = tid + it * 256;
      int row = idx >> 3, colq = (idx & 7) * 8;
      *(bf16x8*)(&As[row * LDA + colq]) = av[it];
      *(bf16x8*)(&Bs[row * LDA + colq]) = bvv[it];
    }
    __syncthreads();
#pragma unroll
    for (int ks = 0; ks < 2; ++ks) {
      bf16x8 a0r = *(const bf16x8*)(&As[(wm + r) * LDA + ks * 32 + q * 8]);
      bf16x8 a1r = *(const bf16x8*)(&As[(wm + 16 + r) * LDA + ks * 32 + q * 8]);
#pragma unroll
      for (int j = 0; j < 8; ++j) {
        bf16x8 br = *(const bf16x8*)(&Bs[(j * 16 + r) * LDA + ks * 32 + q * 8]);
        acc[0][j] = __builtin_amdgcn_mfma_f32_16x16x32_bf16(a0r, br, acc[0][j], 0, 0, 0);
        acc[1][j] = __builtin_amdgcn_mfma_f32_16x16x32_bf16(a1r, br, acc[1][j], 0, 0, 0);
      }
    }
  }
#pragma unroll
  for (int i = 0; i < 2; ++i)
#pragma unroll
    for (int j = 0; j < 8; ++j)
#pragma unroll
      for (int reg = 0; reg < 4; ++reg) {
        int m = m0 + wm + i * 16 + q * 4 + reg;
        int n = n0 + j * 16 + r;
        C[(size_t)m * N + n] = acc[i][j][reg];
      }
}

// ------- context proj, split-K f32 -------
__global__ __launch_bounds__(256) void ctx_gemm(const float* __restrict__ A,
                                                const float* __restrict__ Wm,
                                                float* __restrict__ part) {
  const int nt = blockIdx.x;
  const int ky = blockIdx.y;
  const int tid = threadIdx.x;
  __shared__ float As[32][68];
  __shared__ float Ws[64][68];
  {
    int m = tid >> 3, kq = (tid & 7) * 8;
    float4 a0 = *(const float4*)(A + (size_t)m * DD + ky * 64 + kq);
    float4 a1 = *(const float4*)(A + (size_t)m * DD + ky * 64 + kq + 4);
    As[m][kq + 0] = a0.x; As[m][kq + 1] = a0.y; As[m][kq + 2] = a0.z; As[m][kq + 3] = a0.w;
    As[m][kq + 4] = a1.x; As[m][kq + 5] = a1.y; As[m][kq + 6] = a1.z; As[m][kq + 7] = a1.w;
  }
  {
    int k = tid >> 2, nq = (tid & 3) * 16;
#pragma unroll
    for (int i = 0; i < 4; ++i) {
      float4 wv = *(const float4*)(Wm + (size_t)(ky * 64 + k) * DD + nt * 64 + nq + i * 4);
      Ws[k][nq + i * 4 + 0] = wv.x; Ws[k][nq + i * 4 + 1] = wv.y;
      Ws[k][nq + i * 4 + 2] = wv.z; Ws[k][nq + i * 4 + 3] = wv.w;
    }
  }
  __syncthreads();
  const int tx = tid & 63, my = tid >> 6;
  float acc[8] = {};
  for (int k = 0; k < 64; ++k) {
    float wv = Ws[k][tx];
#pragma unroll
    for (int m = 0; m < 8; ++m) acc[m] += As[my * 8 + m][k] * wv;
  }
#pragma unroll
  for (int m = 0; m < 8; ++m)
    part[((size_t)ky * 32 + my * 8 + m) * DD + nt * 64 + tx] = acc[m];
}

__global__ __launch_bounds__(256) void ctx_reduce(const float* __restrict__ part,
                                                  float* __restrict__ cs) {
  int i = blockIdx.x * 256 + threadIdx.x;
  float s = 0.f;
#pragma unroll
  for (int ky = 0; ky < 8; ++ky) s += part[(size_t)ky * 32 * DD + i];
  cs[i] = s;
}

#define LDW 72
#define LDN 40

// ---------------- scan phase A: chunk-local sums via MFMA, w computed inline ----------------
__global__ __launch_bounds__(256) void scanA_kernel(const float* __restrict__ kk,
                                                    const float* __restrict__ vs,
                                                    const float* __restrict__ cs,
                                                    float* __restrict__ csums) {
  const int bh = blockIdx.y, c = blockIdx.x;
  const int b = bh >> 3, h = bh & 7;
  const int tid = threadIdx.x;
  const int lane = tid & 63, wvid = tid >> 6;
  const int r = lane & 15, q = lane >> 4;

  __shared__ short csh[16 * LDW], csl[16 * LDW];
  __shared__ short kh[64 * LDW], kl[64 * LDW];
  __shared__ short kTh[64 * LDW], kTl[64 * LDW];
  __shared__ short vT[64 * LDW];
  __shared__ short wh[16 * LDW], wl[16 * LDW];
  __shared__ float nPart[4][16];

  const int row = tid >> 2, c16 = (tid & 3) * 16;
  const size_t gb = ((size_t)(b * SS + c * CLEN + row)) * DD + h * EE + c16;
  float4 kv[4], vv[4];
#pragma unroll
  for (int i = 0; i < 4; ++i) {
    kv[i] = *(const float4*)(kk + gb + i * 4);
    vv[i] = *(const float4*)(vs + gb + i * 4);
  }
  short hiA[16], loA[16];
#pragma unroll
  for (int i = 0; i < 4; ++i) {
    const float* pk = (const float*)&kv[i];
#pragma unroll
    for (int e = 0; e < 4; ++e) bsplit(pk[e], hiA[i * 4 + e], loA[i * 4 + e]);
  }
  {
    bf16x8 p0, p1, p2, p3;
#pragma unroll
    for (int e = 0; e < 8; ++e) { p0[e] = hiA[e]; p1[e] = hiA[8 + e]; p2[e] = loA[e]; p3[e] = loA[8 + e]; }
    *(bf16x8*)(&kh[row * LDW + c16]) = p0;
    *(bf16x8*)(&kh[row * LDW + c16 + 8]) = p1;
    *(bf16x8*)(&kl[row * LDW + c16]) = p2;
    *(bf16x8*)(&kl[row * LDW + c16 + 8]) = p3;
  }
#pragma unroll
  for (int t = 0; t < 16; ++t) {
    kTh[(c16 + t) * LDW + row] = hiA[t];
    kTl[(c16 + t) * LDW + row] = loA[t];
  }
#pragma unroll
  for (int i = 0; i < 4; ++i) {
    const float* pv = (const float*)&vv[i];
#pragma unroll
    for (int e = 0; e < 4; ++e) vT[(c16 + i * 4 + e) * LDW + row] = f2bf(pv[e]);
  }
  {
    const int g0 = tid >> 4, t4 = (tid & 15) * 4;
    float4 csv = *(const float4*)(cs + ((size_t)(b * GG + g0)) * DD + h * EE + t4);
    const float* pc = (const float*)&csv;
#pragma unroll
    for (int e = 0; e < 4; ++e) {
      short hi, lo;
      bsplit(pc[e], hi, lo);
      csh[g0 * LDW + t4 + e] = hi;
      csl[g0 * LDW + t4 + e] = lo;
    }
  }
  __syncthreads();  // S0

  f32x4 accw = {0.f, 0.f, 0.f, 0.f};
#pragma unroll
  for (int ks = 0; ks < 2; ++ks) {
    bf16x8 ah = *(const bf16x8*)(&csh[r * LDW + ks * 32 + q * 8]);
    bf16x8 al = *(const bf16x8*)(&csl[r * LDW + ks * 32 + q * 8]);
    bf16x8 bh = *(const bf16x8*)(&kh[(wvid * 16 + r) * LDW + ks * 32 + q * 8]);
    bf16x8 bl = *(const bf16x8*)(&kl[(wvid * 16 + r) * LDW + ks * 32 + q * 8]);
    accw = __builtin_amdgcn_mfma_f32_16x16x32_bf16(ah, bh, accw, 0, 0, 0);
    accw = __builtin_amdgcn_mfma_f32_16x16x32_bf16(ah, bl, accw, 0, 0, 0);
    accw = __builtin_amdgcn_mfma_f32_16x16x32_bf16(al, bh, accw, 0, 0, 0);
  }
  float wf[4];
#pragma unroll
  for (int reg = 0; reg < 4; ++reg) {
    wf[reg] = expf(accw[reg] * 0.125f);
    short hi, lo;
    bsplit(wf[reg], hi, lo);
    int g = q * 4 + reg, t = wvid * 16 + r;
    wh[g * LDW + t] = hi;
    wl[g * LDW + t] = lo;
  }
#pragma unroll
  for (int reg = 0; reg < 4; ++reg) {
    float np = wf[reg];
    np += __shfl_xor(np, 1);
    np += __shfl_xor(np, 2);
    np += __shfl_xor(np, 4);
    np += __shfl_xor(np, 8);
    if (r == 0) nPart[wvid][q * 4 + reg] = np;
  }
  __syncthreads();  // S1

  f32x4 ask = {0.f, 0.f, 0.f, 0.f}, asv = ask;
#pragma unroll
  for (int ks = 0; ks < 2; ++ks) {
    bf16x8 awh = *(const bf16x8*)(&wh[r * LDW + ks * 32 + q * 8]);
    bf16x8 awl = *(const bf16x8*)(&wl[r * LDW + ks * 32 + q * 8]);
    bf16x8 bkh = *(const bf16x8*)(&kTh[(wvid * 16 + r) * LDW + ks * 32 + q * 8]);
    bf16x8 bkl = *(const bf16x8*)(&kTl[(wvid * 16 + r) * LDW + ks * 32 + q * 8]);
    bf16x8 bv = *(const bf16x8*)(&vT[(wvid * 16 + r) * LDW + ks * 32 + q * 8]);
    ask = __builtin_amdgcn_mfma_f32_16x16x32_bf16(awh, bkh, ask, 0, 0, 0);
    ask = __builtin_amdgcn_mfma_f32_16x16x32_bf16(awh, bkl, ask, 0, 0, 0);
    ask = __builtin_amdgcn_mfma_f32_16x16x32_bf16(awl, bkh, ask, 0, 0, 0);
    asv = __builtin_amdgcn_mfma_f32_16x16x32_bf16(awh, bv, asv, 0, 0, 0);
    asv = __builtin_amdgcn_mfma_f32_16x16x32_bf16(awl, bv, asv, 0, 0, 0);
  }
#pragma unroll
  for (int reg = 0; reg < 4; ++reg) {
    int g = q * 4 + reg, e = wvid * 16 + r;
    size_t ob = ((size_t)((bh * NCHUNK + c) * GG + g)) * CS_STRIDE;
    csums[ob + e] = ask[reg];
    csums[ob + 64 + e] = asv[reg];
  }
  if (tid < 16) {
    size_t ob = ((size_t)((bh * NCHUNK + c) * GG + tid)) * CS_STRIDE;
    csums[ob + 128] = nPart[0][tid] + nPart[1][tid] + nPart[2][tid] + nPart[3][tid];
  }
}

// ---------------- chunk kernel: MFMA-based parallel causal attention ----------------
__global__ __launch_bounds__(256) void chunk_kernel(const float* __restrict__ kk,
                                                    const float* __restrict__ vs,
                                                    const float* __restrict__ qs,
                                                    const float* __restrict__ cs,
                                                    const float* __restrict__ csums,
                                                    short* __restrict__ attnbf) {
  const int c = blockIdx.x, bh = blockIdx.y;
  const int b = bh >> 3, h = bh & 7;
  const int tid = threadIdx.x;
  const int lane = tid & 63, wvid = tid >> 6;
  const int r = lane & 15, q = lane >> 4;
  const int sw = wvid * 16;

  __shared__ short qh[64 * LDW], qlo[64 * LDW], khb[64 * LDW], klo[64 * LDW], dh[64 * LDW];
  __shared__ short whb[16 * LDW], wlb[16 * LDW], skph[16 * LDW], skpl[16 * LDW];
  __shared__ short cshb[16 * LDW], cslb[16 * LDW];
  __shared__ short svpt[64 * LDN];
  __shared__ float nL[16 * 68];
  __shared__ float npreL[16];
  short* wct = qh;   // reused post-B1
  short* cmb = qlo;  // reused post-B1
  short* vt = khb;   // reused post-B1
  short* uh = dh;    // reused post-phase3

  const int row = tid >> 2, c16 = (tid & 3) * 16;
  const size_t gb = ((size_t)(b * SS + c * CLEN + row)) * DD + h * EE + c16;
  float4 qv[4], kv[4], vv[4];
#pragma unroll
  for (int i = 0; i < 4; ++i) {
    qv[i] = *(const float4*)(qs + gb + i * 4);
    kv[i] = *(const float4*)(kk + gb + i * 4);
    vv[i] = *(const float4*)(vs + gb + i * 4);
  }
  const int g0 = tid >> 4, t4 = (tid & 15) * 4;
  float4 csv = *(const float4*)(cs + ((size_t)(b * GG + g0)) * DD + h * EE + t4);

  float4 skv = make_float4(0, 0, 0, 0), svv = make_float4(0, 0, 0, 0);
  {
    int c2 = 0;
    for (; c2 + 4 <= c; c2 += 4) {
#pragma unroll
      for (int u = 0; u < 4; ++u) {
        size_t ob2 = ((size_t)((bh * NCHUNK + c2 + u) * GG + g0)) * CS_STRIDE;
        float4 a = *(const float4*)(csums + ob2 + t4);
        float4 bsum = *(const float4*)(csums + ob2 + 64 + t4);
        skv.x += a.x; skv.y += a.y; skv.z += a.z; skv.w += a.w;
        svv.x += bsum.x; svv.y += bsum.y; svv.z += bsum.z; svv.w += bsum.w;
      }
    }
    for (; c2 < c; ++c2) {
      size_t ob2 = ((size_t)((bh * NCHUNK + c2) * GG + g0)) * CS_STRIDE;
      float4 a = *(const float4*)(csums + ob2 + t4);
      float4 bsum = *(const float4*)(csums + ob2 + 64 + t4);
      skv.x += a.x; skv.y += a.y; skv.z += a.z; skv.w += a.w;
      svv.x += bsum.x; svv.y += bsum.y; svv.z += bsum.z; svv.w += bsum.w;
    }
  }
  if (tid < 16) {
    float npr = 0.f;
    for (int c2 = 0; c2 < c; ++c2)
      npr += csums[((size_t)((bh * NCHUNK + c2) * GG + tid)) * CS_STRIDE + 128];
    npreL[tid] = npr;
  }

#pragma unroll
  for (int i = 0; i < 4; ++i) {
    const float* pq = (const float*)&qv[i];
    const float* pk = (const float*)&kv[i];
#pragma unroll
    for (int e = 0; e < 4; ++e) {
      int col = c16 + i * 4 + e;
      short hi, lo;
      bsplit(pq[e], hi, lo);
      qh[row * LDW + col] = hi;
      qlo[row * LDW + col] = lo;
      bsplit(pk[e], hi, lo);
      khb[row * LDW + col] = hi;
      klo[row * LDW + col] = lo;
    }
  }
  {
    const float* pc = (const float*)&csv;
    const float* ps = (const float*)&skv;
#pragma unroll
    for (int e = 0; e < 4; ++e) {
      short hi, lo;
      bsplit(pc[e], hi, lo);
      cshb[g0 * LDW + t4 + e] = hi;
      cslb[g0 * LDW + t4 + e] = lo;
      bsplit(ps[e], hi, lo);
      skph[g0 * LDW + t4 + e] = hi;
      skpl[g0 * LDW + t4 + e] = lo;
    }
  }
  __syncthreads();  // S0

  {
    f32x4 accw = {0.f, 0.f, 0.f, 0.f};
#pragma unroll
    for (int ks = 0; ks < 2; ++ks) {
      bf16x8 ah = *(const bf16x8*)(&cshb[r * LDW + ks * 32 + q * 8]);
      bf16x8 al = *(const bf16x8*)(&cslb[r * LDW + ks * 32 + q * 8]);
      bf16x8 bh = *(const bf16x8*)(&khb[(sw + r) * LDW + ks * 32 + q * 8]);
      bf16x8 bl = *(const bf16x8*)(&klo[(sw + r) * LDW + ks * 32 + q * 8]);
      accw = __builtin_amdgcn_mfma_f32_16x16x32_bf16(ah, bh, accw, 0, 0, 0);
      accw = __builtin_amdgcn_mfma_f32_16x16x32_bf16(ah, bl, accw, 0, 0, 0);
      accw = __builtin_amdgcn_mfma_f32_16x16x32_bf16(al, bh, accw, 0, 0, 0);
    }
#pragma unroll
    for (int reg = 0; reg < 4; ++reg) {
      float wv = expf(accw[reg] * 0.125f);
      short hi, lo;
      bsplit(wv, hi, lo);
      int g = q * 4 + reg, t = sw + r;
      whb[g * LDW + t] = hi;
      wlb[g * LDW + t] = lo;
    }
  }
  __syncthreads();  // S0b

#pragma unroll
  for (int gg = 0; gg < 4; ++gg) {
    int g = wvid * 4 + gg;
    float val = bf2f(whb[g * LDW + lane]) + bf2f(wlb[g * LDW + lane]);
#pragma unroll
    for (int d = 1; d < 64; d <<= 1) {
      float tup = __shfl_up(val, d);
      if (lane >= d) val += tup;
    }
    nL[g * 68 + lane] = npreL[g] + val;
  }

  f32x4 accd[4];
  f32x4 accwt = {0.f, 0.f, 0.f, 0.f};
#pragma unroll
  for (int ct = 0; ct < 4; ++ct) accd[ct] = accwt;
#pragma unroll
  for (int kst = 0; kst < 2; ++kst) {
    bf16x8 aq = *(const bf16x8*)(&qh[(sw + r) * LDW + kst * 32 + q * 8]);
    bf16x8 aql = *(const bf16x8*)(&qlo[(sw + r) * LDW + kst * 32 + q * 8]);
    bf16x8 bsh = *(const bf16x8*)(&skph[r * LDW + kst * 32 + q * 8]);
    bf16x8 bsl = *(const bf16x8*)(&skpl[r * LDW + kst * 32 + q * 8]);
    accwt = __builtin_amdgcn_mfma_f32_16x16x32_bf16(aq, bsh, accwt, 0, 0, 0);
    accwt = __builtin_amdgcn_mfma_f32_16x16x32_bf16(aq, bsl, accwt, 0, 0, 0);
    accwt = __builtin_amdgcn_mfma_f32_16x16x32_bf16(aql, bsh, accwt, 0, 0, 0);
#pragma unroll
    for (int ct = 0; ct < 4; ++ct) {
      bf16x8 bk = *(const bf16x8*)(&khb[(ct * 16 + r) * LDW + kst * 32 + q * 8]);
      accd[ct] = __builtin_amdgcn_mfma_f32_16x16x32_bf16(aq, bk, accd[ct], 0, 0, 0);
    }
  }
#pragma unroll
  for (int ct = 0; ct < 4; ++ct)
#pragma unroll
    for (int reg = 0; reg < 4; ++reg) {
      int sl = sw + q * 4 + reg, tl = ct * 16 + r;
      float v = (tl <= sl) ? accd[ct][reg] : 0.f;
      dh[sl * LDW + tl] = f2bf(v);
    }
  __syncthreads();  // B1

#pragma unroll
  for (int i = 0; i < 4; ++i) {
    const float* pv = (const float*)&vv[i];
#pragma unroll
    for (int e = 0; e < 4; ++e)
      vt[(c16 + i * 4 + e) * LDW + row] = f2bf(pv[e]);
  }
  {
    const float* pv = (const float*)&svv;
#pragma unroll
    for (int e = 0; e < 4; ++e)
      svpt[(t4 + e) * LDN + g0] = f2bf(pv[e]);
    int ez = tid >> 2, gz = 16 + (tid & 3) * 4;
#pragma unroll
    for (int e = 0; e < 4; ++e) svpt[ez * LDN + gz + e] = 0;
    int tt = tid >> 2, gw = (tid & 3) * 4;
#pragma unroll
    for (int e = 0; e < 4; ++e) {
      wct[tt * LDN + gw + e] = whb[(gw + e) * LDW + tt];
      wct[tt * LDN + 16 + gw + e] = 0;
    }
  }

#pragma unroll
  for (int kst = 0; kst < 2; ++kst) {
    bf16x8 ad = *(const bf16x8*)(&dh[(sw + r) * LDW + kst * 32 + q * 8]);
    bf16x8 bw = *(const bf16x8*)(&whb[r * LDW + kst * 32 + q * 8]);
    bf16x8 bl = *(const bf16x8*)(&wlb[r * LDW + kst * 32 + q * 8]);
    accwt = __builtin_amdgcn_mfma_f32_16x16x32_bf16(ad, bw, accwt, 0, 0, 0);
    accwt = __builtin_amdgcn_mfma_f32_16x16x32_bf16(ad, bl, accwt, 0, 0, 0);
  }
#pragma unroll
  for (int reg = 0; reg < 4; ++reg) {
    int sl = sw + q * 4 + reg;
    float nv = fmaxf(nL[r * 68 + sl], 1e-8f);
    float wt = accwt[reg] / nv;
    float m = wt;
    m = fmaxf(m, __shfl_xor(m, 1));
    m = fmaxf(m, __shfl_xor(m, 2));
    m = fmaxf(m, __shfl_xor(m, 4));
    m = fmaxf(m, __shfl_xor(m, 8));
    float ex = expf(wt - m);
    float den = ex;
    den += __shfl_xor(den, 1);
    den += __shfl_xor(den, 2);
    den += __shfl_xor(den, 4);
    den += __shfl_xor(den, 8);
    float cmv = (ex / den) / nv;
    cmb[sl * LDN + r] = f2bf(cmv);
    cmb[sl * LDN + 16 + r] = 0;
  }
  __syncthreads();  // B2

  bf16x8 acm = *(const bf16x8*)(&cmb[(sw + r) * LDN + q * 8]);
  f32x4 accu[4];
#pragma unroll
  for (int ct = 0; ct < 4; ++ct) accu[ct] = (f32x4){0.f, 0.f, 0.f, 0.f};
#pragma unroll
  for (int ct = 0; ct < 4; ++ct) {
    bf16x8 bwc = *(const bf16x8*)(&wct[(ct * 16 + r) * LDN + q * 8]);
    accu[ct] = __builtin_amdgcn_mfma_f32_16x16x32_bf16(acm, bwc, accu[ct], 0, 0, 0);
  }
#pragma unroll
  for (int ct = 0; ct < 4; ++ct)
#pragma unroll
    for (int reg = 0; reg < 4; ++reg) {
      int sl = sw + q * 4 + reg, tl = ct * 16 + r;
      float v = (tl <= sl) ? accu[ct][reg] : 0.f;
      uh[sl * LDW + tl] = f2bf(v);
    }

  f32x4 acco[4];
#pragma unroll
  for (int et = 0; et < 4; ++et) acco[et] = (f32x4){0.f, 0.f, 0.f, 0.f};
#pragma unroll
  for (int et = 0; et < 4; ++et) {
    bf16x8 bs = *(const bf16x8*)(&svpt[(et * 16 + r) * LDN + q * 8]);
    acco[et] = __builtin_amdgcn_mfma_f32_16x16x32_bf16(acm, bs, acco[et], 0, 0, 0);
  }
#pragma unroll
  for (int kst = 0; kst < 2; ++kst) {
    bf16x8 au = *(const bf16x8*)(&uh[(sw + r) * LDW + kst * 32 + q * 8]);
#pragma unroll
    for (int et = 0; et < 4; ++et) {
      bf16x8 bv = *(const bf16x8*)(&vt[(et * 16 + r) * LDW + kst * 32 + q * 8]);
      acco[et] = __builtin_amdgcn_mfma_f32_16x16x32_bf16(au, bv, acco[et], 0, 0, 0);
    }
  }
#pragma unroll
  for (int et = 0; et < 4; ++et)
#pragma unroll
    for (int reg = 0; reg < 4; ++reg) {
      int sl = sw + q * 4 + reg;
      attnbf[((size_t)(b * SS + c * CLEN + sl)) * DD + h * EE + et * 16 + r] =
          f2bf(acco[et][reg]);
    }
}

extern "C" void kernel_launch(void* const* d_in, const int* in_sizes, int n_in,
                              void* d_out, int out_size, void* d_ws, size_t ws_size,
                              hipStream_t stream) {
  const float* query = (const float*)d_in[0];
  const float* key = (const float*)d_in[1];
  const float* value = (const float*)d_in[2];
  const float* context = (const float*)d_in[3];
  const float* query_proj = (const float*)d_in[4];
  const float* key_proj = (const float*)d_in[5];
  const float* value_proj = (const float*)d_in[6];
  const float* output_proj = (const float*)d_in[7];
  const float* context_proj = (const float*)d_in[8];
  float* out = (float*)d_out;

  float* fbase = (float*)d_ws;
  const size_t MS = (size_t)BB * SS * DD;  // 2M
  float* qs_t = fbase;
  float* kk_t = qs_t + MS;
  float* vs_t = kk_t + MS;
  float* cs_t = vs_t + MS;                          // 32*512
  float* csums = cs_t + (size_t)BB * GG * DD;       // 8192*132
  float* part = csums + (size_t)BB * HH * NCHUNK * GG * CS_STRIDE;  // 8*32*512
  short* Abf = (short*)(part + (size_t)8 * 32 * DD);  // attn bf16
  short* Wq = Abf + MS;
  short* Wk = Wq + (size_t)DD * DD;
  short* Wv = Wk + (size_t)DD * DD;
  short* Wo = Wv + (size_t)DD * DD;

  dim3 blk(256);
  dim3 tb(32, 8), tg4(DD / 32, DD / 32, 4);

  cvtT4_bf16<<<tg4, tb, 0, stream>>>(query_proj, key_proj, value_proj, output_proj,
                                     Wq, Wk, Wv, Wo);
  ctx_gemm<<<dim3(8, 8), blk, 0, stream>>>(context, context_proj, part);
  ctx_reduce<<<dim3(BB * GG * DD / 256), blk, 0, stream>>>(part, cs_t);

  proj_gemm<<<dim3(DD / 128, (BB * SS) / 128, 3), blk, 0, stream>>>(
      query, key, value, Wq, Wk, Wv, qs_t, kk_t, vs_t);

  dim3 gscan(NCHUNK, BB * HH);
  scanA_kernel<<<gscan, blk, 0, stream>>>(kk_t, vs_t, cs_t, csums);
  chunk_kernel<<<gscan, blk, 0, stream>>>(kk_t, vs_t, qs_t, cs_t, csums, Abf);

  gemm_bf16<<<dim3(DD / 128, (BB * SS) / 128), blk, 0, stream>>>(Abf, Wo, out, BB * SS, DD, DD);
}

// Round 10
// 146.778 us; speedup vs baseline: 3.6419x; 1.0040x over previous
//
#include <hip/hip_runtime.h>
#include <hip/hip_bf16.h>

// Problem constants
#define BB 2
#define SS 2048
#define GG 16
#define HH 8
#define EE 64
#define DD 512
#define NCHUNK 32
#define CLEN 64
#define CS_STRIDE 132  // 64 sk + 64 sv + 1 n + 3 pad

typedef __attribute__((ext_vector_type(8))) short bf16x8;
typedef __attribute__((ext_vector_type(4))) float f32x4;

static __device__ __forceinline__ short f2bf(float x) {
  union { float f; unsigned u; } v; v.f = x;
  unsigned r = v.u + 0x7fffu + ((v.u >> 16) & 1u);  // round-nearest-even
  return (short)(r >> 16);
}
static __device__ __forceinline__ float bf2f(short s) {
  return __uint_as_float(((unsigned)(unsigned short)s) << 16);
}
static __device__ __forceinline__ void bsplit(float x, short& hi, short& lo) {
  hi = f2bf(x);
  lo = f2bf(x - bf2f(hi));
}

// ---- prep kernel: z<4 -> weight transpose+cvt; z==4 -> ctx split-K partials ----
// block = (32,8). cvtT4 uses grid (16,16); ctx uses (8,8) subset.
__global__ __launch_bounds__(256) void prep_kernel(const float* __restrict__ w0,
                                                   const float* __restrict__ w1,
                                                   const float* __restrict__ w2,
                                                   const float* __restrict__ w3,
                                                   short* __restrict__ o0,
                                                   short* __restrict__ o1,
                                                   short* __restrict__ o2,
                                                   short* __restrict__ o3,
                                                   const float* __restrict__ ctxA,
                                                   const float* __restrict__ ctxW,
                                                   float* __restrict__ part) {
  __shared__ float smem[32 * 68 + 64 * 68];
  const int tx = threadIdx.x, ty = threadIdx.y;
  if (blockIdx.z < 4) {
    const float* W; short* O;
    if (blockIdx.z == 0)      { W = w0; O = o0; }
    else if (blockIdx.z == 1) { W = w1; O = o1; }
    else if (blockIdx.z == 2) { W = w2; O = o2; }
    else                      { W = w3; O = o3; }
    float (*t)[33] = (float (*)[33])smem;
    const int k0 = blockIdx.x * 32, n0 = blockIdx.y * 32;
#pragma unroll
    for (int i = 0; i < 4; ++i)
      t[ty + i * 8][tx] = W[(size_t)(k0 + ty + i * 8) * DD + n0 + tx];
    __syncthreads();
#pragma unroll
    for (int i = 0; i < 4; ++i)
      O[(size_t)(n0 + ty + i * 8) * DD + k0 + tx] = f2bf(t[tx][ty + i * 8]);
    return;
  }
  // ctx split-K: part[ky][32][512] = A[32][64ky] @ W[64ky][512]
  if (blockIdx.x >= 8 || blockIdx.y >= 8) return;
  const int nt = blockIdx.x, ky = blockIdx.y;
  const int tid = ty * 32 + tx;
  float (*As)[68] = (float (*)[68])smem;
  float (*Ws)[68] = (float (*)[68])(smem + 32 * 68);
  {
    int m = tid >> 3, kq = (tid & 7) * 8;
    float4 a0 = *(const float4*)(ctxA + (size_t)m * DD + ky * 64 + kq);
    float4 a1 = *(const float4*)(ctxA + (size_t)m * DD + ky * 64 + kq + 4);
    As[m][kq + 0] = a0.x; As[m][kq + 1] = a0.y; As[m][kq + 2] = a0.z; As[m][kq + 3] = a0.w;
    As[m][kq + 4] = a1.x; As[m][kq + 5] = a1.y; As[m][kq + 6] = a1.z; As[m][kq + 7] = a1.w;
  }
  {
    int k = tid >> 2, nq = (tid & 3) * 16;
#pragma unroll
    for (int i = 0; i < 4; ++i) {
      float4 wv = *(const float4*)(ctxW + (size_t)(ky * 64 + k) * DD + nt * 64 + nq + i * 4);
      Ws[k][nq + i * 4 + 0] = wv.x; Ws[k][nq + i * 4 + 1] = wv.y;
      Ws[k][nq + i * 4 + 2] = wv.z; Ws[k][nq + i * 4 + 3] = wv.w;
    }
  }
  __syncthreads();
  const int txl = tid & 63, my = tid >> 6;
  float acc[8] = {};
  for (int k = 0; k < 64; ++k) {
    float wv = Ws[k][txl];
#pragma unroll
    for (int m = 0; m < 8; ++m) acc[m] += As[my * 8 + m][k] * wv;
  }
#pragma unroll
  for (int m = 0; m < 8; ++m)
    part[((size_t)ky * 32 + my * 8 + m) * DD + nt * 64 + txl] = acc[m];
}

// ---- batched projection GEMM: C[M,N] = cvt_bf16(A_f32[M,K]) @ Bt[N,K]^T ----
// 128x128 tile, BK=64; blockIdx.z selects (A,Bt,C) triple.
#define LDA 72
__global__ __launch_bounds__(256) void proj_gemm(const float* __restrict__ a0,
                                                 const float* __restrict__ a1,
                                                 const float* __restrict__ a2,
                                                 const short* __restrict__ b0,
                                                 const short* __restrict__ b1,
                                                 const short* __restrict__ b2,
                                                 float* __restrict__ c0,
                                                 float* __restrict__ c1,
                                                 float* __restrict__ c2) {
  const float* A; const short* Bt; float* C;
  if (blockIdx.z == 0)      { A = a0; Bt = b0; C = c0; }
  else if (blockIdx.z == 1) { A = a1; Bt = b1; C = c1; }
  else                      { A = a2; Bt = b2; C = c2; }
  const int N = DD, K = DD;
  __shared__ short As[128 * LDA];
  __shared__ short Bs[128 * LDA];
  const int tid = threadIdx.x;
  const int m0 = blockIdx.y * 128, n0 = blockIdx.x * 128;
  const int wv = tid >> 6, lane = tid & 63;
  const int wm = wv * 32;
  const int r = lane & 15, q = lane >> 4;
  f32x4 acc[2][8] = {};
  for (int k0 = 0; k0 < K; k0 += 64) {
    float4 af[4][2];
    bf16x8 bvv[4];
#pragma unroll
    for (int it = 0; it < 4; ++it) {
      int idx = tid + it * 256;
      int row = idx >> 3, colq = (idx & 7) * 8;
      af[it][0] = *(const float4*)(A + (size_t)(m0 + row) * K + k0 + colq);
      af[it][1] = *(const float4*)(A + (size_t)(m0 + row) * K + k0 + colq + 4);
      bvv[it] = *(const bf16x8*)(Bt + (size_t)(n0 + row) * K + k0 + colq);
    }
    __syncthreads();
#pragma unroll
    for (int it = 0; it < 4; ++it) {
      int idx = tid + it * 256;
      int row = idx >> 3, colq = (idx & 7) * 8;
      bf16x8 av;
      const float* p0 = (const float*)&af[it][0];
      const float* p1 = (const float*)&af[it][1];
      av[0] = f2bf(p0[0]); av[1] = f2bf(p0[1]); av[2] = f2bf(p0[2]); av[3] = f2bf(p0[3]);
      av[4] = f2bf(p1[0]); av[5] = f2bf(p1[1]); av[6] = f2bf(p1[2]); av[7] = f2bf(p1[3]);
      *(bf16x8*)(&As[row * LDA + colq]) = av;
      *(bf16x8*)(&Bs[row * LDA + colq]) = bvv[it];
    }
    __syncthreads();
#pragma unroll
    for (int ks = 0; ks < 2; ++ks) {
      bf16x8 a0r = *(const bf16x8*)(&As[(wm + r) * LDA + ks * 32 + q * 8]);
      bf16x8 a1r = *(const bf16x8*)(&As[(wm + 16 + r) * LDA + ks * 32 + q * 8]);
#pragma unroll
      for (int j = 0; j < 8; ++j) {
        bf16x8 br = *(const bf16x8*)(&Bs[(j * 16 + r) * LDA + ks * 32 + q * 8]);
        acc[0][j] = __builtin_amdgcn_mfma_f32_16x16x32_bf16(a0r, br, acc[0][j], 0, 0, 0);
        acc[1][j] = __builtin_amdgcn_mfma_f32_16x16x32_bf16(a1r, br, acc[1][j], 0, 0, 0);
      }
    }
  }
#pragma unroll
  for (int i = 0; i < 2; ++i)
#pragma unroll
    for (int j = 0; j < 8; ++j)
#pragma unroll
      for (int reg = 0; reg < 4; ++reg) {
        int m = m0 + wm + i * 16 + q * 4 + reg;
        int n = n0 + j * 16 + r;
        C[(size_t)m * N + n] = acc[i][j][reg];
      }
}

// ---------------- bf16 MFMA GEMM (bf16 A), 128x128 tile, BK=64 ----------------
__global__ __launch_bounds__(256) void gemm_bf16(const short* __restrict__ A,
                                                 const short* __restrict__ Bt,
                                                 float* __restrict__ C,
                                                 int M, int N, int K) {
  __shared__ short As[128 * LDA];
  __shared__ short Bs[128 * LDA];
  const int tid = threadIdx.x;
  const int m0 = blockIdx.y * 128, n0 = blockIdx.x * 128;
  const int wv = tid >> 6, lane = tid & 63;
  const int wm = wv * 32;
  const int r = lane & 15, q = lane >> 4;
  f32x4 acc[2][8] = {};
  for (int k0 = 0; k0 < K; k0 += 64) {
    bf16x8 av[4], bvv[4];
#pragma unroll
    for (int it = 0; it < 4; ++it) {
      int idx = tid + it * 256;
      int row = idx >> 3, colq = (idx & 7) * 8;
      av[it] = *(const bf16x8*)(A + (size_t)(m0 + row) * K + k0 + colq);
      bvv[it] = *(const bf16x8*)(Bt + (size_t)(n0 + row) * K + k0 + colq);
    }
    __syncthreads();
#pragma unroll
    for (int it = 0; it < 4; ++it) {
      int idx = tid + it * 256;
      int row = idx >> 3, colq = (idx & 7) * 8;
      *(bf16x8*)(&As[row * LDA + colq]) = av[it];
      *(bf16x8*)(&Bs[row * LDA + colq]) = bvv[it];
    }
    __syncthreads();
#pragma unroll
    for (int ks = 0; ks < 2; ++ks) {
      bf16x8 a0r = *(const bf16x8*)(&As[(wm + r) * LDA + ks * 32 + q * 8]);
      bf16x8 a1r = *(const bf16x8*)(&As[(wm + 16 + r) * LDA + ks * 32 + q * 8]);
#pragma unroll
      for (int j = 0; j < 8; ++j) {
        bf16x8 br = *(const bf16x8*)(&Bs[(j * 16 + r) * LDA + ks * 32 + q * 8]);
        acc[0][j] = __builtin_amdgcn_mfma_f32_16x16x32_bf16(a0r, br, acc[0][j], 0, 0, 0);
        acc[1][j] = __builtin_amdgcn_mfma_f32_16x16x32_bf16(a1r, br, acc[1][j], 0, 0, 0);
      }
    }
  }
#pragma unroll
  for (int i = 0; i < 2; ++i)
#pragma unroll
    for (int j = 0; j < 8; ++j)
#pragma unroll
      for (int reg = 0; reg < 4; ++reg) {
        int m = m0 + wm + i * 16 + q * 4 + reg;
        int n = n0 + j * 16 + r;
        C[(size_t)m * N + n] = acc[i][j][reg];
      }
}

#define LDW 72
#define LDN 40

// ---------------- scan phase A: chunk-local sums via MFMA, w computed inline ----------------
__global__ __launch_bounds__(256) void scanA_kernel(const float* __restrict__ kk,
                                                    const float* __restrict__ vs,
                                                    const float* __restrict__ part,
                                                    float* __restrict__ csums) {
  const int bh = blockIdx.y, c = blockIdx.x;
  const int b = bh >> 3, h = bh & 7;
  const int tid = threadIdx.x;
  const int lane = tid & 63, wvid = tid >> 6;
  const int r = lane & 15, q = lane >> 4;

  __shared__ short csh[16 * LDW], csl[16 * LDW];
  __shared__ short kh[64 * LDW], kl[64 * LDW];
  __shared__ short kTh[64 * LDW], kTl[64 * LDW];
  __shared__ short vT[64 * LDW];
  __shared__ short wh[16 * LDW], wl[16 * LDW];
  __shared__ float nPart[4][16];

  const int row = tid >> 2, c16 = (tid & 3) * 16;
  const size_t gb = ((size_t)(b * SS + c * CLEN + row)) * DD + h * EE + c16;
  float4 kv[4], vv[4];
#pragma unroll
  for (int i = 0; i < 4; ++i) {
    kv[i] = *(const float4*)(kk + gb + i * 4);
    vv[i] = *(const float4*)(vs + gb + i * 4);
  }
  short hiA[16], loA[16];
#pragma unroll
  for (int i = 0; i < 4; ++i) {
    const float* pk = (const float*)&kv[i];
#pragma unroll
    for (int e = 0; e < 4; ++e) bsplit(pk[e], hiA[i * 4 + e], loA[i * 4 + e]);
  }
  {
    bf16x8 p0, p1, p2, p3;
#pragma unroll
    for (int e = 0; e < 8; ++e) { p0[e] = hiA[e]; p1[e] = hiA[8 + e]; p2[e] = loA[e]; p3[e] = loA[8 + e]; }
    *(bf16x8*)(&kh[row * LDW + c16]) = p0;
    *(bf16x8*)(&kh[row * LDW + c16 + 8]) = p1;
    *(bf16x8*)(&kl[row * LDW + c16]) = p2;
    *(bf16x8*)(&kl[row * LDW + c16 + 8]) = p3;
  }
#pragma unroll
  for (int t = 0; t < 16; ++t) {
    kTh[(c16 + t) * LDW + row] = hiA[t];
    kTl[(c16 + t) * LDW + row] = loA[t];
  }
#pragma unroll
  for (int i = 0; i < 4; ++i) {
    const float* pv = (const float*)&vv[i];
#pragma unroll
    for (int e = 0; e < 4; ++e) vT[(c16 + i * 4 + e) * LDW + row] = f2bf(pv[e]);
  }
  {
    const int g0 = tid >> 4, t4 = (tid & 15) * 4;
    float4 csv = make_float4(0, 0, 0, 0);
#pragma unroll
    for (int ky = 0; ky < 8; ++ky) {
      float4 p = *(const float4*)(part + ((size_t)(ky * 32 + b * GG + g0)) * DD + h * EE + t4);
      csv.x += p.x; csv.y += p.y; csv.z += p.z; csv.w += p.w;
    }
    const float* pc = (const float*)&csv;
#pragma unroll
    for (int e = 0; e < 4; ++e) {
      short hi, lo;
      bsplit(pc[e], hi, lo);
      csh[g0 * LDW + t4 + e] = hi;
      csl[g0 * LDW + t4 + e] = lo;
    }
  }
  __syncthreads();  // S0

  f32x4 accw = {0.f, 0.f, 0.f, 0.f};
#pragma unroll
  for (int ks = 0; ks < 2; ++ks) {
    bf16x8 ah = *(const bf16x8*)(&csh[r * LDW + ks * 32 + q * 8]);
    bf16x8 al = *(const bf16x8*)(&csl[r * LDW + ks * 32 + q * 8]);
    bf16x8 bh = *(const bf16x8*)(&kh[(wvid * 16 + r) * LDW + ks * 32 + q * 8]);
    bf16x8 bl = *(const bf16x8*)(&kl[(wvid * 16 + r) * LDW + ks * 32 + q * 8]);
    accw = __builtin_amdgcn_mfma_f32_16x16x32_bf16(ah, bh, accw, 0, 0, 0);
    accw = __builtin_amdgcn_mfma_f32_16x16x32_bf16(ah, bl, accw, 0, 0, 0);
    accw = __builtin_amdgcn_mfma_f32_16x16x32_bf16(al, bh, accw, 0, 0, 0);
  }
  float wf[4];
#pragma unroll
  for (int reg = 0; reg < 4; ++reg) {
    wf[reg] = expf(accw[reg] * 0.125f);
    short hi, lo;
    bsplit(wf[reg], hi, lo);
    int g = q * 4 + reg, t = wvid * 16 + r;
    wh[g * LDW + t] = hi;
    wl[g * LDW + t] = lo;
  }
#pragma unroll
  for (int reg = 0; reg < 4; ++reg) {
    float np = wf[reg];
    np += __shfl_xor(np, 1);
    np += __shfl_xor(np, 2);
    np += __shfl_xor(np, 4);
    np += __shfl_xor(np, 8);
    if (r == 0) nPart[wvid][q * 4 + reg] = np;
  }
  __syncthreads();  // S1

  f32x4 ask = {0.f, 0.f, 0.f, 0.f}, asv = ask;
#pragma unroll
  for (int ks = 0; ks < 2; ++ks) {
    bf16x8 awh = *(const bf16x8*)(&wh[r * LDW + ks * 32 + q * 8]);
    bf16x8 awl = *(const bf16x8*)(&wl[r * LDW + ks * 32 + q * 8]);
    bf16x8 bkh = *(const bf16x8*)(&kTh[(wvid * 16 + r) * LDW + ks * 32 + q * 8]);
    bf16x8 bkl = *(const bf16x8*)(&kTl[(wvid * 16 + r) * LDW + ks * 32 + q * 8]);
    bf16x8 bv = *(const bf16x8*)(&vT[(wvid * 16 + r) * LDW + ks * 32 + q * 8]);
    ask = __builtin_amdgcn_mfma_f32_16x16x32_bf16(awh, bkh, ask, 0, 0, 0);
    ask = __builtin_amdgcn_mfma_f32_16x16x32_bf16(awh, bkl, ask, 0, 0, 0);
    ask = __builtin_amdgcn_mfma_f32_16x16x32_bf16(awl, bkh, ask, 0, 0, 0);
    asv = __builtin_amdgcn_mfma_f32_16x16x32_bf16(awh, bv, asv, 0, 0, 0);
    asv = __builtin_amdgcn_mfma_f32_16x16x32_bf16(awl, bv, asv, 0, 0, 0);
  }
#pragma unroll
  for (int reg = 0; reg < 4; ++reg) {
    int g = q * 4 + reg, e = wvid * 16 + r;
    size_t ob = ((size_t)((bh * NCHUNK + c) * GG + g)) * CS_STRIDE;
    csums[ob + e] = ask[reg];
    csums[ob + 64 + e] = asv[reg];
  }
  if (tid < 16) {
    size_t ob = ((size_t)((bh * NCHUNK + c) * GG + tid)) * CS_STRIDE;
    csums[ob + 128] = nPart[0][tid] + nPart[1][tid] + nPart[2][tid] + nPart[3][tid];
  }
}

// ---------------- chunk kernel: MFMA-based parallel causal attention ----------------
__global__ __launch_bounds__(256) void chunk_kernel(const float* __restrict__ kk,
                                                    const float* __restrict__ vs,
                                                    const float* __restrict__ qs,
                                                    const float* __restrict__ part,
                                                    const float* __restrict__ csums,
                                                    short* __restrict__ attnbf) {
  const int c = blockIdx.x, bh = blockIdx.y;
  const int b = bh >> 3, h = bh & 7;
  const int tid = threadIdx.x;
  const int lane = tid & 63, wvid = tid >> 6;
  const int r = lane & 15, q = lane >> 4;
  const int sw = wvid * 16;

  __shared__ short qh[64 * LDW], qlo[64 * LDW], khb[64 * LDW], klo[64 * LDW], dh[64 * LDW];
  __shared__ short whb[16 * LDW], wlb[16 * LDW], skph[16 * LDW], skpl[16 * LDW];
  __shared__ short cshb[16 * LDW], cslb[16 * LDW];
  __shared__ short svpt[64 * LDN];
  __shared__ float nL[16 * 68];
  __shared__ float npreL[16];
  short* wct = qh;   // reused post-B1
  short* cmb = qlo;  // reused post-B1
  short* vt = khb;   // reused post-B1
  short* uh = dh;    // reused post-phase3

  const int row = tid >> 2, c16 = (tid & 3) * 16;
  const size_t gb = ((size_t)(b * SS + c * CLEN + row)) * DD + h * EE + c16;
  float4 qv[4], kv[4], vv[4];
#pragma unroll
  for (int i = 0; i < 4; ++i) {
    qv[i] = *(const float4*)(qs + gb + i * 4);
    kv[i] = *(const float4*)(kk + gb + i * 4);
    vv[i] = *(const float4*)(vs + gb + i * 4);
  }
  const int g0 = tid >> 4, t4 = (tid & 15) * 4;
  float4 csv = make_float4(0, 0, 0, 0);
#pragma unroll
  for (int ky = 0; ky < 8; ++ky) {
    float4 p = *(const float4*)(part + ((size_t)(ky * 32 + b * GG + g0)) * DD + h * EE + t4);
    csv.x += p.x; csv.y += p.y; csv.z += p.z; csv.w += p.w;
  }

  float4 skv = make_float4(0, 0, 0, 0), svv = make_float4(0, 0, 0, 0);
  {
    int c2 = 0;
    for (; c2 + 4 <= c; c2 += 4) {
#pragma unroll
      for (int u = 0; u < 4; ++u) {
        size_t ob2 = ((size_t)((bh * NCHUNK + c2 + u) * GG + g0)) * CS_STRIDE;
        float4 a = *(const float4*)(csums + ob2 + t4);
        float4 bsum = *(const float4*)(csums + ob2 + 64 + t4);
        skv.x += a.x; skv.y += a.y; skv.z += a.z; skv.w += a.w;
        svv.x += bsum.x; svv.y += bsum.y; svv.z += bsum.z; svv.w += bsum.w;
      }
    }
    for (; c2 < c; ++c2) {
      size_t ob2 = ((size_t)((bh * NCHUNK + c2) * GG + g0)) * CS_STRIDE;
      float4 a = *(const float4*)(csums + ob2 + t4);
      float4 bsum = *(const float4*)(csums + ob2 + 64 + t4);
      skv.x += a.x; skv.y += a.y; skv.z += a.z; skv.w += a.w;
      svv.x += bsum.x; svv.y += bsum.y; svv.z += bsum.z; svv.w += bsum.w;
    }
  }
  if (tid < 16) {
    float npr = 0.f;
    for (int c2 = 0; c2 < c; ++c2)
      npr += csums[((size_t)((bh * NCHUNK + c2) * GG + tid)) * CS_STRIDE + 128];
    npreL[tid] = npr;
  }

#pragma unroll
  for (int i = 0; i < 4; ++i) {
    const float* pq = (const float*)&qv[i];
    const float* pk = (const float*)&kv[i];
#pragma unroll
    for (int e = 0; e < 4; ++e) {
      int col = c16 + i * 4 + e;
      short hi, lo;
      bsplit(pq[e], hi, lo);
      qh[row * LDW + col] = hi;
      qlo[row * LDW + col] = lo;
      bsplit(pk[e], hi, lo);
      khb[row * LDW + col] = hi;
      klo[row * LDW + col] = lo;
    }
  }
  {
    const float* pc = (const float*)&csv;
    const float* ps = (const float*)&skv;
#pragma unroll
    for (int e = 0; e < 4; ++e) {
      short hi, lo;
      bsplit(pc[e], hi, lo);
      cshb[g0 * LDW + t4 + e] = hi;
      cslb[g0 * LDW + t4 + e] = lo;
      bsplit(ps[e], hi, lo);
      skph[g0 * LDW + t4 + e] = hi;
      skpl[g0 * LDW + t4 + e] = lo;
    }
  }
  __syncthreads();  // S0

  {
    f32x4 accw = {0.f, 0.f, 0.f, 0.f};
#pragma unroll
    for (int ks = 0; ks < 2; ++ks) {
      bf16x8 ah = *(const bf16x8*)(&cshb[r * LDW + ks * 32 + q * 8]);
      bf16x8 al = *(const bf16x8*)(&cslb[r * LDW + ks * 32 + q * 8]);
      bf16x8 bh = *(const bf16x8*)(&khb[(sw + r) * LDW + ks * 32 + q * 8]);
      bf16x8 bl = *(const bf16x8*)(&klo[(sw + r) * LDW + ks * 32 + q * 8]);
      accw = __builtin_amdgcn_mfma_f32_16x16x32_bf16(ah, bh, accw, 0, 0, 0);
      accw = __builtin_amdgcn_mfma_f32_16x16x32_bf16(ah, bl, accw, 0, 0, 0);
      accw = __builtin_amdgcn_mfma_f32_16x16x32_bf16(al, bh, accw, 0, 0, 0);
    }
#pragma unroll
    for (int reg = 0; reg < 4; ++reg) {
      float wv = expf(accw[reg] * 0.125f);
      short hi, lo;
      bsplit(wv, hi, lo);
      int g = q * 4 + reg, t = sw + r;
      whb[g * LDW + t] = hi;
      wlb[g * LDW + t] = lo;
    }
  }
  __syncthreads();  // S0b

#pragma unroll
  for (int gg = 0; gg < 4; ++gg) {
    int g = wvid * 4 + gg;
    float val = bf2f(whb[g * LDW + lane]) + bf2f(wlb[g * LDW + lane]);
#pragma unroll
    for (int d = 1; d < 64; d <<= 1) {
      float tup = __shfl_up(val, d);
      if (lane >= d) val += tup;
    }
    nL[g * 68 + lane] = npreL[g] + val;
  }

  f32x4 accd[4];
  f32x4 accwt = {0.f, 0.f, 0.f, 0.f};
#pragma unroll
  for (int ct = 0; ct < 4; ++ct) accd[ct] = accwt;
#pragma unroll
  for (int kst = 0; kst < 2; ++kst) {
    bf16x8 aq = *(const bf16x8*)(&qh[(sw + r) * LDW + kst * 32 + q * 8]);
    bf16x8 aql = *(const bf16x8*)(&qlo[(sw + r) * LDW + kst * 32 + q * 8]);
    bf16x8 bsh = *(const bf16x8*)(&skph[r * LDW + kst * 32 + q * 8]);
    bf16x8 bsl = *(const bf16x8*)(&skpl[r * LDW + kst * 32 + q * 8]);
    accwt = __builtin_amdgcn_mfma_f32_16x16x32_bf16(aq, bsh, accwt, 0, 0, 0);
    accwt = __builtin_amdgcn_mfma_f32_16x16x32_bf16(aq, bsl, accwt, 0, 0, 0);
    accwt = __builtin_amdgcn_mfma_f32_16x16x32_bf16(aql, bsh, accwt, 0, 0, 0);
#pragma unroll
    for (int ct = 0; ct < 4; ++ct) {
      bf16x8 bk = *(const bf16x8*)(&khb[(ct * 16 + r) * LDW + kst * 32 + q * 8]);
      accd[ct] = __builtin_amdgcn_mfma_f32_16x16x32_bf16(aq, bk, accd[ct], 0, 0, 0);
    }
  }
#pragma unroll
  for (int ct = 0; ct < 4; ++ct)
#pragma unroll
    for (int reg = 0; reg < 4; ++reg) {
      int sl = sw + q * 4 + reg, tl = ct * 16 + r;
      float v = (tl <= sl) ? accd[ct][reg] : 0.f;
      dh[sl * LDW + tl] = f2bf(v);
    }
  __syncthreads();  // B1

#pragma unroll
  for (int i = 0; i < 4; ++i) {
    const float* pv = (const float*)&vv[i];
#pragma unroll
    for (int e = 0; e < 4; ++e)
      vt[(c16 + i * 4 + e) * LDW + row] = f2bf(pv[e]);
  }
  {
    const float* pv = (const float*)&svv;
#pragma unroll
    for (int e = 0; e < 4; ++e)
      svpt[(t4 + e) * LDN + g0] = f2bf(pv[e]);
    int ez = tid >> 2, gz = 16 + (tid & 3) * 4;
#pragma unroll
    for (int e = 0; e < 4; ++e) svpt[ez * LDN + gz + e] = 0;
    int tt = tid >> 2, gw = (tid & 3) * 4;
#pragma unroll
    for (int e = 0; e < 4; ++e) {
      wct[tt * LDN + gw + e] = whb[(gw + e) * LDW + tt];
      wct[tt * LDN + 16 + gw + e] = 0;
    }
  }

#pragma unroll
  for (int kst = 0; kst < 2; ++kst) {
    bf16x8 ad = *(const bf16x8*)(&dh[(sw + r) * LDW + kst * 32 + q * 8]);
    bf16x8 bw = *(const bf16x8*)(&whb[r * LDW + kst * 32 + q * 8]);
    bf16x8 bl = *(const bf16x8*)(&wlb[r * LDW + kst * 32 + q * 8]);
    accwt = __builtin_amdgcn_mfma_f32_16x16x32_bf16(ad, bw, accwt, 0, 0, 0);
    accwt = __builtin_amdgcn_mfma_f32_16x16x32_bf16(ad, bl, accwt, 0, 0, 0);
  }
#pragma unroll
  for (int reg = 0; reg < 4; ++reg) {
    int sl = sw + q * 4 + reg;
    float nv = fmaxf(nL[r * 68 + sl], 1e-8f);
    float wt = accwt[reg] / nv;
    float m = wt;
    m = fmaxf(m, __shfl_xor(m, 1));
    m = fmaxf(m, __shfl_xor(m, 2));
    m = fmaxf(m, __shfl_xor(m, 4));
    m = fmaxf(m, __shfl_xor(m, 8));
    float ex = expf(wt - m);
    float den = ex;
    den += __shfl_xor(den, 1);
    den += __shfl_xor(den, 2);
    den += __shfl_xor(den, 4);
    den += __shfl_xor(den, 8);
    float cmv = (ex / den) / nv;
    cmb[sl * LDN + r] = f2bf(cmv);
    cmb[sl * LDN + 16 + r] = 0;
  }
  __syncthreads();  // B2

  bf16x8 acm = *(const bf16x8*)(&cmb[(sw + r) * LDN + q * 8]);
  f32x4 accu[4];
#pragma unroll
  for (int ct = 0; ct < 4; ++ct) accu[ct] = (f32x4){0.f, 0.f, 0.f, 0.f};
#pragma unroll
  for (int ct = 0; ct < 4; ++ct) {
    bf16x8 bwc = *(const bf16x8*)(&wct[(ct * 16 + r) * LDN + q * 8]);
    accu[ct] = __builtin_amdgcn_mfma_f32_16x16x32_bf16(acm, bwc, accu[ct], 0, 0, 0);
  }
#pragma unroll
  for (int ct = 0; ct < 4; ++ct)
#pragma unroll
    for (int reg = 0; reg < 4; ++reg) {
      int sl = sw + q * 4 + reg, tl = ct * 16 + r;
      float v = (tl <= sl) ? accu[ct][reg] : 0.f;
      uh[sl * LDW + tl] = f2bf(v);
    }

  f32x4 acco[4];
#pragma unroll
  for (int et = 0; et < 4; ++et) acco[et] = (f32x4){0.f, 0.f, 0.f, 0.f};
#pragma unroll
  for (int et = 0; et < 4; ++et) {
    bf16x8 bs = *(const bf16x8*)(&svpt[(et * 16 + r) * LDN + q * 8]);
    acco[et] = __builtin_amdgcn_mfma_f32_16x16x32_bf16(acm, bs, acco[et], 0, 0, 0);
  }
#pragma unroll
  for (int kst = 0; kst < 2; ++kst) {
    bf16x8 au = *(const bf16x8*)(&uh[(sw + r) * LDW + kst * 32 + q * 8]);
#pragma unroll
    for (int et = 0; et < 4; ++et) {
      bf16x8 bv = *(const bf16x8*)(&vt[(et * 16 + r) * LDW + kst * 32 + q * 8]);
      acco[et] = __builtin_amdgcn_mfma_f32_16x16x32_bf16(au, bv, acco[et], 0, 0, 0);
    }
  }
#pragma unroll
  for (int et = 0; et < 4; ++et)
#pragma unroll
    for (int reg = 0; reg < 4; ++reg) {
      int sl = sw + q * 4 + reg;
      attnbf[((size_t)(b * SS + c * CLEN + sl)) * DD + h * EE + et * 16 + r] =
          f2bf(acco[et][reg]);
    }
}

extern "C" void kernel_launch(void* const* d_in, const int* in_sizes, int n_in,
                              void* d_out, int out_size, void* d_ws, size_t ws_size,
                              hipStream_t stream) {
  const float* query = (const float*)d_in[0];
  const float* key = (const float*)d_in[1];
  const float* value = (const float*)d_in[2];
  const float* context = (const float*)d_in[3];
  const float* query_proj = (const float*)d_in[4];
  const float* key_proj = (const float*)d_in[5];
  const float* value_proj = (const float*)d_in[6];
  const float* output_proj = (const float*)d_in[7];
  const float* context_proj = (const float*)d_in[8];
  float* out = (float*)d_out;

  float* fbase = (float*)d_ws;
  const size_t MS = (size_t)BB * SS * DD;  // 2M
  float* qs_t = fbase;
  float* kk_t = qs_t + MS;
  float* vs_t = kk_t + MS;
  float* csums = vs_t + MS;                         // 8192*132
  float* part = csums + (size_t)BB * HH * NCHUNK * GG * CS_STRIDE;  // 8*32*512
  short* Abf = (short*)(part + (size_t)8 * 32 * DD);  // attn bf16
  short* Wq = Abf + MS;
  short* Wk = Wq + (size_t)DD * DD;
  short* Wv = Wk + (size_t)DD * DD;
  short* Wo = Wv + (size_t)DD * DD;

  dim3 blk(256);
  dim3 tb(32, 8);

  prep_kernel<<<dim3(16, 16, 5), tb, 0, stream>>>(
      query_proj, key_proj, value_proj, output_proj, Wq, Wk, Wv, Wo,
      context, context_proj, part);

  proj_gemm<<<dim3(DD / 128, (BB * SS) / 128, 3), blk, 0, stream>>>(
      query, key, value, Wq, Wk, Wv, qs_t, kk_t, vs_t);

  dim3 gscan(NCHUNK, BB * HH);
  scanA_kernel<<<gscan, blk, 0, stream>>>(kk_t, vs_t, part, csums);
  chunk_kernel<<<gscan, blk, 0, stream>>>(kk_t, vs_t, qs_t, part, csums, Abf);

  gemm_bf16<<<dim3(DD / 128, (BB * SS) / 128), blk, 0, stream>>>(Abf, Wo, out, BB * SS, DD, DD);
}

// Round 11
// 145.756 us; speedup vs baseline: 3.6674x; 1.0070x over previous
//
#include <hip/hip_runtime.h>
#include <hip/hip_bf16.h>

// Problem constants
#define BB 2
#define SS 2048
#define GG 16
#define HH 8
#define EE 64
#define DD 512
#define NCHUNK 32
#define CLEN 64
#define CS_STRIDE 132  // 64 sk + 64 sv + 1 n + 3 pad

typedef __attribute__((ext_vector_type(8))) short bf16x8;
typedef __attribute__((ext_vector_type(4))) float f32x4;

static __device__ __forceinline__ short f2bf(float x) {
  union { float f; unsigned u; } v; v.f = x;
  unsigned r = v.u + 0x7fffu + ((v.u >> 16) & 1u);  // round-nearest-even
  return (short)(r >> 16);
}
static __device__ __forceinline__ float bf2f(short s) {
  return __uint_as_float(((unsigned)(unsigned short)s) << 16);
}
static __device__ __forceinline__ void bsplit(float x, short& hi, short& lo) {
  hi = f2bf(x);
  lo = f2bf(x - bf2f(hi));
}

// ---- prep kernel: z<4 -> weight transpose+cvt; z==4 -> ctx split-K partials ----
__global__ __launch_bounds__(256) void prep_kernel(const float* __restrict__ w0,
                                                   const float* __restrict__ w1,
                                                   const float* __restrict__ w2,
                                                   const float* __restrict__ w3,
                                                   short* __restrict__ o0,
                                                   short* __restrict__ o1,
                                                   short* __restrict__ o2,
                                                   short* __restrict__ o3,
                                                   const float* __restrict__ ctxA,
                                                   const float* __restrict__ ctxW,
                                                   float* __restrict__ part) {
  __shared__ float smem[32 * 68 + 64 * 68];
  const int tx = threadIdx.x, ty = threadIdx.y;
  if (blockIdx.z < 4) {
    const float* W; short* O;
    if (blockIdx.z == 0)      { W = w0; O = o0; }
    else if (blockIdx.z == 1) { W = w1; O = o1; }
    else if (blockIdx.z == 2) { W = w2; O = o2; }
    else                      { W = w3; O = o3; }
    float (*t)[33] = (float (*)[33])smem;
    const int k0 = blockIdx.x * 32, n0 = blockIdx.y * 32;
#pragma unroll
    for (int i = 0; i < 4; ++i)
      t[ty + i * 8][tx] = W[(size_t)(k0 + ty + i * 8) * DD + n0 + tx];
    __syncthreads();
#pragma unroll
    for (int i = 0; i < 4; ++i)
      O[(size_t)(n0 + ty + i * 8) * DD + k0 + tx] = f2bf(t[tx][ty + i * 8]);
    return;
  }
  if (blockIdx.x >= 8 || blockIdx.y >= 8) return;
  const int nt = blockIdx.x, ky = blockIdx.y;
  const int tid = ty * 32 + tx;
  float (*As)[68] = (float (*)[68])smem;
  float (*Ws)[68] = (float (*)[68])(smem + 32 * 68);
  {
    int m = tid >> 3, kq = (tid & 7) * 8;
    float4 a0 = *(const float4*)(ctxA + (size_t)m * DD + ky * 64 + kq);
    float4 a1 = *(const float4*)(ctxA + (size_t)m * DD + ky * 64 + kq + 4);
    As[m][kq + 0] = a0.x; As[m][kq + 1] = a0.y; As[m][kq + 2] = a0.z; As[m][kq + 3] = a0.w;
    As[m][kq + 4] = a1.x; As[m][kq + 5] = a1.y; As[m][kq + 6] = a1.z; As[m][kq + 7] = a1.w;
  }
  {
    int k = tid >> 2, nq = (tid & 3) * 16;
#pragma unroll
    for (int i = 0; i < 4; ++i) {
      float4 wv = *(const float4*)(ctxW + (size_t)(ky * 64 + k) * DD + nt * 64 + nq + i * 4);
      Ws[k][nq + i * 4 + 0] = wv.x; Ws[k][nq + i * 4 + 1] = wv.y;
      Ws[k][nq + i * 4 + 2] = wv.z; Ws[k][nq + i * 4 + 3] = wv.w;
    }
  }
  __syncthreads();
  const int txl = tid & 63, my = tid >> 6;
  float acc[8] = {};
  for (int k = 0; k < 64; ++k) {
    float wv = Ws[k][txl];
#pragma unroll
    for (int m = 0; m < 8; ++m) acc[m] += As[my * 8 + m][k] * wv;
  }
#pragma unroll
  for (int m = 0; m < 8; ++m)
    part[((size_t)ky * 32 + my * 8 + m) * DD + nt * 64 + txl] = acc[m];
}

// ---- batched projection GEMM: bf16 hi/lo planes out ----
// 128x128 tile, BK=64; z=0 -> (Qh,Ql), z=1 -> (Kh,Kl), z=2 -> (Vb, null).
#define LDA 72
__global__ __launch_bounds__(256) void proj_gemm(const float* __restrict__ a0,
                                                 const float* __restrict__ a1,
                                                 const float* __restrict__ a2,
                                                 const short* __restrict__ b0,
                                                 const short* __restrict__ b1,
                                                 const short* __restrict__ b2,
                                                 short* __restrict__ h0,
                                                 short* __restrict__ l0,
                                                 short* __restrict__ h1,
                                                 short* __restrict__ l1,
                                                 short* __restrict__ h2) {
  const float* A; const short* Bt; short* Chi; short* Clo;
  if (blockIdx.z == 0)      { A = a0; Bt = b0; Chi = h0; Clo = l0; }
  else if (blockIdx.z == 1) { A = a1; Bt = b1; Chi = h1; Clo = l1; }
  else                      { A = a2; Bt = b2; Chi = h2; Clo = nullptr; }
  const int N = DD, K = DD;
  __shared__ short As[128 * LDA];
  __shared__ short Bs[128 * LDA];
  const int tid = threadIdx.x;
  const int m0 = blockIdx.y * 128, n0 = blockIdx.x * 128;
  const int wv = tid >> 6, lane = tid & 63;
  const int wm = wv * 32;
  const int r = lane & 15, q = lane >> 4;
  f32x4 acc[2][8] = {};
  for (int k0 = 0; k0 < K; k0 += 64) {
    float4 af[4][2];
    bf16x8 bvv[4];
#pragma unroll
    for (int it = 0; it < 4; ++it) {
      int idx = tid + it * 256;
      int row = idx >> 3, colq = (idx & 7) * 8;
      af[it][0] = *(const float4*)(A + (size_t)(m0 + row) * K + k0 + colq);
      af[it][1] = *(const float4*)(A + (size_t)(m0 + row) * K + k0 + colq + 4);
      bvv[it] = *(const bf16x8*)(Bt + (size_t)(n0 + row) * K + k0 + colq);
    }
    __syncthreads();
#pragma unroll
    for (int it = 0; it < 4; ++it) {
      int idx = tid + it * 256;
      int row = idx >> 3, colq = (idx & 7) * 8;
      bf16x8 av;
      const float* p0 = (const float*)&af[it][0];
      const float* p1 = (const float*)&af[it][1];
      av[0] = f2bf(p0[0]); av[1] = f2bf(p0[1]); av[2] = f2bf(p0[2]); av[3] = f2bf(p0[3]);
      av[4] = f2bf(p1[0]); av[5] = f2bf(p1[1]); av[6] = f2bf(p1[2]); av[7] = f2bf(p1[3]);
      *(bf16x8*)(&As[row * LDA + colq]) = av;
      *(bf16x8*)(&Bs[row * LDA + colq]) = bvv[it];
    }
    __syncthreads();
#pragma unroll
    for (int ks = 0; ks < 2; ++ks) {
      bf16x8 a0r = *(const bf16x8*)(&As[(wm + r) * LDA + ks * 32 + q * 8]);
      bf16x8 a1r = *(const bf16x8*)(&As[(wm + 16 + r) * LDA + ks * 32 + q * 8]);
#pragma unroll
      for (int j = 0; j < 8; ++j) {
        bf16x8 br = *(const bf16x8*)(&Bs[(j * 16 + r) * LDA + ks * 32 + q * 8]);
        acc[0][j] = __builtin_amdgcn_mfma_f32_16x16x32_bf16(a0r, br, acc[0][j], 0, 0, 0);
        acc[1][j] = __builtin_amdgcn_mfma_f32_16x16x32_bf16(a1r, br, acc[1][j], 0, 0, 0);
      }
    }
  }
#pragma unroll
  for (int i = 0; i < 2; ++i)
#pragma unroll
    for (int j = 0; j < 8; ++j)
#pragma unroll
      for (int reg = 0; reg < 4; ++reg) {
        int m = m0 + wm + i * 16 + q * 4 + reg;
        int n = n0 + j * 16 + r;
        float x = acc[i][j][reg];
        short hi = f2bf(x);
        Chi[(size_t)m * N + n] = hi;
        if (Clo) Clo[(size_t)m * N + n] = f2bf(x - bf2f(hi));
      }
}

// ---------------- bf16 MFMA GEMM (bf16 A), 128x128 tile, BK=64 ----------------
__global__ __launch_bounds__(256) void gemm_bf16(const short* __restrict__ A,
                                                 const short* __restrict__ Bt,
                                                 float* __restrict__ C,
                                                 int M, int N, int K) {
  __shared__ short As[128 * LDA];
  __shared__ short Bs[128 * LDA];
  const int tid = threadIdx.x;
  const int m0 = blockIdx.y * 128, n0 = blockIdx.x * 128;
  const int wv = tid >> 6, lane = tid & 63;
  const int wm = wv * 32;
  const int r = lane & 15, q = lane >> 4;
  f32x4 acc[2][8] = {};
  for (int k0 = 0; k0 < K; k0 += 64) {
    bf16x8 av[4], bvv[4];
#pragma unroll
    for (int it = 0; it < 4; ++it) {
      int idx = tid + it * 256;
      int row = idx >> 3, colq = (idx & 7) * 8;
      av[it] = *(const bf16x8*)(A + (size_t)(m0 + row) * K + k0 + colq);
      bvv[it] = *(const bf16x8*)(Bt + (size_t)(n0 + row) * K + k0 + colq);
    }
    __syncthreads();
#pragma unroll
    for (int it = 0; it < 4; ++it) {
      int idx = tid + it * 256;
      int row = idx >> 3, colq = (idx & 7) * 8;
      *(bf16x8*)(&As[row * LDA + colq]) = av[it];
      *(bf16x8*)(&Bs[row * LDA + colq]) = bvv[it];
    }
    __syncthreads();
#pragma unroll
    for (int ks = 0; ks < 2; ++ks) {
      bf16x8 a0r = *(const bf16x8*)(&As[(wm + r) * LDA + ks * 32 + q * 8]);
      bf16x8 a1r = *(const bf16x8*)(&As[(wm + 16 + r) * LDA + ks * 32 + q * 8]);
#pragma unroll
      for (int j = 0; j < 8; ++j) {
        bf16x8 br = *(const bf16x8*)(&Bs[(j * 16 + r) * LDA + ks * 32 + q * 8]);
        acc[0][j] = __builtin_amdgcn_mfma_f32_16x16x32_bf16(a0r, br, acc[0][j], 0, 0, 0);
        acc[1][j] = __builtin_amdgcn_mfma_f32_16x16x32_bf16(a1r, br, acc[1][j], 0, 0, 0);
      }
    }
  }
#pragma unroll
  for (int i = 0; i < 2; ++i)
#pragma unroll
    for (int j = 0; j < 8; ++j)
#pragma unroll
      for (int reg = 0; reg < 4; ++reg) {
        int m = m0 + wm + i * 16 + q * 4 + reg;
        int n = n0 + j * 16 + r;
        C[(size_t)m * N + n] = acc[i][j][reg];
      }
}

#define LDW 72
#define LDN 40

// ---------------- scan phase A: chunk-local sums via MFMA, w computed inline ----------------
__global__ __launch_bounds__(256) void scanA_kernel(const short* __restrict__ Kh,
                                                    const short* __restrict__ Kl,
                                                    const short* __restrict__ Vb,
                                                    const float* __restrict__ part,
                                                    float* __restrict__ csums) {
  const int bh = blockIdx.y, c = blockIdx.x;
  const int b = bh >> 3, h = bh & 7;
  const int tid = threadIdx.x;
  const int lane = tid & 63, wvid = tid >> 6;
  const int r = lane & 15, q = lane >> 4;

  __shared__ short csh[16 * LDW], csl[16 * LDW];
  __shared__ short kh[64 * LDW], kl[64 * LDW];
  __shared__ short kTh[64 * LDW], kTl[64 * LDW];
  __shared__ short vT[64 * LDW];
  __shared__ short wh[16 * LDW], wl[16 * LDW];
  __shared__ float nPart[4][16];

  const int row = tid >> 2, c16 = (tid & 3) * 16;
  const size_t gb = ((size_t)(b * SS + c * CLEN + row)) * DD + h * EE + c16;
  bf16x8 kh0 = *(const bf16x8*)(Kh + gb);
  bf16x8 kh1 = *(const bf16x8*)(Kh + gb + 8);
  bf16x8 kl0 = *(const bf16x8*)(Kl + gb);
  bf16x8 kl1 = *(const bf16x8*)(Kl + gb + 8);
  bf16x8 v0 = *(const bf16x8*)(Vb + gb);
  bf16x8 v1 = *(const bf16x8*)(Vb + gb + 8);
  *(bf16x8*)(&kh[row * LDW + c16]) = kh0;
  *(bf16x8*)(&kh[row * LDW + c16 + 8]) = kh1;
  *(bf16x8*)(&kl[row * LDW + c16]) = kl0;
  *(bf16x8*)(&kl[row * LDW + c16 + 8]) = kl1;
#pragma unroll
  for (int t = 0; t < 8; ++t) {
    kTh[(c16 + t) * LDW + row] = kh0[t];
    kTh[(c16 + 8 + t) * LDW + row] = kh1[t];
    kTl[(c16 + t) * LDW + row] = kl0[t];
    kTl[(c16 + 8 + t) * LDW + row] = kl1[t];
    vT[(c16 + t) * LDW + row] = v0[t];
    vT[(c16 + 8 + t) * LDW + row] = v1[t];
  }
  {
    const int g0 = tid >> 4, t4 = (tid & 15) * 4;
    float4 csv = make_float4(0, 0, 0, 0);
#pragma unroll
    for (int ky = 0; ky < 8; ++ky) {
      float4 p = *(const float4*)(part + ((size_t)(ky * 32 + b * GG + g0)) * DD + h * EE + t4);
      csv.x += p.x; csv.y += p.y; csv.z += p.z; csv.w += p.w;
    }
    const float* pc = (const float*)&csv;
#pragma unroll
    for (int e = 0; e < 4; ++e) {
      short hi, lo;
      bsplit(pc[e], hi, lo);
      csh[g0 * LDW + t4 + e] = hi;
      csl[g0 * LDW + t4 + e] = lo;
    }
  }
  __syncthreads();  // S0

  f32x4 accw = {0.f, 0.f, 0.f, 0.f};
#pragma unroll
  for (int ks = 0; ks < 2; ++ks) {
    bf16x8 ah = *(const bf16x8*)(&csh[r * LDW + ks * 32 + q * 8]);
    bf16x8 al = *(const bf16x8*)(&csl[r * LDW + ks * 32 + q * 8]);
    bf16x8 bh = *(const bf16x8*)(&kh[(wvid * 16 + r) * LDW + ks * 32 + q * 8]);
    bf16x8 bl = *(const bf16x8*)(&kl[(wvid * 16 + r) * LDW + ks * 32 + q * 8]);
    accw = __builtin_amdgcn_mfma_f32_16x16x32_bf16(ah, bh, accw, 0, 0, 0);
    accw = __builtin_amdgcn_mfma_f32_16x16x32_bf16(ah, bl, accw, 0, 0, 0);
    accw = __builtin_amdgcn_mfma_f32_16x16x32_bf16(al, bh, accw, 0, 0, 0);
  }
  float wf[4];
#pragma unroll
  for (int reg = 0; reg < 4; ++reg) {
    wf[reg] = expf(accw[reg] * 0.125f);
    short hi, lo;
    bsplit(wf[reg], hi, lo);
    int g = q * 4 + reg, t = wvid * 16 + r;
    wh[g * LDW + t] = hi;
    wl[g * LDW + t] = lo;
  }
#pragma unroll
  for (int reg = 0; reg < 4; ++reg) {
    float np = wf[reg];
    np += __shfl_xor(np, 1);
    np += __shfl_xor(np, 2);
    np += __shfl_xor(np, 4);
    np += __shfl_xor(np, 8);
    if (r == 0) nPart[wvid][q * 4 + reg] = np;
  }
  __syncthreads();  // S1

  f32x4 ask = {0.f, 0.f, 0.f, 0.f}, asv = ask;
#pragma unroll
  for (int ks = 0; ks < 2; ++ks) {
    bf16x8 awh = *(const bf16x8*)(&wh[r * LDW + ks * 32 + q * 8]);
    bf16x8 awl = *(const bf16x8*)(&wl[r * LDW + ks * 32 + q * 8]);
    bf16x8 bkh = *(const bf16x8*)(&kTh[(wvid * 16 + r) * LDW + ks * 32 + q * 8]);
    bf16x8 bkl = *(const bf16x8*)(&kTl[(wvid * 16 + r) * LDW + ks * 32 + q * 8]);
    bf16x8 bv = *(const bf16x8*)(&vT[(wvid * 16 + r) * LDW + ks * 32 + q * 8]);
    ask = __builtin_amdgcn_mfma_f32_16x16x32_bf16(awh, bkh, ask, 0, 0, 0);
    ask = __builtin_amdgcn_mfma_f32_16x16x32_bf16(awh, bkl, ask, 0, 0, 0);
    ask = __builtin_amdgcn_mfma_f32_16x16x32_bf16(awl, bkh, ask, 0, 0, 0);
    asv = __builtin_amdgcn_mfma_f32_16x16x32_bf16(awh, bv, asv, 0, 0, 0);
    asv = __builtin_amdgcn_mfma_f32_16x16x32_bf16(awl, bv, asv, 0, 0, 0);
  }
#pragma unroll
  for (int reg = 0; reg < 4; ++reg) {
    int g = q * 4 + reg, e = wvid * 16 + r;
    size_t ob = ((size_t)((bh * NCHUNK + c) * GG + g)) * CS_STRIDE;
    csums[ob + e] = ask[reg];
    csums[ob + 64 + e] = asv[reg];
  }
  if (tid < 16) {
    size_t ob = ((size_t)((bh * NCHUNK + c) * GG + tid)) * CS_STRIDE;
    csums[ob + 128] = nPart[0][tid] + nPart[1][tid] + nPart[2][tid] + nPart[3][tid];
  }
}

// ---------------- chunk kernel: MFMA-based parallel causal attention ----------------
__global__ __launch_bounds__(256) void chunk_kernel(const short* __restrict__ Kh,
                                                    const short* __restrict__ Kl,
                                                    const short* __restrict__ Vb,
                                                    const short* __restrict__ Qh,
                                                    const short* __restrict__ Ql,
                                                    const float* __restrict__ part,
                                                    const float* __restrict__ csums,
                                                    short* __restrict__ attnbf) {
  const int c = blockIdx.x, bh = blockIdx.y;
  const int b = bh >> 3, h = bh & 7;
  const int tid = threadIdx.x;
  const int lane = tid & 63, wvid = tid >> 6;
  const int r = lane & 15, q = lane >> 4;
  const int sw = wvid * 16;

  __shared__ short qh[64 * LDW], qlo[64 * LDW], khb[64 * LDW], klo[64 * LDW], dh[64 * LDW];
  __shared__ short whb[16 * LDW], wlb[16 * LDW], skph[16 * LDW], skpl[16 * LDW];
  __shared__ short cshb[16 * LDW], cslb[16 * LDW];
  __shared__ short svpt[64 * LDN];
  __shared__ float nL[16 * 68];
  __shared__ float npreL[16];
  short* wct = qh;   // reused post-B1
  short* cmb = qlo;  // reused post-B1
  short* vt = khb;   // reused post-B1
  short* uh = dh;    // reused post-phase3

  const int row = tid >> 2, c16 = (tid & 3) * 16;
  const size_t gb = ((size_t)(b * SS + c * CLEN + row)) * DD + h * EE + c16;
  bf16x8 q0 = *(const bf16x8*)(Qh + gb);
  bf16x8 q1 = *(const bf16x8*)(Qh + gb + 8);
  bf16x8 ql0 = *(const bf16x8*)(Ql + gb);
  bf16x8 ql1 = *(const bf16x8*)(Ql + gb + 8);
  bf16x8 k0 = *(const bf16x8*)(Kh + gb);
  bf16x8 k1 = *(const bf16x8*)(Kh + gb + 8);
  bf16x8 kl0 = *(const bf16x8*)(Kl + gb);
  bf16x8 kl1 = *(const bf16x8*)(Kl + gb + 8);
  bf16x8 v0 = *(const bf16x8*)(Vb + gb);
  bf16x8 v1 = *(const bf16x8*)(Vb + gb + 8);

  const int g0 = tid >> 4, t4 = (tid & 15) * 4;
  float4 csv = make_float4(0, 0, 0, 0);
#pragma unroll
  for (int ky = 0; ky < 8; ++ky) {
    float4 p = *(const float4*)(part + ((size_t)(ky * 32 + b * GG + g0)) * DD + h * EE + t4);
    csv.x += p.x; csv.y += p.y; csv.z += p.z; csv.w += p.w;
  }

  float4 skv = make_float4(0, 0, 0, 0), svv = make_float4(0, 0, 0, 0);
  {
    int c2 = 0;
    for (; c2 + 4 <= c; c2 += 4) {
#pragma unroll
      for (int u = 0; u < 4; ++u) {
        size_t ob2 = ((size_t)((bh * NCHUNK + c2 + u) * GG + g0)) * CS_STRIDE;
        float4 a = *(const float4*)(csums + ob2 + t4);
        float4 bsum = *(const float4*)(csums + ob2 + 64 + t4);
        skv.x += a.x; skv.y += a.y; skv.z += a.z; skv.w += a.w;
        svv.x += bsum.x; svv.y += bsum.y; svv.z += bsum.z; svv.w += bsum.w;
      }
    }
    for (; c2 < c; ++c2) {
      size_t ob2 = ((size_t)((bh * NCHUNK + c2) * GG + g0)) * CS_STRIDE;
      float4 a = *(const float4*)(csums + ob2 + t4);
      float4 bsum = *(const float4*)(csums + ob2 + 64 + t4);
      skv.x += a.x; skv.y += a.y; skv.z += a.z; skv.w += a.w;
      svv.x += bsum.x; svv.y += bsum.y; svv.z += bsum.z; svv.w += bsum.w;
    }
  }
  if (tid < 16) {
    float npr = 0.f;
    for (int c2 = 0; c2 < c; ++c2)
      npr += csums[((size_t)((bh * NCHUNK + c2) * GG + tid)) * CS_STRIDE + 128];
    npreL[tid] = npr;
  }

  *(bf16x8*)(&qh[row * LDW + c16]) = q0;
  *(bf16x8*)(&qh[row * LDW + c16 + 8]) = q1;
  *(bf16x8*)(&qlo[row * LDW + c16]) = ql0;
  *(bf16x8*)(&qlo[row * LDW + c16 + 8]) = ql1;
  *(bf16x8*)(&khb[row * LDW + c16]) = k0;
  *(bf16x8*)(&khb[row * LDW + c16 + 8]) = k1;
  *(bf16x8*)(&klo[row * LDW + c16]) = kl0;
  *(bf16x8*)(&klo[row * LDW + c16 + 8]) = kl1;
  {
    const float* pc = (const float*)&csv;
    const float* ps = (const float*)&skv;
#pragma unroll
    for (int e = 0; e < 4; ++e) {
      short hi, lo;
      bsplit(pc[e], hi, lo);
      cshb[g0 * LDW + t4 + e] = hi;
      cslb[g0 * LDW + t4 + e] = lo;
      bsplit(ps[e], hi, lo);
      skph[g0 * LDW + t4 + e] = hi;
      skpl[g0 * LDW + t4 + e] = lo;
    }
  }
  __syncthreads();  // S0

  {
    f32x4 accw = {0.f, 0.f, 0.f, 0.f};
#pragma unroll
    for (int ks = 0; ks < 2; ++ks) {
      bf16x8 ah = *(const bf16x8*)(&cshb[r * LDW + ks * 32 + q * 8]);
      bf16x8 al = *(const bf16x8*)(&cslb[r * LDW + ks * 32 + q * 8]);
      bf16x8 bh = *(const bf16x8*)(&khb[(sw + r) * LDW + ks * 32 + q * 8]);
      bf16x8 bl = *(const bf16x8*)(&klo[(sw + r) * LDW + ks * 32 + q * 8]);
      accw = __builtin_amdgcn_mfma_f32_16x16x32_bf16(ah, bh, accw, 0, 0, 0);
      accw = __builtin_amdgcn_mfma_f32_16x16x32_bf16(ah, bl, accw, 0, 0, 0);
      accw = __builtin_amdgcn_mfma_f32_16x16x32_bf16(al, bh, accw, 0, 0, 0);
    }
#pragma unroll
    for (int reg = 0; reg < 4; ++reg) {
      float wv = expf(accw[reg] * 0.125f);
      short hi, lo;
      bsplit(wv, hi, lo);
      int g = q * 4 + reg, t = sw + r;
      whb[g * LDW + t] = hi;
      wlb[g * LDW + t] = lo;
    }
  }
  __syncthreads();  // S0b

#pragma unroll
  for (int gg = 0; gg < 4; ++gg) {
    int g = wvid * 4 + gg;
    float val = bf2f(whb[g * LDW + lane]) + bf2f(wlb[g * LDW + lane]);
#pragma unroll
    for (int d = 1; d < 64; d <<= 1) {
      float tup = __shfl_up(val, d);
      if (lane >= d) val += tup;
    }
    nL[g * 68 + lane] = npreL[g] + val;
  }

  f32x4 accd[4];
  f32x4 accwt = {0.f, 0.f, 0.f, 0.f};
#pragma unroll
  for (int ct = 0; ct < 4; ++ct) accd[ct] = accwt;
#pragma unroll
  for (int kst = 0; kst < 2; ++kst) {
    bf16x8 aq = *(const bf16x8*)(&qh[(sw + r) * LDW + kst * 32 + q * 8]);
    bf16x8 aql = *(const bf16x8*)(&qlo[(sw + r) * LDW + kst * 32 + q * 8]);
    bf16x8 bsh = *(const bf16x8*)(&skph[r * LDW + kst * 32 + q * 8]);
    bf16x8 bsl = *(const bf16x8*)(&skpl[r * LDW + kst * 32 + q * 8]);
    accwt = __builtin_amdgcn_mfma_f32_16x16x32_bf16(aq, bsh, accwt, 0, 0, 0);
    accwt = __builtin_amdgcn_mfma_f32_16x16x32_bf16(aq, bsl, accwt, 0, 0, 0);
    accwt = __builtin_amdgcn_mfma_f32_16x16x32_bf16(aql, bsh, accwt, 0, 0, 0);
#pragma unroll
    for (int ct = 0; ct < 4; ++ct) {
      bf16x8 bk = *(const bf16x8*)(&khb[(ct * 16 + r) * LDW + kst * 32 + q * 8]);
      accd[ct] = __builtin_amdgcn_mfma_f32_16x16x32_bf16(aq, bk, accd[ct], 0, 0, 0);
    }
  }
#pragma unroll
  for (int ct = 0; ct < 4; ++ct)
#pragma unroll
    for (int reg = 0; reg < 4; ++reg) {
      int sl = sw + q * 4 + reg, tl = ct * 16 + r;
      float v = (tl <= sl) ? accd[ct][reg] : 0.f;
      dh[sl * LDW + tl] = f2bf(v);
    }
  __syncthreads();  // B1

#pragma unroll
  for (int t = 0; t < 8; ++t) {
    vt[(c16 + t) * LDW + row] = v0[t];
    vt[(c16 + 8 + t) * LDW + row] = v1[t];
  }
  {
    const float* pv = (const float*)&svv;
#pragma unroll
    for (int e = 0; e < 4; ++e)
      svpt[(t4 + e) * LDN + g0] = f2bf(pv[e]);
    int ez = tid >> 2, gz = 16 + (tid & 3) * 4;
#pragma unroll
    for (int e = 0; e < 4; ++e) svpt[ez * LDN + gz + e] = 0;
    int tt = tid >> 2, gw = (tid & 3) * 4;
#pragma unroll
    for (int e = 0; e < 4; ++e) {
      wct[tt * LDN + gw + e] = whb[(gw + e) * LDW + tt];
      wct[tt * LDN + 16 + gw + e] = 0;
    }
  }

#pragma unroll
  for (int kst = 0; kst < 2; ++kst) {
    bf16x8 ad = *(const bf16x8*)(&dh[(sw + r) * LDW + kst * 32 + q * 8]);
    bf16x8 bw = *(const bf16x8*)(&whb[r * LDW + kst * 32 + q * 8]);
    bf16x8 bl = *(const bf16x8*)(&wlb[r * LDW + kst * 32 + q * 8]);
    accwt = __builtin_amdgcn_mfma_f32_16x16x32_bf16(ad, bw, accwt, 0, 0, 0);
    accwt = __builtin_amdgcn_mfma_f32_16x16x32_bf16(ad, bl, accwt, 0, 0, 0);
  }
#pragma unroll
  for (int reg = 0; reg < 4; ++reg) {
    int sl = sw + q * 4 + reg;
    float nv = fmaxf(nL[r * 68 + sl], 1e-8f);
    float wt = accwt[reg] / nv;
    float m = wt;
    m = fmaxf(m, __shfl_xor(m, 1));
    m = fmaxf(m, __shfl_xor(m, 2));
    m = fmaxf(m, __shfl_xor(m, 4));
    m = fmaxf(m, __shfl_xor(m, 8));
    float ex = expf(wt - m);
    float den = ex;
    den += __shfl_xor(den, 1);
    den += __shfl_xor(den, 2);
    den += __shfl_xor(den, 4);
    den += __shfl_xor(den, 8);
    float cmv = (ex / den) / nv;
    cmb[sl * LDN + r] = f2bf(cmv);
    cmb[sl * LDN + 16 + r] = 0;
  }
  __syncthreads();  // B2

  bf16x8 acm = *(const bf16x8*)(&cmb[(sw + r) * LDN + q * 8]);
  f32x4 accu[4];
#pragma unroll
  for (int ct = 0; ct < 4; ++ct) accu[ct] = (f32x4){0.f, 0.f, 0.f, 0.f};
#pragma unroll
  for (int ct = 0; ct < 4; ++ct) {
    bf16x8 bwc = *(const bf16x8*)(&wct[(ct * 16 + r) * LDN + q * 8]);
    accu[ct] = __builtin_amdgcn_mfma_f32_16x16x32_bf16(acm, bwc, accu[ct], 0, 0, 0);
  }
#pragma unroll
  for (int ct = 0; ct < 4; ++ct)
#pragma unroll
    for (int reg = 0; reg < 4; ++reg) {
      int sl = sw + q * 4 + reg, tl = ct * 16 + r;
      float v = (tl <= sl) ? accu[ct][reg] : 0.f;
      uh[sl * LDW + tl] = f2bf(v);
    }

  f32x4 acco[4];
#pragma unroll
  for (int et = 0; et < 4; ++et) acco[et] = (f32x4){0.f, 0.f, 0.f, 0.f};
#pragma unroll
  for (int et = 0; et < 4; ++et) {
    bf16x8 bs = *(const bf16x8*)(&svpt[(et * 16 + r) * LDN + q * 8]);
    acco[et] = __builtin_amdgcn_mfma_f32_16x16x32_bf16(acm, bs, acco[et], 0, 0, 0);
  }
#pragma unroll
  for (int kst = 0; kst < 2; ++kst) {
    bf16x8 au = *(const bf16x8*)(&uh[(sw + r) * LDW + kst * 32 + q * 8]);
#pragma unroll
    for (int et = 0; et < 4; ++et) {
      bf16x8 bv = *(const bf16x8*)(&vt[(et * 16 + r) * LDW + kst * 32 + q * 8]);
      acco[et] = __builtin_amdgcn_mfma_f32_16x16x32_bf16(au, bv, acco[et], 0, 0, 0);
    }
  }
#pragma unroll
  for (int et = 0; et < 4; ++et)
#pragma unroll
    for (int reg = 0; reg < 4; ++reg) {
      int sl = sw + q * 4 + reg;
      attnbf[((size_t)(b * SS + c * CLEN + sl)) * DD + h * EE + et * 16 + r] =
          f2bf(acco[et][reg]);
    }
}

extern "C" void kernel_launch(void* const* d_in, const int* in_sizes, int n_in,
                              void* d_out, int out_size, void* d_ws, size_t ws_size,
                              hipStream_t stream) {
  const float* query = (const float*)d_in[0];
  const float* key = (const float*)d_in[1];
  const float* value = (const float*)d_in[2];
  const float* context = (const float*)d_in[3];
  const float* query_proj = (const float*)d_in[4];
  const float* key_proj = (const float*)d_in[5];
  const float* value_proj = (const float*)d_in[6];
  const float* output_proj = (const float*)d_in[7];
  const float* context_proj = (const float*)d_in[8];
  float* out = (float*)d_out;

  const size_t MS = (size_t)BB * SS * DD;  // 2M elements
  float* fbase = (float*)d_ws;
  float* csums = fbase;                              // 8192*132
  float* part = csums + (size_t)BB * HH * NCHUNK * GG * CS_STRIDE;  // 8*32*512
  short* Qh = (short*)(part + (size_t)8 * 32 * DD);
  short* Ql = Qh + MS;
  short* Kh = Ql + MS;
  short* Kl = Kh + MS;
  short* Vb = Kl + MS;
  short* Abf = Vb + MS;  // attn bf16
  short* Wq = Abf + MS;
  short* Wk = Wq + (size_t)DD * DD;
  short* Wv = Wk + (size_t)DD * DD;
  short* Wo = Wv + (size_t)DD * DD;

  dim3 blk(256);
  dim3 tb(32, 8);

  prep_kernel<<<dim3(16, 16, 5), tb, 0, stream>>>(
      query_proj, key_proj, value_proj, output_proj, Wq, Wk, Wv, Wo,
      context, context_proj, part);

  proj_gemm<<<dim3(DD / 128, (BB * SS) / 128, 3), blk, 0, stream>>>(
      query, key, value, Wq, Wk, Wv, Qh, Ql, Kh, Kl, Vb);

  dim3 gscan(NCHUNK, BB * HH);
  scanA_kernel<<<gscan, blk, 0, stream>>>(Kh, Kl, Vb, part, csums);
  chunk_kernel<<<gscan, blk, 0, stream>>>(Kh, Kl, Vb, Qh, Ql, part, csums, Abf);

  gemm_bf16<<<dim3(DD / 128, (BB * SS) / 128), blk, 0, stream>>>(Abf, Wo, out, BB * SS, DD, DD);
}